// Round 1
// 374.328 us; speedup vs baseline: 1.1826x; 1.1826x over previous
//
#include <hip/hip_runtime.h>

typedef unsigned short u16;

constexpr int kN   = 512;
constexpr int kIN  = 256;
constexpr int kHID = 256;
constexpr int kHD  = 64;
constexpr int kOUT = 256;

// ---------- bf16 helpers ----------
__device__ __forceinline__ float us2f(u16 u){
  union { unsigned int i; float f; } c; c.i = ((unsigned int)u) << 16; return c.f;
}
__device__ __forceinline__ u16 f2us(float f){
  union { float f; unsigned int i; } c; c.f = f;
  unsigned int r = c.i + 0x7fff + ((c.i >> 16) & 1);
  return (u16)(r >> 16);
}

// ---------- dtype probe: decide bf16 vs fp32 input buffers ----------
__global__ void k_probe(const unsigned int* __restrict__ V, int* __restrict__ flag){
  __shared__ int cnt;
  if (threadIdx.x == 0) cnt = 0;
  __syncthreads();
  int c = 0;
  for (int k = threadIdx.x; k < 4096; k += 256){
    float x = us2f((u16)(V[k] & 0xffffu));
    float ax = fabsf(x);
    if (!(ax <= 32.0f)) c++;   // also catches NaN/Inf bit patterns
  }
  atomicAdd(&cnt, c);
  __syncthreads();
  if (threadIdx.x == 0) *flag = (cnt > 64) ? 1 : 0;
}

// ---------- convert all float tensors to fp32 in workspace ----------
struct ConvArgs { const void* src[23]; float* dst[23]; int n[23]; };

__global__ void k_convert_all(ConvArgs a, const int* __restrict__ flag){
  bool f32 = (*flag != 0);
  int stride = gridDim.x * blockDim.x;
  int t = blockIdx.x * blockDim.x + threadIdx.x;
  for (int s = 0; s < 23; ++s){
    int n = a.n[s];
    const float* sf = (const float*)a.src[s];
    const u16*   sb = (const u16*)a.src[s];
    float* d = a.dst[s];
    for (int i = t; i < n; i += stride)
      d[i] = f32 ? sf[i] : us2f(sb[i]);
  }
}

// ---------- block reduction (blockDim multiple of 64, <=512) ----------
__device__ __forceinline__ float blk_red(float v, float* tmp, bool isMax){
  int lane = threadIdx.x & 63, wv = threadIdx.x >> 6;
  #pragma unroll
  for (int o = 32; o > 0; o >>= 1){
    float t = __shfl_down(v, o, 64);
    v = isMax ? fmaxf(v, t) : (v + t);
  }
  __syncthreads();
  if (lane == 0) tmp[wv] = v;
  __syncthreads();
  int nw = (blockDim.x + 63) >> 6;
  float r = tmp[0];
  for (int i = 1; i < nw; ++i) r = isMax ? fmaxf(r, tmp[i]) : (r + tmp[i]);
  return r;
}

// ================== tiled multi-GEMM ==================
// C[i,n] = act( sum_k X[i,k] * W[n,k] + bias[n] ),  X = concat(Xa[K1], Xb[Ktot-K1])
// M = 512 fixed. Tile 64x64, BK=32, 256 threads, 4x4 micro-tile per thread.
// grid = dim3(8 * (Nout/64), nsegs); all segs in one launch share Nout.
struct GSeg {
  const float* Xa; const float* Xb; const float* W; const float* bias; float* C;
  int K1, Ktot, ldw, act, Nout;
};
struct GArgs { GSeg s[3]; };

__global__ __launch_bounds__(256) void k_gemm_t(GArgs ga)
{
  const GSeg sg = ga.s[blockIdx.y];
  const int tm = blockIdx.x & 7;       // row tile (M/64 = 8)
  const int tn = blockIdx.x >> 3;      // col tile
  const int i0 = tm << 6;
  const int n0 = tn << 6;
  const int tid = threadIdx.x;

  // padded stride 68: keeps ds_read_b128 16B-aligned, banks spread
  __shared__ float Xs[32][68];
  __shared__ float Ws[32][68];

  const int rg = tid >> 4;             // 0..15
  const int cg = tid & 15;             // 0..15
  const int r0 = rg << 2;
  const int c0 = cg << 2;

  const int lrow = tid >> 3;           // 0..31  (staging row within half-tile)
  const int lk   = (tid & 7) << 2;     // 0,4,...,28 (staging k offset)

  const int K1 = sg.K1;
  const int K2 = sg.Ktot - sg.K1;

  float acc[4][4] = {};

  const int nkt = sg.Ktot >> 5;
  for (int t = 0; t < nkt; ++t){
    const int kt = t << 5;
    if (t) __syncthreads();
    const int kg = kt + lk;            // K1 % 32 == 0, so branch is k-tile-uniform
    #pragma unroll
    for (int ph = 0; ph < 2; ++ph){
      const int row = lrow + (ph << 5);
      const float* xsrc = (kg < K1)
          ? (sg.Xa + (size_t)(i0 + row) * K1 + kg)
          : (sg.Xb + (size_t)(i0 + row) * K2 + (kg - K1));
      const float4 xv = *(const float4*)xsrc;
      Xs[lk+0][row] = xv.x; Xs[lk+1][row] = xv.y;
      Xs[lk+2][row] = xv.z; Xs[lk+3][row] = xv.w;
      const float4 wv = *(const float4*)(sg.W + (size_t)(n0 + row) * sg.ldw + kg);
      Ws[lk+0][row] = wv.x; Ws[lk+1][row] = wv.y;
      Ws[lk+2][row] = wv.z; Ws[lk+3][row] = wv.w;
    }
    __syncthreads();
    #pragma unroll
    for (int kk = 0; kk < 32; ++kk){
      const float4 a = *(const float4*)&Xs[kk][r0];
      const float4 b = *(const float4*)&Ws[kk][c0];
      acc[0][0] += a.x*b.x; acc[0][1] += a.x*b.y; acc[0][2] += a.x*b.z; acc[0][3] += a.x*b.w;
      acc[1][0] += a.y*b.x; acc[1][1] += a.y*b.y; acc[1][2] += a.y*b.z; acc[1][3] += a.y*b.w;
      acc[2][0] += a.z*b.x; acc[2][1] += a.z*b.y; acc[2][2] += a.z*b.z; acc[2][3] += a.z*b.w;
      acc[3][0] += a.w*b.x; acc[3][1] += a.w*b.y; acc[3][2] += a.w*b.z; acc[3][3] += a.w*b.w;
    }
  }

  float bb[4] = {0.f, 0.f, 0.f, 0.f};
  if (sg.bias){
    bb[0] = sg.bias[n0+c0+0]; bb[1] = sg.bias[n0+c0+1];
    bb[2] = sg.bias[n0+c0+2]; bb[3] = sg.bias[n0+c0+3];
  }
  #pragma unroll
  for (int ri = 0; ri < 4; ++ri){
    float4 v;
    v.x = acc[ri][0] + bb[0];
    v.y = acc[ri][1] + bb[1];
    v.z = acc[ri][2] + bb[2];
    v.w = acc[ri][3] + bb[3];
    if (sg.act){
      v.x = fmaxf(v.x, 0.f); v.y = fmaxf(v.y, 0.f);
      v.z = fmaxf(v.z, 0.f); v.w = fmaxf(v.w, 0.f);
    }
    *(float4*)(sg.C + (size_t)(i0 + r0 + ri) * sg.Nout + (n0 + c0)) = v;
  }
}

// ---------- e1[j] = Wh1[j,:] . sa1 ----------
__global__ void k_e1(const float* __restrict__ Wh1, const float* __restrict__ sa1,
                     float* __restrict__ e1)
{
  int i = blockIdx.x, lane = threadIdx.x; // block 64
  float a = 0.f;
  for (int k = lane; k < kHID; k += 64) a += Wh1[(size_t)i*kHID + k] * sa1[k];
  #pragma unroll
  for (int o = 32; o > 0; o >>= 1) a += __shfl_down(a, o, 64);
  if (lane == 0) e1[i] = a;
}

// ---------- H1: row-wise masked softmax over e1[j], weighted sum of Wh1 rows ----------
__global__ void k_h1(const int* __restrict__ adj, const float* __restrict__ e1,
                     const float* __restrict__ Wh1, float* __restrict__ H1)
{
  __shared__ float w[4][kN];
  __shared__ float red[8];
  int i0 = blockIdx.x * 4, tid = threadIdx.x; // block 256
  float invz[4];
  #pragma unroll
  for (int r = 0; r < 4; ++r){
    int i = i0 + r;
    int m0 = adj[(size_t)i*kN + tid];
    int m1 = adj[(size_t)i*kN + tid + 256];
    float ea = e1[tid], eb = e1[tid+256];
    float v0 = m0 ? ea : -1e30f;
    float v1 = m1 ? eb : -1e30f;
    float m = blk_red(fmaxf(v0, v1), red, true);
    float w0 = m0 ? expf(ea - m) : 0.0f;
    float w1 = m1 ? expf(eb - m) : 0.0f;
    w[r][tid] = w0; w[r][tid+256] = w1;
    float z = blk_red(w0 + w1, red, false);
    invz[r] = 1.0f / z;
  }
  __syncthreads();
  float a0=0,a1=0,a2=0,a3=0;
  for (int j = 0; j < kN; ++j){
    float wh = Wh1[(size_t)j*kHID + tid];
    a0 += w[0][j]*wh; a1 += w[1][j]*wh; a2 += w[2][j]*wh; a3 += w[3][j]*wh;
  }
  H1[(size_t)(i0+0)*kHID+tid] = a0*invz[0];
  H1[(size_t)(i0+1)*kHID+tid] = a1*invz[1];
  H1[(size_t)(i0+2)*kHID+tid] = a2*invz[2];
  H1[(size_t)(i0+3)*kHID+tid] = a3*invz[3];
}

// ---------- u = ce_w2^T (ca0+ca1), beta = ce_b2 . (ca0+ca1) ----------
__global__ void k_ub(const float* __restrict__ ce_w2, const float* __restrict__ ce_b2,
                     const float* __restrict__ ca0, const float* __restrict__ ca1,
                     float* __restrict__ u, float* __restrict__ beta)
{
  __shared__ float c[kHD];
  int tid = threadIdx.x; // 256
  if (tid < kHD) c[tid] = ca0[tid] + ca1[tid];
  __syncthreads();
  float a = 0.f;
  for (int d = 0; d < kHD; ++d) a += ce_w2[(size_t)d*kHID + tid] * c[d];
  u[tid] = a;
  if (tid == 0){
    float b = 0.f;
    for (int d = 0; d < kHD; ++d) b += ce_b2[d] * c[d];
    *beta = b;
  }
}

// ---------- s2[i,j] = relu(A_i + B_j + b1) . u + beta (diag -> -1e30); rowmax/rowZ ----------
__global__ void k_s2(const float* __restrict__ A, const float* __restrict__ Bm,
                     const float* __restrict__ ce_b1,
                     const float* __restrict__ u, const float* __restrict__ beta,
                     float* __restrict__ s2, float* __restrict__ rowmax,
                     float* __restrict__ rowZ)
{
  __shared__ float aib[4][kHID];
  __shared__ float uu[kHID];
  __shared__ float red[8];
  int i0 = blockIdx.x * 4, tid = threadIdx.x; // block 256
  uu[tid] = u[tid];
  float b1v = ce_b1[tid];
  #pragma unroll
  for (int r = 0; r < 4; ++r) aib[r][tid] = A[(size_t)(i0+r)*kHID + tid] + b1v;
  __syncthreads();
  float bet = *beta;
  float sv[4][2];
  #pragma unroll
  for (int t = 0; t < 2; ++t){
    int j = tid + t*256;
    float a0=bet, a1=bet, a2=bet, a3=bet;
    const float4* bp = (const float4*)(Bm + (size_t)j*kHID);
    for (int k4 = 0; k4 < kHID/4; ++k4){
      float4 b = bp[k4];
      int k = k4*4;
      a0 += fmaxf(aib[0][k+0]+b.x,0.f)*uu[k+0] + fmaxf(aib[0][k+1]+b.y,0.f)*uu[k+1]
          + fmaxf(aib[0][k+2]+b.z,0.f)*uu[k+2] + fmaxf(aib[0][k+3]+b.w,0.f)*uu[k+3];
      a1 += fmaxf(aib[1][k+0]+b.x,0.f)*uu[k+0] + fmaxf(aib[1][k+1]+b.y,0.f)*uu[k+1]
          + fmaxf(aib[1][k+2]+b.z,0.f)*uu[k+2] + fmaxf(aib[1][k+3]+b.w,0.f)*uu[k+3];
      a2 += fmaxf(aib[2][k+0]+b.x,0.f)*uu[k+0] + fmaxf(aib[2][k+1]+b.y,0.f)*uu[k+1]
          + fmaxf(aib[2][k+2]+b.z,0.f)*uu[k+2] + fmaxf(aib[2][k+3]+b.w,0.f)*uu[k+3];
      a3 += fmaxf(aib[3][k+0]+b.x,0.f)*uu[k+0] + fmaxf(aib[3][k+1]+b.y,0.f)*uu[k+1]
          + fmaxf(aib[3][k+2]+b.z,0.f)*uu[k+2] + fmaxf(aib[3][k+3]+b.w,0.f)*uu[k+3];
    }
    if (j == i0+0) a0 = -1e30f;
    if (j == i0+1) a1 = -1e30f;
    if (j == i0+2) a2 = -1e30f;
    if (j == i0+3) a3 = -1e30f;
    s2[(size_t)(i0+0)*kN + j] = a0;
    s2[(size_t)(i0+1)*kN + j] = a1;
    s2[(size_t)(i0+2)*kN + j] = a2;
    s2[(size_t)(i0+3)*kN + j] = a3;
    sv[0][t]=a0; sv[1][t]=a1; sv[2][t]=a2; sv[3][t]=a3;
  }
  #pragma unroll
  for (int r = 0; r < 4; ++r){
    float m = blk_red(fmaxf(sv[r][0], sv[r][1]), red, true);
    float z = blk_red(expf(sv[r][0]-m) + expf(sv[r][1]-m), red, false);
    if (tid == 0){ rowmax[i0+r] = m; rowZ[i0+r] = z; }
  }
}

// ---------- global softmax stats over s2 ----------
__global__ void k_mz(const float* __restrict__ rowmax, const float* __restrict__ rowZ,
                     float* __restrict__ MZ)
{
  __shared__ float red[8];
  int tid = threadIdx.x; // 256
  float m = fmaxf(rowmax[tid], rowmax[tid+256]);
  m = blk_red(m, red, true);
  float z = rowZ[tid]*expf(rowmax[tid]-m) + rowZ[tid+256]*expf(rowmax[tid+256]-m);
  z = blk_red(z, red, false);
  if (tid == 0){ MZ[0] = m; MZ[1] = z; }
}

// ---------- gpart[i,k] = sum_j a2[i,j] * relu(A_i[k]+B_j[k]+b1[k]) ----------
__global__ void k_gpart(const float* __restrict__ A, const float* __restrict__ Bm,
                        const float* __restrict__ ce_b1,
                        const float* __restrict__ s2, const float* __restrict__ MZ,
                        float* __restrict__ gpart)
{
  __shared__ float w[4][kN];
  int i0 = blockIdx.x * 4, tid = threadIdx.x; // block 256
  float M = MZ[0], invZ = 1.0f / MZ[1];
  #pragma unroll
  for (int r = 0; r < 4; ++r){
    w[r][tid]     = expf(s2[(size_t)(i0+r)*kN + tid]       - M) * invZ;
    w[r][tid+256] = expf(s2[(size_t)(i0+r)*kN + tid + 256] - M) * invZ;
  }
  float b1v = ce_b1[tid];
  float ai0 = A[(size_t)(i0+0)*kHID + tid] + b1v;
  float ai1 = A[(size_t)(i0+1)*kHID + tid] + b1v;
  float ai2 = A[(size_t)(i0+2)*kHID + tid] + b1v;
  float ai3 = A[(size_t)(i0+3)*kHID + tid] + b1v;
  __syncthreads();
  float g0=0,g1=0,g2=0,g3=0;
  for (int j = 0; j < kN; ++j){
    float bj = Bm[(size_t)j*kHID + tid];
    g0 += w[0][j]*fmaxf(ai0+bj, 0.f);
    g1 += w[1][j]*fmaxf(ai1+bj, 0.f);
    g2 += w[2][j]*fmaxf(ai2+bj, 0.f);
    g3 += w[3][j]*fmaxf(ai3+bj, 0.f);
  }
  gpart[(size_t)(i0+0)*kHID+tid]=g0;
  gpart[(size_t)(i0+1)*kHID+tid]=g1;
  gpart[(size_t)(i0+2)*kHID+tid]=g2;
  gpart[(size_t)(i0+3)*kHID+tid]=g3;
}

// ---------- g = colsum(gpart); H2vec = g @ ce_w2^T + ce_b2 ----------
__global__ void k_h2(const float* __restrict__ gpart, const float* __restrict__ ce_w2,
                     const float* __restrict__ ce_b2, float* __restrict__ H2vec)
{
  __shared__ float g[kHID];
  int tid = threadIdx.x; // 256, single block
  float a = 0.f;
  for (int i = 0; i < kN; ++i) a += gpart[(size_t)i*kHID + tid];
  g[tid] = a;
  __syncthreads();
  if (tid < kHD){
    float h = ce_b2[tid];
    for (int k = 0; k < kHID; ++k) h += g[k] * ce_w2[(size_t)tid*kHID + k];
    H2vec[tid] = h;
  }
}

// ---------- H3[i,d] = mean(tf[0..i, d]) ----------
__global__ void k_h3(const float* __restrict__ tf, float* __restrict__ H3)
{
  __shared__ float s[kN];
  int d = blockIdx.x, i = threadIdx.x; // block 512
  s[i] = tf[(size_t)i*kHD + d];
  __syncthreads();
  for (int off = 1; off < kN; off <<= 1){
    float t = (i >= off) ? s[i-off] : 0.0f;
    __syncthreads();
    s[i] += t;
    __syncthreads();
  }
  H3[(size_t)i*kHD + d] = s[i] / (float)(i+1);
}

// ---------- first two neighbors per row ----------
__global__ void k_pairsel(const int* __restrict__ adj, int* __restrict__ nbr)
{
  int i = blockIdx.x * blockDim.x + threadIdx.x; // 512 threads total
  int j0 = -1, j1 = -1;
  for (int j = 0; j < kN; ++j){
    if (adj[(size_t)i*kN + j] != 0){
      if (j0 < 0) j0 = j;
      else { j1 = j; break; }
    }
  }
  if (j1 < 0) j0 = -1;
  nbr[2*i] = j0; nbr[2*i+1] = j1;
}

// ---------- Xp = [V | n0 | n1] (fp32, gathered) ----------
__global__ void k_packxp(const float* __restrict__ Vf, const int* __restrict__ nbr,
                         float* __restrict__ Xp)
{
  int i = blockIdx.x, k = threadIdx.x; // block 256
  int j0 = nbr[2*i], j1 = nbr[2*i+1];
  Xp[(size_t)i*768 + k]       = Vf[(size_t)i*kIN + k];
  Xp[(size_t)i*768 + 256 + k] = (j0 >= 0) ? Vf[(size_t)j0*kIN + k] : 0.0f;
  Xp[(size_t)i*768 + 512 + k] = (j1 >= 0) ? Vf[(size_t)j1*kIN + k] : 0.0f;
}

// ---------- H4v = colsum(cf) ----------
__global__ void k_h4(const float* __restrict__ cf, float* __restrict__ H4v)
{
  int d = threadIdx.x; // block 64, single block
  float a = 0.f;
  for (int i = 0; i < kN; ++i) a += cf[(size_t)i*kHD + d];
  H4v[d] = a;
}

// ---------- out2 = [H1 | H2vec | H3 | H4col] @ W2^T (ld 385) ----------
__global__ void k_out2(const float* __restrict__ H1, const float* __restrict__ H2vec,
                       const float* __restrict__ H3, const float* __restrict__ H4v,
                       const float* __restrict__ W2, float* __restrict__ out2)
{
  __shared__ float h1r[kHID];
  __shared__ float h3r[kHD];
  __shared__ float h2v[kHD];
  __shared__ float h4s[1];
  int i = blockIdx.x, o = threadIdx.x; // block 256
  h1r[o] = H1[(size_t)i*kHID + o];
  if (o < kHD){ h3r[o] = H3[(size_t)i*kHD + o]; h2v[o] = H2vec[o]; }
  if (o == 0) h4s[0] = (i < kHD) ? H4v[i] : 0.0f;
  __syncthreads();
  const float* wr = W2 + (size_t)o * 385;
  float acc = 0.f;
  for (int k = 0; k < kHID; ++k) acc += h1r[k] * wr[k];
  for (int d = 0; d < kHD; ++d)  acc += h2v[d] * wr[256+d];
  for (int d = 0; d < kHD; ++d)  acc += h3r[d] * wr[320+d];
  acc += h4s[0] * wr[384];
  out2[(size_t)i*kOUT + o] = acc;
}

// ---------- out = elu(layernorm(out2 @ op_w^T + op_b)), store per dtype flag ----------
__global__ void k_final(const float* __restrict__ out2, const float* __restrict__ op_w,
                        const float* __restrict__ op_b, const float* __restrict__ ln_g,
                        const float* __restrict__ ln_b, const int* __restrict__ flag,
                        void* __restrict__ out)
{
  __shared__ float row[kOUT];
  __shared__ float red[8];
  int i = blockIdx.x, o = threadIdx.x; // block 256
  row[o] = out2[(size_t)i*kOUT + o];
  __syncthreads();
  const float4* wr = (const float4*)(op_w + (size_t)o * kOUT);
  float acc = op_b[o];
  for (int kb = 0; kb < kOUT; kb += 4){
    float4 q = *wr++;
    acc += row[kb+0]*q.x + row[kb+1]*q.y + row[kb+2]*q.z + row[kb+3]*q.w;
  }
  float mu = blk_red(acc, red, false) * (1.0f/kOUT);
  float dv = acc - mu;
  float var = blk_red(dv*dv, red, false) * (1.0f/kOUT);
  float y = dv * rsqrtf(var + 1e-5f) * ln_g[o] + ln_b[o];
  y = (y > 0.f) ? y : expm1f(y);
  if (*flag) ((float*)out)[(size_t)i*kOUT + o] = y;
  else       ((u16*)out)[(size_t)i*kOUT + o]   = f2us(y);
}

extern "C" void kernel_launch(void* const* d_in, const int* in_sizes, int n_in,
                              void* d_out, int out_size, void* d_ws, size_t ws_size,
                              hipStream_t stream)
{
  const void* V     = d_in[0];
  const int*  adj   = (const int*)d_in[1];
  const void* prev  = d_in[2];
  const void* W1    = d_in[3];
  // d_in[4] = sa0 : dead (row-shift invariant softmax)
  const void* sa1   = d_in[5];
  const void* ce_w1 = d_in[6];
  const void* ce_b1 = d_in[7];
  const void* ce_w2 = d_in[8];
  const void* ce_b2 = d_in[9];
  const void* ca0   = d_in[10];
  const void* ca1   = d_in[11];
  const void* te_w1 = d_in[12];
  const void* te_b1 = d_in[13];
  const void* te_w2 = d_in[14];
  const void* te_b2 = d_in[15];
  // d_in[16,17] = ta0,ta1 : dead (uniform causal softmax)
  const void* pe_w1 = d_in[18];
  const void* pe_b1 = d_in[19];
  const void* pe_w2 = d_in[20];
  const void* pe_b2 = d_in[21];
  // d_in[22,23] = pa0,pa1 : dead
  const void* W2    = d_in[24];
  const void* op_w  = d_in[25];
  const void* op_b  = d_in[26];
  const void* ln_g  = d_in[27];
  const void* ln_b  = d_in[28];

  // ---- workspace layout (floats). All segment sizes multiple of 16 floats. ----
  float* ws  = (float*)d_ws;
  int*  flag = (int*)ws;               // 16 floats reserved
  float* p   = ws + 16;
  float* Vf   = p; p += 131072;
  float* prevf= p; p += 131072;
  float* W1f  = p; p += 65536;
  float* sa1f = p; p += 256;
  float* cw1f = p; p += 131072;
  float* cb1f = p; p += 256;
  float* cw2f = p; p += 16384;
  float* cb2f = p; p += 64;
  float* ca0f = p; p += 64;
  float* ca1f = p; p += 64;
  float* tw1f = p; p += 131072;
  float* tb1f = p; p += 256;
  float* tw2f = p; p += 16384;
  float* tb2f = p; p += 64;
  float* pw1f = p; p += 196608;
  float* pb1f = p; p += 256;
  float* pw2f = p; p += 16384;
  float* pb2f = p; p += 64;
  float* W2f  = p; p += 98560;
  float* opwf = p; p += 65536;
  float* opbf = p; p += 256;
  float* lngf = p; p += 256;
  float* lnbf = p; p += 256;
  float* Wh1      = p; p += 131072;
  float* e1v      = p; p += 512;
  float* H1       = p; p += 131072;
  float* Am       = p; p += 131072;
  float* Bm       = p; p += 131072;
  float* uvec     = p; p += 256;
  float* beta     = p; p += 16;
  float* s2       = p; p += 262144;
  float* rowmax   = p; p += 512;
  float* rowZ     = p; p += 512;
  float* MZ       = p; p += 16;
  float* gpart    = p; p += 131072;
  float* H2vec    = p; p += 64;
  float* hidden_t = p; p += 131072;
  float* tfm      = p; p += 32768;
  float* H3       = p; p += 32768;
  int*   nbr      = (int*)p; p += 1024;
  float* Xp       = p; p += 393216;
  float* hidden_p = p; p += 131072;
  float* cfm      = p; p += 32768;
  float* H4v      = p; p += 64;
  float* out2     = p; p += 131072;

  // ---- dtype probe + input widening ----
  k_probe<<<1, 256, 0, stream>>>((const unsigned int*)V, flag);
  ConvArgs ca;
  const void* srcs[23] = {V, prev, W1, sa1, ce_w1, ce_b1, ce_w2, ce_b2, ca0, ca1,
                          te_w1, te_b1, te_w2, te_b2, pe_w1, pe_b1, pe_w2, pe_b2,
                          W2, op_w, op_b, ln_g, ln_b};
  float* dsts[23] = {Vf, prevf, W1f, sa1f, cw1f, cb1f, cw2f, cb2f, ca0f, ca1f,
                     tw1f, tb1f, tw2f, tb2f, pw1f, pb1f, pw2f, pb2f,
                     W2f, opwf, opbf, lngf, lnbf};
  int ns[23] = {131072, 131072, 65536, 256, 131072, 256, 16384, 64, 64, 64,
                131072, 256, 16384, 64, 196608, 256, 16384, 64,
                98560, 65536, 256, 256, 256};
  for (int s = 0; s < 23; ++s){ ca.src[s] = srcs[s]; ca.dst[s] = dsts[s]; ca.n[s] = ns[s]; }
  k_convert_all<<<512, 256, 0, stream>>>(ca, flag);

  // ---- pair-branch input prep (independent of GEMMs) ----
  k_pairsel<<<2, 256, 0, stream>>>(adj, nbr);
  k_packxp<<<kN, 256, 0, stream>>>(Vf, nbr, Xp);

  // ---- GEMM batch 1: Wh1 / Am / Bm  (all X=Vf, K=256, Nout=256) ----
  {
    GArgs g{};
    g.s[0] = {Vf, Vf, W1f,        nullptr, Wh1, 256, 256, 256, 0, 256};
    g.s[1] = {Vf, Vf, cw1f,       nullptr, Am,  256, 256, 512, 0, 256};
    g.s[2] = {Vf, Vf, cw1f + 256, nullptr, Bm,  256, 256, 512, 0, 256};
    k_gemm_t<<<dim3(32, 3), 256, 0, stream>>>(g);
  }
  // ---- GEMM batch 2: hidden_t (K=512) / hidden_p (K=768), Nout=256, relu ----
  {
    GArgs g{};
    g.s[0] = {Vf, prevf, tw1f, tb1f, hidden_t, 256, 512, 512, 1, 256};
    g.s[1] = {Xp, Xp,    pw1f, pb1f, hidden_p, 768, 768, 768, 1, 256};
    g.s[2] = g.s[0]; // unused (gridDim.y = 2)
    k_gemm_t<<<dim3(32, 2), 256, 0, stream>>>(g);
  }
  // ---- GEMM batch 3: tfm / cfm (K=256, Nout=64) ----
  {
    GArgs g{};
    g.s[0] = {hidden_t, hidden_t, tw2f, tb2f, tfm, 256, 256, 256, 0, 64};
    g.s[1] = {hidden_p, hidden_p, pw2f, pb2f, cfm, 256, 256, 256, 0, 64};
    g.s[2] = g.s[0]; // unused
    k_gemm_t<<<dim3(8, 2), 256, 0, stream>>>(g);
  }

  // --- GAT branch (H1) ---
  k_e1<<<kN, 64, 0, stream>>>(Wh1, sa1f, e1v);
  k_h1<<<kN/4, 256, 0, stream>>>(adj, e1v, Wh1, H1);

  // --- cross-edge branch (H2) ---
  k_ub<<<1, 256, 0, stream>>>(cw2f, cb2f, ca0f, ca1f, uvec, beta);
  k_s2<<<kN/4, 256, 0, stream>>>(Am, Bm, cb1f, uvec, beta, s2, rowmax, rowZ);
  k_mz<<<1, 256, 0, stream>>>(rowmax, rowZ, MZ);
  k_gpart<<<kN/4, 256, 0, stream>>>(Am, Bm, cb1f, s2, MZ, gpart);
  k_h2<<<1, 256, 0, stream>>>(gpart, cw2f, cb2f, H2vec);

  // --- temporal branch (H3) ---
  k_h3<<<kHD, kN, 0, stream>>>(tfm, H3);

  // --- pair branch (H4) ---
  k_h4<<<1, 64, 0, stream>>>(cfm, H4v);

  // --- combine + output head ---
  k_out2<<<kN, 256, 0, stream>>>(H1, H2vec, H3, H4v, W2f, out2);
  k_final<<<kN, 256, 0, stream>>>(out2, opwf, opbf, lngf, lnbf, flag, d_out);
}

// Round 2
// 354.220 us; speedup vs baseline: 1.2497x; 1.0568x over previous
//
#include <hip/hip_runtime.h>

typedef unsigned short u16;

constexpr int kN   = 512;
constexpr int kIN  = 256;
constexpr int kHID = 256;
constexpr int kHD  = 64;
constexpr int kOUT = 256;

// ---------- bf16 helpers ----------
__device__ __forceinline__ float us2f(u16 u){
  union { unsigned int i; float f; } c; c.i = ((unsigned int)u) << 16; return c.f;
}
__device__ __forceinline__ u16 f2us(float f){
  union { float f; unsigned int i; } c; c.f = f;
  unsigned int r = c.i + 0x7fff + ((c.i >> 16) & 1);
  return (u16)(r >> 16);
}

// ---------- dtype probe: decide bf16 vs fp32 input buffers ----------
__global__ void k_probe(const unsigned int* __restrict__ V, int* __restrict__ flag){
  __shared__ int cnt;
  if (threadIdx.x == 0) cnt = 0;
  __syncthreads();
  int c = 0;
  for (int k = threadIdx.x; k < 4096; k += 256){
    float x = us2f((u16)(V[k] & 0xffffu));
    float ax = fabsf(x);
    if (!(ax <= 32.0f)) c++;   // also catches NaN/Inf bit patterns
  }
  atomicAdd(&cnt, c);
  __syncthreads();
  if (threadIdx.x == 0) *flag = (cnt > 64) ? 1 : 0;
}

// ---------- convert all float tensors to fp32 in workspace ----------
struct ConvArgs { const void* src[23]; float* dst[23]; int n[23]; };

__global__ void k_convert_all(ConvArgs a, const int* __restrict__ flag){
  bool f32 = (*flag != 0);
  int stride = gridDim.x * blockDim.x;
  int t = blockIdx.x * blockDim.x + threadIdx.x;
  for (int s = 0; s < 23; ++s){
    int n = a.n[s];
    const float* sf = (const float*)a.src[s];
    const u16*   sb = (const u16*)a.src[s];
    float* d = a.dst[s];
    for (int i = t; i < n; i += stride)
      d[i] = f32 ? sf[i] : us2f(sb[i]);
  }
}

// ---------- block reduction (blockDim multiple of 64, <=512) ----------
__device__ __forceinline__ float blk_red(float v, float* tmp, bool isMax){
  int lane = threadIdx.x & 63, wv = threadIdx.x >> 6;
  #pragma unroll
  for (int o = 32; o > 0; o >>= 1){
    float t = __shfl_down(v, o, 64);
    v = isMax ? fmaxf(v, t) : (v + t);
  }
  __syncthreads();
  if (lane == 0) tmp[wv] = v;
  __syncthreads();
  int nw = (blockDim.x + 63) >> 6;
  float r = tmp[0];
  for (int i = 1; i < nw; ++i) r = isMax ? fmaxf(r, tmp[i]) : (r + tmp[i]);
  return r;
}

// ================== tiled multi-GEMM ==================
struct GSeg {
  const float* Xa; const float* Xb; const float* W; const float* bias; float* C;
  int K1, Ktot, ldw, act, Nout;
};
struct GArgs { GSeg s[3]; };

__global__ __launch_bounds__(256) void k_gemm_t(GArgs ga)
{
  const GSeg sg = ga.s[blockIdx.y];
  const int tm = blockIdx.x & 7;
  const int tn = blockIdx.x >> 3;
  const int i0 = tm << 6;
  const int n0 = tn << 6;
  const int tid = threadIdx.x;

  __shared__ float Xs[32][68];
  __shared__ float Ws[32][68];

  const int rg = tid >> 4;
  const int cg = tid & 15;
  const int r0 = rg << 2;
  const int c0 = cg << 2;

  const int lrow = tid >> 3;
  const int lk   = (tid & 7) << 2;

  const int K1 = sg.K1;
  const int K2 = sg.Ktot - sg.K1;

  float acc[4][4] = {};

  const int nkt = sg.Ktot >> 5;
  for (int t = 0; t < nkt; ++t){
    const int kt = t << 5;
    if (t) __syncthreads();
    const int kg = kt + lk;
    #pragma unroll
    for (int ph = 0; ph < 2; ++ph){
      const int row = lrow + (ph << 5);
      const float* xsrc = (kg < K1)
          ? (sg.Xa + (size_t)(i0 + row) * K1 + kg)
          : (sg.Xb + (size_t)(i0 + row) * K2 + (kg - K1));
      const float4 xv = *(const float4*)xsrc;
      Xs[lk+0][row] = xv.x; Xs[lk+1][row] = xv.y;
      Xs[lk+2][row] = xv.z; Xs[lk+3][row] = xv.w;
      const float4 wv = *(const float4*)(sg.W + (size_t)(n0 + row) * sg.ldw + kg);
      Ws[lk+0][row] = wv.x; Ws[lk+1][row] = wv.y;
      Ws[lk+2][row] = wv.z; Ws[lk+3][row] = wv.w;
    }
    __syncthreads();
    #pragma unroll
    for (int kk = 0; kk < 32; ++kk){
      const float4 a = *(const float4*)&Xs[kk][r0];
      const float4 b = *(const float4*)&Ws[kk][c0];
      acc[0][0] += a.x*b.x; acc[0][1] += a.x*b.y; acc[0][2] += a.x*b.z; acc[0][3] += a.x*b.w;
      acc[1][0] += a.y*b.x; acc[1][1] += a.y*b.y; acc[1][2] += a.y*b.z; acc[1][3] += a.y*b.w;
      acc[2][0] += a.z*b.x; acc[2][1] += a.z*b.y; acc[2][2] += a.z*b.z; acc[2][3] += a.z*b.w;
      acc[3][0] += a.w*b.x; acc[3][1] += a.w*b.y; acc[3][2] += a.w*b.z; acc[3][3] += a.w*b.w;
    }
  }

  float bb[4] = {0.f, 0.f, 0.f, 0.f};
  if (sg.bias){
    bb[0] = sg.bias[n0+c0+0]; bb[1] = sg.bias[n0+c0+1];
    bb[2] = sg.bias[n0+c0+2]; bb[3] = sg.bias[n0+c0+3];
  }
  #pragma unroll
  for (int ri = 0; ri < 4; ++ri){
    float4 v;
    v.x = acc[ri][0] + bb[0];
    v.y = acc[ri][1] + bb[1];
    v.z = acc[ri][2] + bb[2];
    v.w = acc[ri][3] + bb[3];
    if (sg.act){
      v.x = fmaxf(v.x, 0.f); v.y = fmaxf(v.y, 0.f);
      v.z = fmaxf(v.z, 0.f); v.w = fmaxf(v.w, 0.f);
    }
    *(float4*)(sg.C + (size_t)(i0 + r0 + ri) * sg.Nout + (n0 + c0)) = v;
  }
}

// ---------- e1[j] = Wh1[j,:] . sa1 ----------
__global__ void k_e1(const float* __restrict__ Wh1, const float* __restrict__ sa1,
                     float* __restrict__ e1)
{
  int i = blockIdx.x, lane = threadIdx.x; // block 64
  float a = 0.f;
  for (int k = lane; k < kHID; k += 64) a += Wh1[(size_t)i*kHID + k] * sa1[k];
  #pragma unroll
  for (int o = 32; o > 0; o >>= 1) a += __shfl_down(a, o, 64);
  if (lane == 0) e1[i] = a;
}

// ---------- per-row masked softmax stats for H1 ----------
__global__ void k_h1stats(const int* __restrict__ adj, const float* __restrict__ e1,
                          float* __restrict__ minv, float* __restrict__ invz)
{
  __shared__ float red[8];
  int i = blockIdx.x, tid = threadIdx.x; // grid 512, block 256
  int m0 = adj[(size_t)i*kN + tid];
  int m1 = adj[(size_t)i*kN + tid + 256];
  float ea = e1[tid], eb = e1[tid+256];
  float v0 = m0 ? ea : -1e30f;
  float v1 = m1 ? eb : -1e30f;
  float m = blk_red(fmaxf(v0, v1), red, true);
  float z = blk_red((m0 ? expf(ea-m) : 0.f) + (m1 ? expf(eb-m) : 0.f), red, false);
  if (tid == 0){ minv[i] = m; invz[i] = 1.0f / z; }
}

// ---------- H1 partials over j-tiles: grid (128, 8) ----------
__global__ __launch_bounds__(256) void k_h1p(const int* __restrict__ adj, const float* __restrict__ e1,
                      const float* __restrict__ minv, const float* __restrict__ invz,
                      const float* __restrict__ Wh1, float* __restrict__ H1p)
{
  __shared__ float w[4][64];
  int i0 = blockIdx.x * 4, jt = blockIdx.y, j0 = jt * 64;
  int tid = threadIdx.x;
  {
    int r = tid >> 6, jj = tid & 63;
    int j = j0 + jj;
    w[r][jj] = adj[(size_t)(i0+r)*kN + j]
             ? expf(e1[j] - minv[i0+r]) * invz[i0+r] : 0.f;
  }
  __syncthreads();
  float a0=0,a1=0,a2=0,a3=0;
  #pragma unroll 4
  for (int jj = 0; jj < 64; ++jj){
    float wh = Wh1[(size_t)(j0+jj)*kHID + tid];
    a0 += w[0][jj]*wh; a1 += w[1][jj]*wh; a2 += w[2][jj]*wh; a3 += w[3][jj]*wh;
  }
  size_t base = ((size_t)jt*kN + i0)*kHID + tid;
  H1p[base]          = a0;
  H1p[base + kHID]   = a1;
  H1p[base + 2*kHID] = a2;
  H1p[base + 3*kHID] = a3;
}

// ---------- H1 reduce over 8 j-tiles ----------
__global__ void k_h1r(const float* __restrict__ H1p, float* __restrict__ H1)
{
  int i = blockIdx.x, tid = threadIdx.x; // grid 512, block 256
  float s = 0.f;
  #pragma unroll
  for (int jt = 0; jt < 8; ++jt)
    s += H1p[((size_t)jt*kN + i)*kHID + tid];
  H1[(size_t)i*kHID + tid] = s;
}

// ---------- u = ce_w2^T (ca0+ca1), beta = ce_b2 . (ca0+ca1) ----------
__global__ void k_ub(const float* __restrict__ ce_w2, const float* __restrict__ ce_b2,
                     const float* __restrict__ ca0, const float* __restrict__ ca1,
                     float* __restrict__ u, float* __restrict__ beta)
{
  __shared__ float c[kHD];
  int tid = threadIdx.x; // 256
  if (tid < kHD) c[tid] = ca0[tid] + ca1[tid];
  __syncthreads();
  float a = 0.f;
  for (int d = 0; d < kHD; ++d) a += ce_w2[(size_t)d*kHID + tid] * c[d];
  u[tid] = a;
  if (tid == 0){
    float b = 0.f;
    for (int d = 0; d < kHD; ++d) b += ce_b2[d] * c[d];
    *beta = b;
  }
}

// ---------- s2 pair scores: grid (128, 8), thread owns one (i,j) pair ----------
__global__ __launch_bounds__(256) void k_s2(const float* __restrict__ A, const float* __restrict__ Bm,
                     const float* __restrict__ ce_b1,
                     const float* __restrict__ u, const float* __restrict__ beta,
                     float* __restrict__ s2, float* __restrict__ maxp,
                     float* __restrict__ zp)
{
  __shared__ __align__(16) float aib[4][kHID];
  __shared__ __align__(16) float uu[kHID];
  int i0 = blockIdx.x * 4, j0 = blockIdx.y * 64;
  int tid = threadIdx.x;
  int wv = tid >> 6, lane = tid & 63;
  uu[tid] = u[tid];
  float b1v = ce_b1[tid];
  #pragma unroll
  for (int r = 0; r < 4; ++r) aib[r][tid] = A[(size_t)(i0+r)*kHID + tid] + b1v;
  __syncthreads();
  int i = i0 + wv, j = j0 + lane;
  const float4* bp = (const float4*)(Bm + (size_t)j*kHID);
  float acc = *beta;
  #pragma unroll 8
  for (int k4 = 0; k4 < kHID/4; ++k4){
    float4 b = bp[k4];
    float4 a4 = *(const float4*)&aib[wv][k4*4];
    float4 u4 = *(const float4*)&uu[k4*4];
    acc += fmaxf(a4.x+b.x,0.f)*u4.x + fmaxf(a4.y+b.y,0.f)*u4.y
         + fmaxf(a4.z+b.z,0.f)*u4.z + fmaxf(a4.w+b.w,0.f)*u4.w;
  }
  if (j == i) acc = -1e30f;
  s2[(size_t)i*kN + j] = acc;
  // per-wave (64-j segment) softmax partials -> global M,Z reduction
  float m = acc;
  #pragma unroll
  for (int o = 32; o > 0; o >>= 1) m = fmaxf(m, __shfl_down(m, o, 64));
  m = __shfl(m, 0, 64);
  float e = expf(acc - m);
  #pragma unroll
  for (int o = 32; o > 0; o >>= 1) e += __shfl_down(e, o, 64);
  if (lane == 0){
    int pb = (blockIdx.y * gridDim.x + blockIdx.x) * 4 + wv;
    maxp[pb] = m; zp[pb] = e;
  }
}

// ---------- global softmax stats over 4096 partials; zero g ----------
__global__ void k_mz(const float* __restrict__ maxp, const float* __restrict__ zp,
                     float* __restrict__ MZ, float* __restrict__ g)
{
  __shared__ float red[8];
  int tid = threadIdx.x; // 256
  float m = -1e30f;
  #pragma unroll
  for (int r = 0; r < 16; ++r) m = fmaxf(m, maxp[tid + 256*r]);
  m = blk_red(m, red, true);
  float z = 0.f;
  #pragma unroll
  for (int r = 0; r < 16; ++r) z += zp[tid + 256*r] * expf(maxp[tid + 256*r] - m);
  z = blk_red(z, red, false);
  if (tid == 0){ MZ[0] = m; MZ[1] = z; }
  g[tid] = 0.f;
}

// ---------- g[k] += sum over 16x16 pair tile of a2[i,j]*relu(A_i[k]+B_j[k]+b1[k]) ----------
__global__ __launch_bounds__(256) void k_gpart(const float* __restrict__ A, const float* __restrict__ Bm,
                        const float* __restrict__ ce_b1,
                        const float* __restrict__ s2, const float* __restrict__ MZ,
                        float* __restrict__ g)
{
  __shared__ float wt[16][16];
  int i0 = blockIdx.x * 16, j0 = blockIdx.y * 16;
  int tid = threadIdx.x;
  float M = MZ[0], invZ = 1.0f / MZ[1];
  {
    int r = tid >> 4, c = tid & 15;
    wt[r][c] = expf(s2[(size_t)(i0+r)*kN + (j0+c)] - M) * invZ;
  }
  float b1v = ce_b1[tid];
  float aib[16];
  #pragma unroll
  for (int r = 0; r < 16; ++r) aib[r] = A[(size_t)(i0+r)*kHID + tid] + b1v;
  __syncthreads();
  float acc = 0.f;
  for (int j = 0; j < 16; ++j){
    float bj = Bm[(size_t)(j0+j)*kHID + tid];
    #pragma unroll
    for (int r = 0; r < 16; ++r)
      acc += wt[r][j] * fmaxf(aib[r] + bj, 0.f);
  }
  atomicAdd(&g[tid], acc);
}

// ---------- H2vec = g @ ce_w2^T + ce_b2 ----------
__global__ void k_h2(const float* __restrict__ g, const float* __restrict__ ce_w2,
                     const float* __restrict__ ce_b2, float* __restrict__ H2vec)
{
  __shared__ float gs[kHID];
  __shared__ float part[kHD][4];
  int tid = threadIdx.x; // 256, single block
  gs[tid] = g[tid];
  __syncthreads();
  int d = tid >> 2, q = tid & 3;
  float a = 0.f;
  for (int kk = 0; kk < 64; ++kk){
    int k = q*64 + kk;
    a += gs[k] * ce_w2[(size_t)d*kHID + k];
  }
  part[d][q] = a;
  __syncthreads();
  if (tid < kHD)
    H2vec[tid] = ce_b2[tid] + part[tid][0] + part[tid][1] + part[tid][2] + part[tid][3];
}

// ---------- H3[i,d] = mean(tf[0..i, d]) ----------
__global__ void k_h3(const float* __restrict__ tf, float* __restrict__ H3)
{
  __shared__ float s[kN];
  int d = blockIdx.x, i = threadIdx.x; // block 512
  s[i] = tf[(size_t)i*kHD + d];
  __syncthreads();
  for (int off = 1; off < kN; off <<= 1){
    float t = (i >= off) ? s[i-off] : 0.0f;
    __syncthreads();
    s[i] += t;
    __syncthreads();
  }
  H3[(size_t)i*kHD + d] = s[i] / (float)(i+1);
}

// ---------- first two neighbors per row ----------
__global__ void k_pairsel(const int* __restrict__ adj, int* __restrict__ nbr)
{
  int i = blockIdx.x * blockDim.x + threadIdx.x; // 512 threads total
  int j0 = -1, j1 = -1;
  for (int j = 0; j < kN; ++j){
    if (adj[(size_t)i*kN + j] != 0){
      if (j0 < 0) j0 = j;
      else { j1 = j; break; }
    }
  }
  if (j1 < 0) j0 = -1;
  nbr[2*i] = j0; nbr[2*i+1] = j1;
}

// ---------- Xp = [V | n0 | n1] (fp32, gathered) ----------
__global__ void k_packxp(const float* __restrict__ Vf, const int* __restrict__ nbr,
                         float* __restrict__ Xp)
{
  int i = blockIdx.x, k = threadIdx.x; // block 256
  int j0 = nbr[2*i], j1 = nbr[2*i+1];
  Xp[(size_t)i*768 + k]       = Vf[(size_t)i*kIN + k];
  Xp[(size_t)i*768 + 256 + k] = (j0 >= 0) ? Vf[(size_t)j0*kIN + k] : 0.0f;
  Xp[(size_t)i*768 + 512 + k] = (j1 >= 0) ? Vf[(size_t)j1*kIN + k] : 0.0f;
}

// ---------- H4v = colsum(cf) ----------
__global__ void k_h4(const float* __restrict__ cf, float* __restrict__ H4v)
{
  int d = threadIdx.x; // block 64, single block
  float a = 0.f;
  for (int i = 0; i < kN; ++i) a += cf[(size_t)i*kHD + d];
  H4v[d] = a;
}

// ---------- out2 = [H1 | H2vec | H3 | H4col] @ W2^T (ld 385) ----------
__global__ void k_out2(const float* __restrict__ H1, const float* __restrict__ H2vec,
                       const float* __restrict__ H3, const float* __restrict__ H4v,
                       const float* __restrict__ W2, float* __restrict__ out2)
{
  __shared__ float h1r[kHID];
  __shared__ float h3r[kHD];
  __shared__ float h2v[kHD];
  __shared__ float h4s[1];
  int i = blockIdx.x, o = threadIdx.x; // block 256
  h1r[o] = H1[(size_t)i*kHID + o];
  if (o < kHD){ h3r[o] = H3[(size_t)i*kHD + o]; h2v[o] = H2vec[o]; }
  if (o == 0) h4s[0] = (i < kHD) ? H4v[i] : 0.0f;
  __syncthreads();
  const float* wr = W2 + (size_t)o * 385;
  float acc = 0.f;
  for (int k = 0; k < kHID; ++k) acc += h1r[k] * wr[k];
  for (int d = 0; d < kHD; ++d)  acc += h2v[d] * wr[256+d];
  for (int d = 0; d < kHD; ++d)  acc += h3r[d] * wr[320+d];
  acc += h4s[0] * wr[384];
  out2[(size_t)i*kOUT + o] = acc;
}

// ---------- out = elu(layernorm(out2 @ op_w^T + op_b)), store per dtype flag ----------
__global__ void k_final(const float* __restrict__ out2, const float* __restrict__ op_w,
                        const float* __restrict__ op_b, const float* __restrict__ ln_g,
                        const float* __restrict__ ln_b, const int* __restrict__ flag,
                        void* __restrict__ out)
{
  __shared__ float row[kOUT];
  __shared__ float red[8];
  int i = blockIdx.x, o = threadIdx.x; // block 256
  row[o] = out2[(size_t)i*kOUT + o];
  __syncthreads();
  const float4* wr = (const float4*)(op_w + (size_t)o * kOUT);
  float acc = op_b[o];
  for (int kb = 0; kb < kOUT; kb += 4){
    float4 q = *wr++;
    acc += row[kb+0]*q.x + row[kb+1]*q.y + row[kb+2]*q.z + row[kb+3]*q.w;
  }
  float mu = blk_red(acc, red, false) * (1.0f/kOUT);
  float dv = acc - mu;
  float var = blk_red(dv*dv, red, false) * (1.0f/kOUT);
  float y = dv * rsqrtf(var + 1e-5f) * ln_g[o] + ln_b[o];
  y = (y > 0.f) ? y : expm1f(y);
  if (*flag) ((float*)out)[(size_t)i*kOUT + o] = y;
  else       ((u16*)out)[(size_t)i*kOUT + o]   = f2us(y);
}

extern "C" void kernel_launch(void* const* d_in, const int* in_sizes, int n_in,
                              void* d_out, int out_size, void* d_ws, size_t ws_size,
                              hipStream_t stream)
{
  const void* V     = d_in[0];
  const int*  adj   = (const int*)d_in[1];
  const void* prev  = d_in[2];
  const void* W1    = d_in[3];
  // d_in[4] = sa0 : dead (row-shift invariant softmax)
  const void* sa1   = d_in[5];
  const void* ce_w1 = d_in[6];
  const void* ce_b1 = d_in[7];
  const void* ce_w2 = d_in[8];
  const void* ce_b2 = d_in[9];
  const void* ca0   = d_in[10];
  const void* ca1   = d_in[11];
  const void* te_w1 = d_in[12];
  const void* te_b1 = d_in[13];
  const void* te_w2 = d_in[14];
  const void* te_b2 = d_in[15];
  // d_in[16,17] = ta0,ta1 : dead (uniform causal softmax)
  const void* pe_w1 = d_in[18];
  const void* pe_b1 = d_in[19];
  const void* pe_w2 = d_in[20];
  const void* pe_b2 = d_in[21];
  // d_in[22,23] = pa0,pa1 : dead
  const void* W2    = d_in[24];
  const void* op_w  = d_in[25];
  const void* op_b  = d_in[26];
  const void* ln_g  = d_in[27];
  const void* ln_b  = d_in[28];

  // ---- workspace layout (floats) ----
  float* ws  = (float*)d_ws;
  int*  flag = (int*)ws;               // 16 floats reserved
  float* p   = ws + 16;
  float* Vf   = p; p += 131072;
  float* prevf= p; p += 131072;
  float* W1f  = p; p += 65536;
  float* sa1f = p; p += 256;
  float* cw1f = p; p += 131072;
  float* cb1f = p; p += 256;
  float* cw2f = p; p += 16384;
  float* cb2f = p; p += 64;
  float* ca0f = p; p += 64;
  float* ca1f = p; p += 64;
  float* tw1f = p; p += 131072;
  float* tb1f = p; p += 256;
  float* tw2f = p; p += 16384;
  float* tb2f = p; p += 64;
  float* pw1f = p; p += 196608;
  float* pb1f = p; p += 256;
  float* pw2f = p; p += 16384;
  float* pb2f = p; p += 64;
  float* W2f  = p; p += 98560;
  float* opwf = p; p += 65536;
  float* opbf = p; p += 256;
  float* lngf = p; p += 256;
  float* lnbf = p; p += 256;
  float* Wh1      = p; p += 131072;
  float* e1v      = p; p += 512;
  float* minv     = p; p += 512;
  float* invzv    = p; p += 512;
  float* H1p      = p; p += 1048576;   // 8 x 512 x 256 partials
  float* H1       = p; p += 131072;
  float* Am       = p; p += 131072;
  float* Bm       = p; p += 131072;
  float* uvec     = p; p += 256;
  float* beta     = p; p += 16;
  float* s2       = p; p += 262144;
  float* maxp     = p; p += 4096;
  float* zpart    = p; p += 4096;
  float* MZ       = p; p += 16;
  float* gsum     = p; p += 256;
  float* H2vec    = p; p += 64;
  float* hidden_t = p; p += 131072;
  float* tfm      = p; p += 32768;
  float* H3       = p; p += 32768;
  int*   nbr      = (int*)p; p += 1024;
  float* Xp       = p; p += 393216;
  float* hidden_p = p; p += 131072;
  float* cfm      = p; p += 32768;
  float* H4v      = p; p += 64;
  float* out2     = p; p += 131072;

  // ---- dtype probe + input widening ----
  k_probe<<<1, 256, 0, stream>>>((const unsigned int*)V, flag);
  ConvArgs ca;
  const void* srcs[23] = {V, prev, W1, sa1, ce_w1, ce_b1, ce_w2, ce_b2, ca0, ca1,
                          te_w1, te_b1, te_w2, te_b2, pe_w1, pe_b1, pe_w2, pe_b2,
                          W2, op_w, op_b, ln_g, ln_b};
  float* dsts[23] = {Vf, prevf, W1f, sa1f, cw1f, cb1f, cw2f, cb2f, ca0f, ca1f,
                     tw1f, tb1f, tw2f, tb2f, pw1f, pb1f, pw2f, pb2f,
                     W2f, opwf, opbf, lngf, lnbf};
  int ns[23] = {131072, 131072, 65536, 256, 131072, 256, 16384, 64, 64, 64,
                131072, 256, 16384, 64, 196608, 256, 16384, 64,
                98560, 65536, 256, 256, 256};
  for (int s = 0; s < 23; ++s){ ca.src[s] = srcs[s]; ca.dst[s] = dsts[s]; ca.n[s] = ns[s]; }
  k_convert_all<<<512, 256, 0, stream>>>(ca, flag);

  // ---- pair-branch input prep ----
  k_pairsel<<<2, 256, 0, stream>>>(adj, nbr);
  k_packxp<<<kN, 256, 0, stream>>>(Vf, nbr, Xp);

  // ---- GEMM batch 1: Wh1 / Am / Bm ----
  {
    GArgs g{};
    g.s[0] = {Vf, Vf, W1f,        nullptr, Wh1, 256, 256, 256, 0, 256};
    g.s[1] = {Vf, Vf, cw1f,       nullptr, Am,  256, 256, 512, 0, 256};
    g.s[2] = {Vf, Vf, cw1f + 256, nullptr, Bm,  256, 256, 512, 0, 256};
    k_gemm_t<<<dim3(32, 3), 256, 0, stream>>>(g);
  }
  // ---- GEMM batch 2: hidden_t / hidden_p ----
  {
    GArgs g{};
    g.s[0] = {Vf, prevf, tw1f, tb1f, hidden_t, 256, 512, 512, 1, 256};
    g.s[1] = {Xp, Xp,    pw1f, pb1f, hidden_p, 768, 768, 768, 1, 256};
    g.s[2] = g.s[0]; // unused
    k_gemm_t<<<dim3(32, 2), 256, 0, stream>>>(g);
  }
  // ---- GEMM batch 3: tfm / cfm ----
  {
    GArgs g{};
    g.s[0] = {hidden_t, hidden_t, tw2f, tb2f, tfm, 256, 256, 256, 0, 64};
    g.s[1] = {hidden_p, hidden_p, pw2f, pb2f, cfm, 256, 256, 256, 0, 64};
    g.s[2] = g.s[0]; // unused
    k_gemm_t<<<dim3(8, 2), 256, 0, stream>>>(g);
  }

  // --- GAT branch (H1) ---
  k_e1<<<kN, 64, 0, stream>>>(Wh1, sa1f, e1v);
  k_h1stats<<<kN, 256, 0, stream>>>(adj, e1v, minv, invzv);
  k_h1p<<<dim3(kN/4, 8), 256, 0, stream>>>(adj, e1v, minv, invzv, Wh1, H1p);
  k_h1r<<<kN, 256, 0, stream>>>(H1p, H1);

  // --- cross-edge branch (H2) ---
  k_ub<<<1, 256, 0, stream>>>(cw2f, cb2f, ca0f, ca1f, uvec, beta);
  k_s2<<<dim3(kN/4, 8), 256, 0, stream>>>(Am, Bm, cb1f, uvec, beta, s2, maxp, zpart);
  k_mz<<<1, 256, 0, stream>>>(maxp, zpart, MZ, gsum);
  k_gpart<<<dim3(kN/16, kN/16), 256, 0, stream>>>(Am, Bm, cb1f, s2, MZ, gsum);
  k_h2<<<1, 256, 0, stream>>>(gsum, cw2f, cb2f, H2vec);

  // --- temporal branch (H3) ---
  k_h3<<<kHD, kN, 0, stream>>>(tfm, H3);

  // --- pair branch (H4) ---
  k_h4<<<1, 64, 0, stream>>>(cfm, H4v);

  // --- combine + output head ---
  k_out2<<<kN, 256, 0, stream>>>(H1, H2vec, H3, H4v, W2f, out2);
  k_final<<<kN, 256, 0, stream>>>(out2, opwf, opbf, lngf, lnbf, flag, d_out);
}

// Round 3
// 319.574 us; speedup vs baseline: 1.3852x; 1.1084x over previous
//
#include <hip/hip_runtime.h>

typedef unsigned short u16;

constexpr int kN   = 512;
constexpr int kIN  = 256;
constexpr int kHID = 256;
constexpr int kHD  = 64;
constexpr int kOUT = 256;

// ---------- bf16 helpers ----------
__device__ __forceinline__ float us2f(u16 u){
  union { unsigned int i; float f; } c; c.i = ((unsigned int)u) << 16; return c.f;
}
__device__ __forceinline__ u16 f2us(float f){
  union { float f; unsigned int i; } c; c.f = f;
  unsigned int r = c.i + 0x7fff + ((c.i >> 16) & 1);
  return (u16)(r >> 16);
}

// ---------- dtype probe ----------
__global__ void k_probe(const unsigned int* __restrict__ V, int* __restrict__ flag){
  __shared__ int cnt;
  if (threadIdx.x == 0) cnt = 0;
  __syncthreads();
  int c = 0;
  for (int k = threadIdx.x; k < 4096; k += 256){
    float x = us2f((u16)(V[k] & 0xffffu));
    float ax = fabsf(x);
    if (!(ax <= 32.0f)) c++;
  }
  atomicAdd(&cnt, c);
  __syncthreads();
  if (threadIdx.x == 0) *flag = (cnt > 64) ? 1 : 0;
}

// ---------- convert all float tensors to fp32 ----------
struct ConvArgs { const void* src[23]; float* dst[23]; int n[23]; };

__global__ void k_convert_all(ConvArgs a, const int* __restrict__ flag){
  bool f32 = (*flag != 0);
  int stride = gridDim.x * blockDim.x;
  int t = blockIdx.x * blockDim.x + threadIdx.x;
  for (int s = 0; s < 23; ++s){
    int n = a.n[s];
    const float* sf = (const float*)a.src[s];
    const u16*   sb = (const u16*)a.src[s];
    float* d = a.dst[s];
    for (int i = t; i < n; i += stride)
      d[i] = f32 ? sf[i] : us2f(sb[i]);
  }
}

// ---------- block reduction ----------
__device__ __forceinline__ float blk_red(float v, float* tmp, bool isMax){
  int lane = threadIdx.x & 63, wv = threadIdx.x >> 6;
  #pragma unroll
  for (int o = 32; o > 0; o >>= 1){
    float t = __shfl_down(v, o, 64);
    v = isMax ? fmaxf(v, t) : (v + t);
  }
  __syncthreads();
  if (lane == 0) tmp[wv] = v;
  __syncthreads();
  int nw = (blockDim.x + 63) >> 6;
  float r = tmp[0];
  for (int i = 1; i < nw; ++i) r = isMax ? fmaxf(r, tmp[i]) : (r + tmp[i]);
  return r;
}

// ================== batched tiled GEMM v2 ==================
// C[i,n] = sum_k X[i,k] * W[n,k]   (pure partial; bias/act in reduce kernels)
// M = 512 fixed. Tile 128x64, BK=32, 256 threads, 8x4 micro-tile.
// Register-prefetch double-buffered LDS, one __syncthreads per K-tile.
// grid = dim3(4 * (Nout/64), nsegs). K uniform per seg (multiple of 32).
struct GSeg2 { const float* X; const float* W; float* C; int ldx, ldw, ldc, K; };
struct GArgs2 { GSeg2 s[8]; };

__global__ __launch_bounds__(256) void k_gemm2(GArgs2 ga)
{
  const GSeg2 sg = ga.s[blockIdx.y];
  const int tm = blockIdx.x & 3;       // M/128 = 4
  const int tn = blockIdx.x >> 2;      // Nout/64
  const int i0 = tm << 7;
  const int n0 = tn << 6;
  const int tid = threadIdx.x;

  // Xs: [k][m] stride 132 (528B = 33*16, float4-aligned); Ws: [k][n] stride 68
  __shared__ float Xs[2][32][132];
  __shared__ float Ws[2][32][68];

  // staging: thread loads 4 X-float4 (rows xrow+32i) and 2 W-float4
  const int xrow = tid >> 3;           // 0..31 per 256 threads -> rows via +32*i
  const int xk   = (tid & 7) << 2;     // k offset 0..28
  // compute: 8 rows x 4 cols per thread
  const int rg = (tid >> 4) << 3;      // 0..120
  const int cg = (tid & 15) << 2;      // 0..60

  const float* Xb = sg.X + (size_t)i0 * sg.ldx;
  const float* Wb = sg.W + (size_t)n0 * sg.ldw;

  float4 xr[4], wr[2];

  auto loadT = [&](int kt){
    #pragma unroll
    for (int i = 0; i < 4; ++i)
      xr[i] = *(const float4*)(Xb + (size_t)(xrow + 32*i) * sg.ldx + kt + xk);
    #pragma unroll
    for (int i = 0; i < 2; ++i)
      wr[i] = *(const float4*)(Wb + (size_t)(xrow + 32*i) * sg.ldw + kt + xk);
  };
  auto writeT = [&](int bu){
    #pragma unroll
    for (int i = 0; i < 4; ++i){
      Xs[bu][xk+0][xrow+32*i] = xr[i].x;
      Xs[bu][xk+1][xrow+32*i] = xr[i].y;
      Xs[bu][xk+2][xrow+32*i] = xr[i].z;
      Xs[bu][xk+3][xrow+32*i] = xr[i].w;
    }
    #pragma unroll
    for (int i = 0; i < 2; ++i){
      Ws[bu][xk+0][xrow+32*i] = wr[i].x;
      Ws[bu][xk+1][xrow+32*i] = wr[i].y;
      Ws[bu][xk+2][xrow+32*i] = wr[i].z;
      Ws[bu][xk+3][xrow+32*i] = wr[i].w;
    }
  };

  loadT(0);
  writeT(0);
  __syncthreads();

  float acc[8][4] = {};
  const int nkt = sg.K >> 5;
  for (int t = 0; t < nkt; ++t){
    if (t + 1 < nkt) loadT((t + 1) << 5);   // issue prefetch; latency hidden by FMAs
    const int bu = t & 1;
    #pragma unroll
    for (int kk = 0; kk < 32; ++kk){
      const float4 a0 = *(const float4*)&Xs[bu][kk][rg];
      const float4 a1 = *(const float4*)&Xs[bu][kk][rg+4];
      const float4 bv = *(const float4*)&Ws[bu][kk][cg];
      acc[0][0]+=a0.x*bv.x; acc[0][1]+=a0.x*bv.y; acc[0][2]+=a0.x*bv.z; acc[0][3]+=a0.x*bv.w;
      acc[1][0]+=a0.y*bv.x; acc[1][1]+=a0.y*bv.y; acc[1][2]+=a0.y*bv.z; acc[1][3]+=a0.y*bv.w;
      acc[2][0]+=a0.z*bv.x; acc[2][1]+=a0.z*bv.y; acc[2][2]+=a0.z*bv.z; acc[2][3]+=a0.z*bv.w;
      acc[3][0]+=a0.w*bv.x; acc[3][1]+=a0.w*bv.y; acc[3][2]+=a0.w*bv.z; acc[3][3]+=a0.w*bv.w;
      acc[4][0]+=a1.x*bv.x; acc[4][1]+=a1.x*bv.y; acc[4][2]+=a1.x*bv.z; acc[4][3]+=a1.x*bv.w;
      acc[5][0]+=a1.y*bv.x; acc[5][1]+=a1.y*bv.y; acc[5][2]+=a1.y*bv.z; acc[5][3]+=a1.y*bv.w;
      acc[6][0]+=a1.z*bv.x; acc[6][1]+=a1.z*bv.y; acc[6][2]+=a1.z*bv.z; acc[6][3]+=a1.z*bv.w;
      acc[7][0]+=a1.w*bv.x; acc[7][1]+=a1.w*bv.y; acc[7][2]+=a1.w*bv.z; acc[7][3]+=a1.w*bv.w;
    }
    if (t + 1 < nkt) writeT((t + 1) & 1);   // other buffer: safe before sync
    __syncthreads();
  }

  #pragma unroll
  for (int ri = 0; ri < 8; ++ri){
    float4 v = make_float4(acc[ri][0], acc[ri][1], acc[ri][2], acc[ri][3]);
    *(float4*)(sg.C + (size_t)(i0 + rg + ri) * sg.ldc + (n0 + cg)) = v;
  }
}

// ---------- hidden reduce: hidden_t = relu(ht0+ht1+tb1), hidden_p = relu(hp0+hp1+hp2+pb1) ----------
__global__ void k_redH(const float* __restrict__ ht0, const float* __restrict__ ht1,
                       const float* __restrict__ tb1,
                       const float* __restrict__ hp0, const float* __restrict__ hp1,
                       const float* __restrict__ hp2, const float* __restrict__ pb1,
                       float* __restrict__ hidden_t, float* __restrict__ hidden_p)
{
  int f = blockIdx.x * 256 + threadIdx.x;   // grid 128 -> 32768 float4 per matrix
  int c4 = f & 63;
  {
    float4 a = ((const float4*)ht0)[f], b = ((const float4*)ht1)[f];
    float4 bb = ((const float4*)tb1)[c4];
    float4 o;
    o.x = fmaxf(a.x+b.x+bb.x, 0.f); o.y = fmaxf(a.y+b.y+bb.y, 0.f);
    o.z = fmaxf(a.z+b.z+bb.z, 0.f); o.w = fmaxf(a.w+b.w+bb.w, 0.f);
    ((float4*)hidden_t)[f] = o;
  }
  {
    float4 a = ((const float4*)hp0)[f], b = ((const float4*)hp1)[f], c = ((const float4*)hp2)[f];
    float4 bb = ((const float4*)pb1)[c4];
    float4 o;
    o.x = fmaxf(a.x+b.x+c.x+bb.x, 0.f); o.y = fmaxf(a.y+b.y+c.y+bb.y, 0.f);
    o.z = fmaxf(a.z+b.z+c.z+bb.z, 0.f); o.w = fmaxf(a.w+b.w+c.w+bb.w, 0.f);
    ((float4*)hidden_p)[f] = o;
  }
}

// ---------- tf/cf reduce: tfm = tf0+tf1+tb2, cfm = cf0+cf1+pb2 ----------
__global__ void k_redB(const float* __restrict__ tf0, const float* __restrict__ tf1,
                       const float* __restrict__ tb2,
                       const float* __restrict__ cf0, const float* __restrict__ cf1,
                       const float* __restrict__ pb2,
                       float* __restrict__ tfm, float* __restrict__ cfm)
{
  int f = blockIdx.x * 256 + threadIdx.x;   // grid 64 -> 8192 float4 per matrix
  int c4 = f & 15;
  {
    float4 a = ((const float4*)tf0)[f], b = ((const float4*)tf1)[f];
    float4 bb = ((const float4*)tb2)[c4];
    float4 o = make_float4(a.x+b.x+bb.x, a.y+b.y+bb.y, a.z+b.z+bb.z, a.w+b.w+bb.w);
    ((float4*)tfm)[f] = o;
  }
  {
    float4 a = ((const float4*)cf0)[f], b = ((const float4*)cf1)[f];
    float4 bb = ((const float4*)pb2)[c4];
    float4 o = make_float4(a.x+b.x+bb.x, a.y+b.y+bb.y, a.z+b.z+bb.z, a.w+b.w+bb.w);
    ((float4*)cfm)[f] = o;
  }
}

// ---------- e1[j] = Wh1[j,:] . sa1 ----------
__global__ void k_e1(const float* __restrict__ Wh1, const float* __restrict__ sa1,
                     float* __restrict__ e1)
{
  int i = blockIdx.x, lane = threadIdx.x; // block 64
  float a = 0.f;
  for (int k = lane; k < kHID; k += 64) a += Wh1[(size_t)i*kHID + k] * sa1[k];
  #pragma unroll
  for (int o = 32; o > 0; o >>= 1) a += __shfl_down(a, o, 64);
  if (lane == 0) e1[i] = a;
}

// ---------- per-row masked softmax stats for H1 ----------
__global__ void k_h1stats(const int* __restrict__ adj, const float* __restrict__ e1,
                          float* __restrict__ minv, float* __restrict__ invz)
{
  __shared__ float red[8];
  int i = blockIdx.x, tid = threadIdx.x; // grid 512, block 256
  int m0 = adj[(size_t)i*kN + tid];
  int m1 = adj[(size_t)i*kN + tid + 256];
  float ea = e1[tid], eb = e1[tid+256];
  float v0 = m0 ? ea : -1e30f;
  float v1 = m1 ? eb : -1e30f;
  float m = blk_red(fmaxf(v0, v1), red, true);
  float z = blk_red((m0 ? expf(ea-m) : 0.f) + (m1 ? expf(eb-m) : 0.f), red, false);
  if (tid == 0){ minv[i] = m; invz[i] = 1.0f / z; }
}

// ---------- H1 partials over j-tiles: grid (128, 8) ----------
__global__ __launch_bounds__(256) void k_h1p(const int* __restrict__ adj, const float* __restrict__ e1,
                      const float* __restrict__ minv, const float* __restrict__ invz,
                      const float* __restrict__ Wh1, float* __restrict__ H1p)
{
  __shared__ float w[4][64];
  int i0 = blockIdx.x * 4, jt = blockIdx.y, j0 = jt * 64;
  int tid = threadIdx.x;
  {
    int r = tid >> 6, jj = tid & 63;
    int j = j0 + jj;
    w[r][jj] = adj[(size_t)(i0+r)*kN + j]
             ? expf(e1[j] - minv[i0+r]) * invz[i0+r] : 0.f;
  }
  __syncthreads();
  float a0=0,a1=0,a2=0,a3=0;
  #pragma unroll 4
  for (int jj = 0; jj < 64; ++jj){
    float wh = Wh1[(size_t)(j0+jj)*kHID + tid];
    a0 += w[0][jj]*wh; a1 += w[1][jj]*wh; a2 += w[2][jj]*wh; a3 += w[3][jj]*wh;
  }
  size_t base = ((size_t)jt*kN + i0)*kHID + tid;
  H1p[base]          = a0;
  H1p[base + kHID]   = a1;
  H1p[base + 2*kHID] = a2;
  H1p[base + 3*kHID] = a3;
}

// ---------- H1 reduce over 8 j-tiles ----------
__global__ void k_h1r(const float* __restrict__ H1p, float* __restrict__ H1)
{
  int i = blockIdx.x, tid = threadIdx.x; // grid 512, block 256
  float s = 0.f;
  #pragma unroll
  for (int jt = 0; jt < 8; ++jt)
    s += H1p[((size_t)jt*kN + i)*kHID + tid];
  H1[(size_t)i*kHID + tid] = s;
}

// ---------- u = ce_w2^T (ca0+ca1), beta = ce_b2 . (ca0+ca1) ----------
__global__ void k_ub(const float* __restrict__ ce_w2, const float* __restrict__ ce_b2,
                     const float* __restrict__ ca0, const float* __restrict__ ca1,
                     float* __restrict__ u, float* __restrict__ beta)
{
  __shared__ float c[kHD];
  int tid = threadIdx.x; // 256
  if (tid < kHD) c[tid] = ca0[tid] + ca1[tid];
  __syncthreads();
  float a = 0.f;
  for (int d = 0; d < kHD; ++d) a += ce_w2[(size_t)d*kHID + tid] * c[d];
  u[tid] = a;
  if (tid == 0){
    float b = 0.f;
    for (int d = 0; d < kHD; ++d) b += ce_b2[d] * c[d];
    *beta = b;
  }
}

// ---------- s2 pair scores: grid (128, 8) ----------
__global__ __launch_bounds__(256) void k_s2(const float* __restrict__ A, const float* __restrict__ Bm,
                     const float* __restrict__ ce_b1,
                     const float* __restrict__ u, const float* __restrict__ beta,
                     float* __restrict__ s2, float* __restrict__ maxp,
                     float* __restrict__ zp)
{
  __shared__ __align__(16) float aib[4][kHID];
  __shared__ __align__(16) float uu[kHID];
  int i0 = blockIdx.x * 4, j0 = blockIdx.y * 64;
  int tid = threadIdx.x;
  int wv = tid >> 6, lane = tid & 63;
  uu[tid] = u[tid];
  float b1v = ce_b1[tid];
  #pragma unroll
  for (int r = 0; r < 4; ++r) aib[r][tid] = A[(size_t)(i0+r)*kHID + tid] + b1v;
  __syncthreads();
  int i = i0 + wv, j = j0 + lane;
  const float4* bp = (const float4*)(Bm + (size_t)j*kHID);
  float acc = *beta;
  #pragma unroll 8
  for (int k4 = 0; k4 < kHID/4; ++k4){
    float4 b = bp[k4];
    float4 a4 = *(const float4*)&aib[wv][k4*4];
    float4 u4 = *(const float4*)&uu[k4*4];
    acc += fmaxf(a4.x+b.x,0.f)*u4.x + fmaxf(a4.y+b.y,0.f)*u4.y
         + fmaxf(a4.z+b.z,0.f)*u4.z + fmaxf(a4.w+b.w,0.f)*u4.w;
  }
  if (j == i) acc = -1e30f;
  s2[(size_t)i*kN + j] = acc;
  float m = acc;
  #pragma unroll
  for (int o = 32; o > 0; o >>= 1) m = fmaxf(m, __shfl_down(m, o, 64));
  m = __shfl(m, 0, 64);
  float e = expf(acc - m);
  #pragma unroll
  for (int o = 32; o > 0; o >>= 1) e += __shfl_down(e, o, 64);
  if (lane == 0){
    int pb = (blockIdx.y * gridDim.x + blockIdx.x) * 4 + wv;
    maxp[pb] = m; zp[pb] = e;
  }
}

// ---------- global softmax stats; zero g ----------
__global__ void k_mz(const float* __restrict__ maxp, const float* __restrict__ zp,
                     float* __restrict__ MZ, float* __restrict__ g)
{
  __shared__ float red[8];
  int tid = threadIdx.x; // 256
  float m = -1e30f;
  #pragma unroll
  for (int r = 0; r < 16; ++r) m = fmaxf(m, maxp[tid + 256*r]);
  m = blk_red(m, red, true);
  float z = 0.f;
  #pragma unroll
  for (int r = 0; r < 16; ++r) z += zp[tid + 256*r] * expf(maxp[tid + 256*r] - m);
  z = blk_red(z, red, false);
  if (tid == 0){ MZ[0] = m; MZ[1] = z; }
  g[tid] = 0.f;
}

// ---------- g[k] += 16x16 pair tile of a2[i,j]*relu(A_i[k]+B_j[k]+b1[k]) ----------
__global__ __launch_bounds__(256) void k_gpart(const float* __restrict__ A, const float* __restrict__ Bm,
                        const float* __restrict__ ce_b1,
                        const float* __restrict__ s2, const float* __restrict__ MZ,
                        float* __restrict__ g)
{
  __shared__ float wt[16][16];
  int i0 = blockIdx.x * 16, j0 = blockIdx.y * 16;
  int tid = threadIdx.x;
  float M = MZ[0], invZ = 1.0f / MZ[1];
  {
    int r = tid >> 4, c = tid & 15;
    wt[r][c] = expf(s2[(size_t)(i0+r)*kN + (j0+c)] - M) * invZ;
  }
  float b1v = ce_b1[tid];
  float aib[16];
  #pragma unroll
  for (int r = 0; r < 16; ++r) aib[r] = A[(size_t)(i0+r)*kHID + tid] + b1v;
  __syncthreads();
  float acc = 0.f;
  for (int j = 0; j < 16; ++j){
    float bj = Bm[(size_t)(j0+j)*kHID + tid];
    #pragma unroll
    for (int r = 0; r < 16; ++r)
      acc += wt[r][j] * fmaxf(aib[r] + bj, 0.f);
  }
  atomicAdd(&g[tid], acc);
}

// ---------- H2vec = g @ ce_w2^T + ce_b2 ----------
__global__ void k_h2(const float* __restrict__ g, const float* __restrict__ ce_w2,
                     const float* __restrict__ ce_b2, float* __restrict__ H2vec)
{
  __shared__ float gs[kHID];
  __shared__ float part[kHD][4];
  int tid = threadIdx.x; // 256, single block
  gs[tid] = g[tid];
  __syncthreads();
  int d = tid >> 2, q = tid & 3;
  float a = 0.f;
  for (int kk = 0; kk < 64; ++kk){
    int k = q*64 + kk;
    a += gs[k] * ce_w2[(size_t)d*kHID + k];
  }
  part[d][q] = a;
  __syncthreads();
  if (tid < kHD)
    H2vec[tid] = ce_b2[tid] + part[tid][0] + part[tid][1] + part[tid][2] + part[tid][3];
}

// ---------- H3[i,d] = mean(tf[0..i, d]) ----------
__global__ void k_h3(const float* __restrict__ tf, float* __restrict__ H3)
{
  __shared__ float s[kN];
  int d = blockIdx.x, i = threadIdx.x; // block 512
  s[i] = tf[(size_t)i*kHD + d];
  __syncthreads();
  for (int off = 1; off < kN; off <<= 1){
    float t = (i >= off) ? s[i-off] : 0.0f;
    __syncthreads();
    s[i] += t;
    __syncthreads();
  }
  H3[(size_t)i*kHD + d] = s[i] / (float)(i+1);
}

// ---------- first two neighbors per row ----------
__global__ void k_pairsel(const int* __restrict__ adj, int* __restrict__ nbr)
{
  int i = blockIdx.x * blockDim.x + threadIdx.x; // 512 threads total
  int j0 = -1, j1 = -1;
  for (int j = 0; j < kN; ++j){
    if (adj[(size_t)i*kN + j] != 0){
      if (j0 < 0) j0 = j;
      else { j1 = j; break; }
    }
  }
  if (j1 < 0) j0 = -1;
  nbr[2*i] = j0; nbr[2*i+1] = j1;
}

// ---------- Xp = [V | n0 | n1] ----------
__global__ void k_packxp(const float* __restrict__ Vf, const int* __restrict__ nbr,
                         float* __restrict__ Xp)
{
  int i = blockIdx.x, k = threadIdx.x; // block 256
  int j0 = nbr[2*i], j1 = nbr[2*i+1];
  Xp[(size_t)i*768 + k]       = Vf[(size_t)i*kIN + k];
  Xp[(size_t)i*768 + 256 + k] = (j0 >= 0) ? Vf[(size_t)j0*kIN + k] : 0.0f;
  Xp[(size_t)i*768 + 512 + k] = (j1 >= 0) ? Vf[(size_t)j1*kIN + k] : 0.0f;
}

// ---------- H4v = colsum(cf) ----------
__global__ void k_h4(const float* __restrict__ cf, float* __restrict__ H4v)
{
  int d = threadIdx.x; // block 64, single block
  float a = 0.f;
  for (int i = 0; i < kN; ++i) a += cf[(size_t)i*kHD + d];
  H4v[d] = a;
}

// ---------- out2 = [H1 | H2vec | H3 | H4col] @ W2^T (ld 385) ----------
__global__ void k_out2(const float* __restrict__ H1, const float* __restrict__ H2vec,
                       const float* __restrict__ H3, const float* __restrict__ H4v,
                       const float* __restrict__ W2, float* __restrict__ out2)
{
  __shared__ float h1r[kHID];
  __shared__ float h3r[kHD];
  __shared__ float h2v[kHD];
  __shared__ float h4s[1];
  int i = blockIdx.x, o = threadIdx.x; // block 256
  h1r[o] = H1[(size_t)i*kHID + o];
  if (o < kHD){ h3r[o] = H3[(size_t)i*kHD + o]; h2v[o] = H2vec[o]; }
  if (o == 0) h4s[0] = (i < kHD) ? H4v[i] : 0.0f;
  __syncthreads();
  const float* wr = W2 + (size_t)o * 385;
  float acc = 0.f;
  for (int k = 0; k < kHID; ++k) acc += h1r[k] * wr[k];
  for (int d = 0; d < kHD; ++d)  acc += h2v[d] * wr[256+d];
  for (int d = 0; d < kHD; ++d)  acc += h3r[d] * wr[320+d];
  acc += h4s[0] * wr[384];
  out2[(size_t)i*kOUT + o] = acc;
}

// ---------- out = elu(layernorm(out2 @ op_w^T + op_b)) ----------
__global__ void k_final(const float* __restrict__ out2, const float* __restrict__ op_w,
                        const float* __restrict__ op_b, const float* __restrict__ ln_g,
                        const float* __restrict__ ln_b, const int* __restrict__ flag,
                        void* __restrict__ out)
{
  __shared__ float row[kOUT];
  __shared__ float red[8];
  int i = blockIdx.x, o = threadIdx.x; // block 256
  row[o] = out2[(size_t)i*kOUT + o];
  __syncthreads();
  const float4* wr = (const float4*)(op_w + (size_t)o * kOUT);
  float acc = op_b[o];
  for (int kb = 0; kb < kOUT; kb += 4){
    float4 q = *wr++;
    acc += row[kb+0]*q.x + row[kb+1]*q.y + row[kb+2]*q.z + row[kb+3]*q.w;
  }
  float mu = blk_red(acc, red, false) * (1.0f/kOUT);
  float dv = acc - mu;
  float var = blk_red(dv*dv, red, false) * (1.0f/kOUT);
  float y = dv * rsqrtf(var + 1e-5f) * ln_g[o] + ln_b[o];
  y = (y > 0.f) ? y : expm1f(y);
  if (*flag) ((float*)out)[(size_t)i*kOUT + o] = y;
  else       ((u16*)out)[(size_t)i*kOUT + o]   = f2us(y);
}

extern "C" void kernel_launch(void* const* d_in, const int* in_sizes, int n_in,
                              void* d_out, int out_size, void* d_ws, size_t ws_size,
                              hipStream_t stream)
{
  const void* V     = d_in[0];
  const int*  adj   = (const int*)d_in[1];
  const void* prev  = d_in[2];
  const void* W1    = d_in[3];
  // d_in[4] = sa0 : dead (row-shift invariant softmax)
  const void* sa1   = d_in[5];
  const void* ce_w1 = d_in[6];
  const void* ce_b1 = d_in[7];
  const void* ce_w2 = d_in[8];
  const void* ce_b2 = d_in[9];
  const void* ca0   = d_in[10];
  const void* ca1   = d_in[11];
  const void* te_w1 = d_in[12];
  const void* te_b1 = d_in[13];
  const void* te_w2 = d_in[14];
  const void* te_b2 = d_in[15];
  // d_in[16,17] = ta0,ta1 : dead
  const void* pe_w1 = d_in[18];
  const void* pe_b1 = d_in[19];
  const void* pe_w2 = d_in[20];
  const void* pe_b2 = d_in[21];
  // d_in[22,23] = pa0,pa1 : dead
  const void* W2    = d_in[24];
  const void* op_w  = d_in[25];
  const void* op_b  = d_in[26];
  const void* ln_g  = d_in[27];
  const void* ln_b  = d_in[28];

  // ---- workspace layout (floats) ----
  float* ws  = (float*)d_ws;
  int*  flag = (int*)ws;               // 16 floats reserved
  float* p   = ws + 16;
  float* Vf   = p; p += 131072;
  float* prevf= p; p += 131072;
  float* W1f  = p; p += 65536;
  float* sa1f = p; p += 256;
  float* cw1f = p; p += 131072;
  float* cb1f = p; p += 256;
  float* cw2f = p; p += 16384;
  float* cb2f = p; p += 64;
  float* ca0f = p; p += 64;
  float* ca1f = p; p += 64;
  float* tw1f = p; p += 131072;
  float* tb1f = p; p += 256;
  float* tw2f = p; p += 16384;
  float* tb2f = p; p += 64;
  float* pw1f = p; p += 196608;
  float* pb1f = p; p += 256;
  float* pw2f = p; p += 16384;
  float* pb2f = p; p += 64;
  float* W2f  = p; p += 98560;
  float* opwf = p; p += 65536;
  float* opbf = p; p += 256;
  float* lngf = p; p += 256;
  float* lnbf = p; p += 256;
  float* Wh1      = p; p += 131072;
  float* e1v      = p; p += 512;
  float* minv     = p; p += 512;
  float* invzv    = p; p += 512;
  float* H1p      = p; p += 1048576;   // 8 x 512 x 256 partials
  float* H1       = p; p += 131072;
  float* Am       = p; p += 131072;
  float* Bm       = p; p += 131072;
  float* uvec     = p; p += 256;
  float* beta     = p; p += 16;
  float* s2       = p; p += 262144;
  float* maxp     = p; p += 4096;
  float* zpart    = p; p += 4096;
  float* MZ       = p; p += 16;
  float* gsum     = p; p += 256;
  float* H2vec    = p; p += 64;
  float* htp0     = p; p += 131072;
  float* htp1     = p; p += 131072;
  float* hpp0     = p; p += 131072;
  float* hpp1     = p; p += 131072;
  float* hpp2     = p; p += 131072;
  float* hidden_t = p; p += 131072;
  float* tfp0     = p; p += 32768;
  float* tfp1     = p; p += 32768;
  float* cfp0     = p; p += 32768;
  float* cfp1     = p; p += 32768;
  float* tfm      = p; p += 32768;
  float* H3       = p; p += 32768;
  int*   nbr      = (int*)p; p += 1024;
  float* Xp       = p; p += 393216;
  float* hidden_p = p; p += 131072;
  float* cfm      = p; p += 32768;
  float* H4v      = p; p += 64;
  float* out2     = p; p += 131072;

  // ---- dtype probe + input widening ----
  k_probe<<<1, 256, 0, stream>>>((const unsigned int*)V, flag);
  ConvArgs ca;
  const void* srcs[23] = {V, prev, W1, sa1, ce_w1, ce_b1, ce_w2, ce_b2, ca0, ca1,
                          te_w1, te_b1, te_w2, te_b2, pe_w1, pe_b1, pe_w2, pe_b2,
                          W2, op_w, op_b, ln_g, ln_b};
  float* dsts[23] = {Vf, prevf, W1f, sa1f, cw1f, cb1f, cw2f, cb2f, ca0f, ca1f,
                     tw1f, tb1f, tw2f, tb2f, pw1f, pb1f, pw2f, pb2f,
                     W2f, opwf, opbf, lngf, lnbf};
  int ns[23] = {131072, 131072, 65536, 256, 131072, 256, 16384, 64, 64, 64,
                131072, 256, 16384, 64, 196608, 256, 16384, 64,
                98560, 65536, 256, 256, 256};
  for (int s = 0; s < 23; ++s){ ca.src[s] = srcs[s]; ca.dst[s] = dsts[s]; ca.n[s] = ns[s]; }
  k_convert_all<<<512, 256, 0, stream>>>(ca, flag);

  // ---- pair-branch input prep ----
  k_pairsel<<<2, 256, 0, stream>>>(adj, nbr);
  k_packxp<<<kN, 256, 0, stream>>>(Vf, nbr, Xp);

  // ---- GEMM batch A: all K=256 chunks, one launch (8 segs x 16 tiles = 128 blocks) ----
  {
    GArgs2 g{};
    g.s[0] = {Vf,       W1f,        Wh1,  256, 256, 256, 256};
    g.s[1] = {Vf,       cw1f,       Am,   256, 512, 256, 256};
    g.s[2] = {Vf,       cw1f + 256, Bm,   256, 512, 256, 256};
    g.s[3] = {Vf,       tw1f,       htp0, 256, 512, 256, 256};
    g.s[4] = {prevf,    tw1f + 256, htp1, 256, 512, 256, 256};
    g.s[5] = {Xp,       pw1f,       hpp0, 768, 768, 256, 256};
    g.s[6] = {Xp + 256, pw1f + 256, hpp1, 768, 768, 256, 256};
    g.s[7] = {Xp + 512, pw1f + 512, hpp2, 768, 768, 256, 256};
    k_gemm2<<<dim3(16, 8), 256, 0, stream>>>(g);
  }
  k_redH<<<128, 256, 0, stream>>>(htp0, htp1, tb1f, hpp0, hpp1, hpp2, pb1f,
                                  hidden_t, hidden_p);

  // ---- GEMM batch B: tf/cf split-K2 (4 segs x 4 tiles = 16 blocks) ----
  {
    GArgs2 g{};
    g.s[0] = {hidden_t,       tw2f,       tfp0, 256, 256, 64, 128};
    g.s[1] = {hidden_t + 128, tw2f + 128, tfp1, 256, 256, 64, 128};
    g.s[2] = {hidden_p,       pw2f,       cfp0, 256, 256, 64, 128};
    g.s[3] = {hidden_p + 128, pw2f + 128, cfp1, 256, 256, 64, 128};
    k_gemm2<<<dim3(4, 4), 256, 0, stream>>>(g);
  }
  k_redB<<<64, 256, 0, stream>>>(tfp0, tfp1, tb2f, cfp0, cfp1, pb2f, tfm, cfm);

  // --- GAT branch (H1) ---
  k_e1<<<kN, 64, 0, stream>>>(Wh1, sa1f, e1v);
  k_h1stats<<<kN, 256, 0, stream>>>(adj, e1v, minv, invzv);
  k_h1p<<<dim3(kN/4, 8), 256, 0, stream>>>(adj, e1v, minv, invzv, Wh1, H1p);
  k_h1r<<<kN, 256, 0, stream>>>(H1p, H1);

  // --- cross-edge branch (H2) ---
  k_ub<<<1, 256, 0, stream>>>(cw2f, cb2f, ca0f, ca1f, uvec, beta);
  k_s2<<<dim3(kN/4, 8), 256, 0, stream>>>(Am, Bm, cb1f, uvec, beta, s2, maxp, zpart);
  k_mz<<<1, 256, 0, stream>>>(maxp, zpart, MZ, gsum);
  k_gpart<<<dim3(kN/16, kN/16), 256, 0, stream>>>(Am, Bm, cb1f, s2, MZ, gsum);
  k_h2<<<1, 256, 0, stream>>>(gsum, cw2f, cb2f, H2vec);

  // --- temporal branch (H3) ---
  k_h3<<<kHD, kN, 0, stream>>>(tfm, H3);

  // --- pair branch (H4) ---
  k_h4<<<1, 64, 0, stream>>>(cfm, H4v);

  // --- combine + output head ---
  k_out2<<<kN, 256, 0, stream>>>(H1, H2vec, H3, H4v, W2f, out2);
  k_final<<<kN, 256, 0, stream>>>(out2, opwf, opbf, lngf, lnbf, flag, d_out);
}

// Round 4
// 277.610 us; speedup vs baseline: 1.5946x; 1.1512x over previous
//
#include <hip/hip_runtime.h>

typedef unsigned short u16;

constexpr int kN   = 512;
constexpr int kIN  = 256;
constexpr int kHID = 256;
constexpr int kHD  = 64;
constexpr int kOUT = 256;

// ---------- bf16 helpers ----------
__device__ __forceinline__ float us2f(u16 u){
  union { unsigned int i; float f; } c; c.i = ((unsigned int)u) << 16; return c.f;
}
__device__ __forceinline__ u16 f2us(float f){
  union { float f; unsigned int i; } c; c.f = f;
  unsigned int r = c.i + 0x7fff + ((c.i >> 16) & 1);
  return (u16)(r >> 16);
}

// ---------- dtype probe ----------
__global__ void k_probe(const unsigned int* __restrict__ V, int* __restrict__ flag){
  __shared__ int cnt;
  if (threadIdx.x == 0) cnt = 0;
  __syncthreads();
  int c = 0;
  for (int k = threadIdx.x; k < 4096; k += 256){
    float x = us2f((u16)(V[k] & 0xffffu));
    float ax = fabsf(x);
    if (!(ax <= 32.0f)) c++;
  }
  atomicAdd(&cnt, c);
  __syncthreads();
  if (threadIdx.x == 0) *flag = (cnt > 64) ? 1 : 0;
}

// ---------- convert all float tensors to fp32 (vectorized x4) ----------
struct ConvArgs { const void* src[23]; float* dst[23]; int n[23]; };

__global__ void k_convert_all(ConvArgs a, const int* __restrict__ flag){
  bool f32 = (*flag != 0);
  int stride = gridDim.x * blockDim.x;
  int t = blockIdx.x * blockDim.x + threadIdx.x;
  for (int s = 0; s < 23; ++s){
    int n4 = a.n[s] >> 2;
    float4* d = (float4*)a.dst[s];
    if (f32){
      const float4* sf = (const float4*)a.src[s];
      for (int i = t; i < n4; i += stride) d[i] = sf[i];
    } else {
      const ushort4* sb = (const ushort4*)a.src[s];
      for (int i = t; i < n4; i += stride){
        ushort4 u = sb[i];
        d[i] = make_float4(us2f(u.x), us2f(u.y), us2f(u.z), us2f(u.w));
      }
    }
  }
}

// ---------- block reduction (256 threads) ----------
__device__ __forceinline__ float blk_red(float v, float* tmp, bool isMax){
  int lane = threadIdx.x & 63, wv = threadIdx.x >> 6;
  #pragma unroll
  for (int o = 32; o > 0; o >>= 1){
    float t = __shfl_down(v, o, 64);
    v = isMax ? fmaxf(v, t) : (v + t);
  }
  __syncthreads();
  if (lane == 0) tmp[wv] = v;
  __syncthreads();
  float r = tmp[0];
  for (int i = 1; i < 4; ++i) r = isMax ? fmaxf(r, tmp[i]) : (r + tmp[i]);
  return r;
}

// ---------- workspace pointer bundle ----------
struct WSP {
  const int* adj; const int* flag; void* out;
  float *Vf,*prevf,*W1f,*sa1f,*cw1f,*cb1f,*cw2f,*cb2f,*ca0f,*ca1f;
  float *tw1f,*tb1f,*tw2f,*tb2f,*pw1f,*pb1f,*pw2f,*pb2f;
  float *W2f,*opwf,*opbf,*lngf,*lnbf;
  float *Wh1,*e1v,*minv,*invzv,*H1p,*H1,*Am,*Bm,*uvec,*beta;
  float *s2,*maxp,*zp,*MZ,*gsum,*c2v;
  float *htp0,*htp1,*hpp0,*hpp1,*hpp2,*hidden_t,*hidden_p;
  float *tfp0,*tfp1,*tfp2,*tfp3,*cfp0,*cfp1,*cfp2,*cfp3;
  float *tfm,*cfm,*H3,*H4v,*Xp;
};

// ================== GEMM core: 128x64 tile, BK=32, 8x4 micro, dbuf ==================
struct GSeg2 { const float* X; const float* W; float* C; int ldx, ldw, ldc, K; };
struct GArgs2 { GSeg2 s[8]; };

__device__ __forceinline__ void gemm_body(const GSeg2 sg, int tm, int tn, int tid,
                                          float* xsB, float* wsB)
{
  const int i0 = tm << 7;
  const int n0 = tn << 6;
  const int xrow = tid >> 3;           // 0..31
  const int xk   = (tid & 7) << 2;     // 0..28
  const int rg = (tid >> 4) << 3;      // 0..120
  const int cg = (tid & 15) << 2;      // 0..60

  const float* Xb = sg.X + (size_t)i0 * sg.ldx;
  const float* Wb = sg.W + (size_t)n0 * sg.ldw;

  float4 xr[4], wr[2];
  auto loadT = [&](int kt){
    #pragma unroll
    for (int i2 = 0; i2 < 4; ++i2)
      xr[i2] = *(const float4*)(Xb + (size_t)(xrow + 32*i2) * sg.ldx + kt + xk);
    #pragma unroll
    for (int i2 = 0; i2 < 2; ++i2)
      wr[i2] = *(const float4*)(Wb + (size_t)(xrow + 32*i2) * sg.ldw + kt + xk);
  };
  auto writeT = [&](int bu){
    float* xs = xsB + bu*4224;
    #pragma unroll
    for (int i2 = 0; i2 < 4; ++i2){
      xs[(xk+0)*132 + xrow+32*i2] = xr[i2].x;
      xs[(xk+1)*132 + xrow+32*i2] = xr[i2].y;
      xs[(xk+2)*132 + xrow+32*i2] = xr[i2].z;
      xs[(xk+3)*132 + xrow+32*i2] = xr[i2].w;
    }
    float* ws2 = wsB + bu*2176;
    #pragma unroll
    for (int i2 = 0; i2 < 2; ++i2){
      ws2[(xk+0)*68 + xrow+32*i2] = wr[i2].x;
      ws2[(xk+1)*68 + xrow+32*i2] = wr[i2].y;
      ws2[(xk+2)*68 + xrow+32*i2] = wr[i2].z;
      ws2[(xk+3)*68 + xrow+32*i2] = wr[i2].w;
    }
  };

  loadT(0); writeT(0); __syncthreads();

  float acc[8][4] = {};
  const int nkt = sg.K >> 5;
  for (int t = 0; t < nkt; ++t){
    if (t + 1 < nkt) loadT((t + 1) << 5);
    const float* xs  = xsB + (t & 1)*4224;
    const float* ws2 = wsB + (t & 1)*2176;
    #pragma unroll
    for (int kk = 0; kk < 32; ++kk){
      const float4 a0 = *(const float4*)&xs[kk*132 + rg];
      const float4 a1 = *(const float4*)&xs[kk*132 + rg + 4];
      const float4 bv = *(const float4*)&ws2[kk*68 + cg];
      acc[0][0]+=a0.x*bv.x; acc[0][1]+=a0.x*bv.y; acc[0][2]+=a0.x*bv.z; acc[0][3]+=a0.x*bv.w;
      acc[1][0]+=a0.y*bv.x; acc[1][1]+=a0.y*bv.y; acc[1][2]+=a0.y*bv.z; acc[1][3]+=a0.y*bv.w;
      acc[2][0]+=a0.z*bv.x; acc[2][1]+=a0.z*bv.y; acc[2][2]+=a0.z*bv.z; acc[2][3]+=a0.z*bv.w;
      acc[3][0]+=a0.w*bv.x; acc[3][1]+=a0.w*bv.y; acc[3][2]+=a0.w*bv.z; acc[3][3]+=a0.w*bv.w;
      acc[4][0]+=a1.x*bv.x; acc[4][1]+=a1.x*bv.y; acc[4][2]+=a1.x*bv.z; acc[4][3]+=a1.x*bv.w;
      acc[5][0]+=a1.y*bv.x; acc[5][1]+=a1.y*bv.y; acc[5][2]+=a1.y*bv.z; acc[5][3]+=a1.y*bv.w;
      acc[6][0]+=a1.z*bv.x; acc[6][1]+=a1.z*bv.y; acc[6][2]+=a1.z*bv.z; acc[6][3]+=a1.z*bv.w;
      acc[7][0]+=a1.w*bv.x; acc[7][1]+=a1.w*bv.y; acc[7][2]+=a1.w*bv.z; acc[7][3]+=a1.w*bv.w;
    }
    if (t + 1 < nkt) writeT((t + 1) & 1);
    __syncthreads();
  }

  #pragma unroll
  for (int ri = 0; ri < 8; ++ri)
    *(float4*)(sg.C + (size_t)(i0 + rg + ri) * sg.ldc + (n0 + cg)) =
      make_float4(acc[ri][0], acc[ri][1], acc[ri][2], acc[ri][3]);
}

// ---------- GEMM batch A: grid (16, 8) ----------
__global__ __launch_bounds__(256) void k_gemmA(GArgs2 ga)
{
  __shared__ __align__(16) float xsB[2*4224];
  __shared__ __align__(16) float wsB[2*2176];
  const GSeg2 sg = ga.s[blockIdx.y];
  gemm_body(sg, blockIdx.x & 3, blockIdx.x >> 2, threadIdx.x, xsB, wsB);
}

// ---------- fused pairsel + packxp: grid 512 ----------
__global__ __launch_bounds__(256) void k_packsel(const int* __restrict__ adj,
                                                 const float* __restrict__ Vf,
                                                 float* __restrict__ Xp)
{
  __shared__ unsigned long long msk[8];
  __shared__ int sj[2];
  int i = blockIdx.x, tid = threadIdx.x;
  int w = tid >> 6, lane = tid & 63;
  unsigned long long m0 = __ballot(adj[(size_t)i*kN + tid] != 0);
  unsigned long long m1 = __ballot(adj[(size_t)i*kN + 256 + tid] != 0);
  if (lane == 0){ msk[w] = m0; msk[4 + w] = m1; }
  __syncthreads();
  if (tid == 0){
    int j0 = -1, j1 = -1;
    for (int c = 0; c < 8 && j1 < 0; ++c){
      unsigned long long m = msk[c];
      while (m && j1 < 0){
        int b = __builtin_ctzll(m);
        int j = c*64 + b;
        if (j0 < 0) j0 = j; else j1 = j;
        m &= m - 1;
      }
    }
    if (j1 < 0) j0 = -1;
    sj[0] = j0; sj[1] = j1;
  }
  __syncthreads();
  int j0 = sj[0], j1 = sj[1];
  Xp[(size_t)i*768 + tid]       = Vf[(size_t)i*kIN + tid];
  Xp[(size_t)i*768 + 256 + tid] = (j0 >= 0) ? Vf[(size_t)j0*kIN + tid] : 0.f;
  Xp[(size_t)i*768 + 512 + tid] = (j1 >= 0) ? Vf[(size_t)j1*kIN + tid] : 0.f;
}

// ---------- stage2: [0,128) redH | [128,256) e1 | [256] ub + zero H4v ----------
__global__ __launch_bounds__(256) void k_stage2(WSP w)
{
  __shared__ float sm[64];
  int b = blockIdx.x, tid = threadIdx.x;
  if (b < 128){
    int f = b*256 + tid;           // 32768 float4 per matrix
    int c4 = f & 63;
    {
      float4 a = ((const float4*)w.htp0)[f], bb = ((const float4*)w.htp1)[f];
      float4 bi = ((const float4*)w.tb1f)[c4];
      ((float4*)w.hidden_t)[f] = make_float4(
        fmaxf(a.x+bb.x+bi.x,0.f), fmaxf(a.y+bb.y+bi.y,0.f),
        fmaxf(a.z+bb.z+bi.z,0.f), fmaxf(a.w+bb.w+bi.w,0.f));
    }
    {
      float4 a = ((const float4*)w.hpp0)[f], bb = ((const float4*)w.hpp1)[f];
      float4 c = ((const float4*)w.hpp2)[f];
      float4 bi = ((const float4*)w.pb1f)[c4];
      ((float4*)w.hidden_p)[f] = make_float4(
        fmaxf(a.x+bb.x+c.x+bi.x,0.f), fmaxf(a.y+bb.y+c.y+bi.y,0.f),
        fmaxf(a.z+bb.z+c.z+bi.z,0.f), fmaxf(a.w+bb.w+c.w+bi.w,0.f));
    }
  } else if (b < 256){
    int r = (b-128)*4 + (tid >> 6), lane = tid & 63;
    float a = 0.f;
    for (int k = lane; k < kHID; k += 64) a += w.Wh1[(size_t)r*kHID + k] * w.sa1f[k];
    #pragma unroll
    for (int o = 32; o > 0; o >>= 1) a += __shfl_down(a, o, 64);
    if (lane == 0) w.e1v[r] = a;
  } else {
    if (tid < 64){ sm[tid] = w.ca0f[tid] + w.ca1f[tid]; w.H4v[tid] = 0.f; }
    __syncthreads();
    float a = 0.f;
    for (int d = 0; d < kHD; ++d) a += w.cw2f[(size_t)d*kHID + tid] * sm[d];
    w.uvec[tid] = a;
    if (tid == 0){
      float bsum = 0.f;
      for (int d = 0; d < kHD; ++d) bsum += w.cb2f[d] * sm[d];
      *w.beta = bsum;
    }
  }
}

// ---------- stage3: [0,32) gemmB | [32,544) h1stats | [544,1568) s2 ----------
__global__ __launch_bounds__(256) void k_stage3(WSP w, GArgs2 gb)
{
  __shared__ __align__(16) char smem[51200];
  int b = blockIdx.x, tid = threadIdx.x;
  if (b < 32){
    const GSeg2 sg = gb.s[b >> 2];
    gemm_body(sg, b & 3, 0, tid, (float*)smem, (float*)(smem + 33792));
  } else if (b < 544){
    float* red = (float*)smem;
    int i = b - 32;
    int m0 = w.adj[(size_t)i*kN + tid];
    int m1 = w.adj[(size_t)i*kN + tid + 256];
    float ea = w.e1v[tid], eb = w.e1v[tid+256];
    float v0 = m0 ? ea : -1e30f;
    float v1 = m1 ? eb : -1e30f;
    float m = blk_red(fmaxf(v0, v1), red, true);
    float z = blk_red((m0 ? expf(ea-m) : 0.f) + (m1 ? expf(eb-m) : 0.f), red, false);
    if (tid == 0){ w.minv[i] = m; w.invzv[i] = 1.0f / z; }
  } else {
    float* aib = (float*)smem;                 // [4][256]
    float* uu  = (float*)(smem + 4096);        // [256]
    int q = b - 544;
    int i0 = (q & 127) * 4, j0 = (q >> 7) * 64;
    int wv = tid >> 6, lane = tid & 63;
    uu[tid] = w.uvec[tid];
    float b1v = w.cb1f[tid];
    #pragma unroll
    for (int r = 0; r < 4; ++r) aib[r*256 + tid] = w.Am[(size_t)(i0+r)*kHID + tid] + b1v;
    __syncthreads();
    int i = i0 + wv, j = j0 + lane;
    const float4* bp = (const float4*)(w.Bm + (size_t)j*kHID);
    float acc = *w.beta;
    #pragma unroll 8
    for (int k4 = 0; k4 < kHID/4; ++k4){
      float4 bv = bp[k4];
      float4 a4 = *(const float4*)&aib[wv*256 + k4*4];
      float4 u4 = *(const float4*)&uu[k4*4];
      acc += fmaxf(a4.x+bv.x,0.f)*u4.x + fmaxf(a4.y+bv.y,0.f)*u4.y
           + fmaxf(a4.z+bv.z,0.f)*u4.z + fmaxf(a4.w+bv.w,0.f)*u4.w;
    }
    if (j == i) acc = -1e30f;
    w.s2[(size_t)i*kN + j] = acc;
    float m = acc;
    #pragma unroll
    for (int o = 32; o > 0; o >>= 1) m = fmaxf(m, __shfl_down(m, o, 64));
    m = __shfl(m, 0, 64);
    float e = expf(acc - m);
    #pragma unroll
    for (int o = 32; o > 0; o >>= 1) e += __shfl_down(e, o, 64);
    if (lane == 0){
      int pb = q*4 + wv;
      w.maxp[pb] = m; w.zp[pb] = e;
    }
  }
}

// ---------- stage4: [0,32) redB+h4 | [32,1056) h1p | [1056] mz + zero gsum ----------
__global__ __launch_bounds__(256) void k_stage4(WSP w)
{
  __shared__ __align__(16) char smem[4096];
  int b = blockIdx.x, tid = threadIdx.x;
  if (b < 32){
    int f = b*256 + tid;             // 8192 float4 per matrix, exact
    int c4 = f & 15;
    {
      float4 a = ((const float4*)w.tfp0)[f], bb = ((const float4*)w.tfp1)[f];
      float4 c = ((const float4*)w.tfp2)[f], d = ((const float4*)w.tfp3)[f];
      float4 bi = ((const float4*)w.tb2f)[c4];
      ((float4*)w.tfm)[f] = make_float4(a.x+bb.x+c.x+d.x+bi.x, a.y+bb.y+c.y+d.y+bi.y,
                                        a.z+bb.z+c.z+d.z+bi.z, a.w+bb.w+c.w+d.w+bi.w);
    }
    float4 cc;
    {
      float4 a = ((const float4*)w.cfp0)[f], bb = ((const float4*)w.cfp1)[f];
      float4 c = ((const float4*)w.cfp2)[f], d = ((const float4*)w.cfp3)[f];
      float4 bi = ((const float4*)w.pb2f)[c4];
      cc = make_float4(a.x+bb.x+c.x+d.x+bi.x, a.y+bb.y+c.y+d.y+bi.y,
                       a.z+bb.z+c.z+d.z+bi.z, a.w+bb.w+c.w+d.w+bi.w);
      ((float4*)w.cfm)[f] = cc;
    }
    float4* red4 = (float4*)smem;    // [256] would be 4KB exactly for 16x16
    red4[tid] = cc;
    __syncthreads();
    #pragma unroll
    for (int st = 128; st >= 16; st >>= 1){
      if (tid < st){
        float4 x = red4[tid], y = red4[tid + st];
        red4[tid] = make_float4(x.x+y.x, x.y+y.y, x.z+y.z, x.w+y.w);
      }
      __syncthreads();
    }
    if (tid < 16){
      float4 v = red4[tid];
      atomicAdd(&w.H4v[tid*4+0], v.x);
      atomicAdd(&w.H4v[tid*4+1], v.y);
      atomicAdd(&w.H4v[tid*4+2], v.z);
      atomicAdd(&w.H4v[tid*4+3], v.w);
    }
  } else if (b < 1056){
    float* wt = (float*)smem;        // [4][64]
    int q = b - 32;
    int i0 = (q & 127) * 4, jt = q >> 7, j0 = jt * 64;
    {
      int r = tid >> 6, jj = tid & 63;
      int j = j0 + jj;
      wt[r*64 + jj] = w.adj[(size_t)(i0+r)*kN + j]
                    ? expf(w.e1v[j] - w.minv[i0+r]) * w.invzv[i0+r] : 0.f;
    }
    __syncthreads();
    float a0=0,a1=0,a2=0,a3=0;
    #pragma unroll 4
    for (int jj = 0; jj < 64; ++jj){
      float wh = w.Wh1[(size_t)(j0+jj)*kHID + tid];
      a0 += wt[jj]*wh; a1 += wt[64+jj]*wh; a2 += wt[128+jj]*wh; a3 += wt[192+jj]*wh;
    }
    size_t base = ((size_t)jt*kN + i0)*kHID + tid;
    w.H1p[base]          = a0;
    w.H1p[base + kHID]   = a1;
    w.H1p[base + 2*kHID] = a2;
    w.H1p[base + 3*kHID] = a3;
  } else {
    float* red = (float*)smem;
    float m = -1e30f;
    #pragma unroll
    for (int r = 0; r < 16; ++r) m = fmaxf(m, w.maxp[tid + 256*r]);
    m = blk_red(m, red, true);
    float z = 0.f;
    #pragma unroll
    for (int r = 0; r < 16; ++r) z += w.zp[tid + 256*r] * expf(w.maxp[tid + 256*r] - m);
    z = blk_red(z, red, false);
    if (tid == 0){ w.MZ[0] = m; w.MZ[1] = z; }
    w.gsum[tid] = 0.f;
  }
}

// ---------- stage5: [0,1024) gpart | [1024,1536) h1r | [1536,1600) h3 ----------
__global__ __launch_bounds__(256) void k_stage5(WSP w)
{
  __shared__ __align__(16) char smem[1536];
  int b = blockIdx.x, tid = threadIdx.x;
  if (b < 1024){
    float* wt = (float*)smem;        // [16][16]
    int i0 = (b & 31) * 16, j0 = (b >> 5) * 16;
    float M = w.MZ[0], invZ = 1.0f / w.MZ[1];
    {
      int r = tid >> 4, c = tid & 15;
      wt[r*16 + c] = expf(w.s2[(size_t)(i0+r)*kN + (j0+c)] - M) * invZ;
    }
    float b1v = w.cb1f[tid];
    float aib[16];
    #pragma unroll
    for (int r = 0; r < 16; ++r) aib[r] = w.Am[(size_t)(i0+r)*kHID + tid] + b1v;
    __syncthreads();
    float acc = 0.f;
    for (int j = 0; j < 16; ++j){
      float bj = w.Bm[(size_t)(j0+j)*kHID + tid];
      #pragma unroll
      for (int r = 0; r < 16; ++r)
        acc += wt[r*16 + j] * fmaxf(aib[r] + bj, 0.f);
    }
    atomicAdd(&w.gsum[tid], acc);
  } else if (b < 1536){
    int i = b - 1024;
    float s = 0.f;
    #pragma unroll
    for (int jt = 0; jt < 8; ++jt)
      s += w.H1p[((size_t)jt*kN + i)*kHID + tid];
    w.H1[(size_t)i*kHID + tid] = s;
  } else {
    int d = b - 1536;
    int lane = tid & 63, wv = tid >> 6;
    float v0 = w.tfm[(size_t)(2*tid)*kHD + d];
    float v1 = w.tfm[(size_t)(2*tid+1)*kHD + d];
    float s = v0 + v1;
    float x = s;
    #pragma unroll
    for (int off = 1; off < 64; off <<= 1){
      float y = __shfl_up(x, off, 64);
      if (lane >= off) x += y;
    }
    float* wsum = (float*)smem;
    if (lane == 63) wsum[wv] = x;
    __syncthreads();
    float base = 0.f;
    for (int k = 0; k < wv; ++k) base += wsum[k];
    float excl = base + x - s;
    w.H3[(size_t)(2*tid)*kHD + d]   = (excl + v0) / (float)(2*tid + 1);
    w.H3[(size_t)(2*tid+1)*kHD + d] = (excl + s)  / (float)(2*tid + 2);
  }
}

// ---------- h2c: H2vec then c2[o] = sum_d H2vec[d]*W2[o,256+d] (1 block) ----------
__global__ void k_h2c(WSP w)
{
  __shared__ float gs[kHID];
  __shared__ float part[kHD][4];
  __shared__ float h2s[kHD];
  int tid = threadIdx.x;
  gs[tid] = w.gsum[tid];
  __syncthreads();
  int d = tid >> 2, q = tid & 3;
  float a = 0.f;
  for (int kk = 0; kk < 64; ++kk){
    int k = q*64 + kk;
    a += gs[k] * w.cw2f[(size_t)d*kHID + k];
  }
  part[d][q] = a;
  __syncthreads();
  if (tid < kHD)
    h2s[tid] = w.cb2f[tid] + part[tid][0] + part[tid][1] + part[tid][2] + part[tid][3];
  __syncthreads();
  float c = 0.f;
  const float* wr = w.W2f + (size_t)tid*385 + 256;
  for (int dd = 0; dd < kHD; ++dd) c += h2s[dd] * wr[dd];
  w.c2v[tid] = c;
}

// ---------- fused out2 + final: grid 512 ----------
__global__ __launch_bounds__(256) void k_outfin(WSP w)
{
  __shared__ float h1s[kHID];
  __shared__ float h3s[kHD];
  __shared__ float row[kOUT];
  __shared__ float red[8];
  __shared__ float h4sh;
  int i = blockIdx.x, o = threadIdx.x;
  h1s[o] = w.H1[(size_t)i*kHID + o];
  if (o < kHD) h3s[o] = w.H3[(size_t)i*kHD + o];
  if (o == 0)  h4sh = (i < kHD) ? w.H4v[i] : 0.f;
  __syncthreads();
  const float* wr = w.W2f + (size_t)o * 385;
  float acc = w.c2v[o];
  for (int k = 0; k < kHID; ++k) acc += h1s[k] * wr[k];
  for (int dd = 0; dd < kHD; ++dd) acc += h3s[dd] * wr[320+dd];
  acc += h4sh * wr[384];
  row[o] = acc;
  __syncthreads();
  const float4* opr = (const float4*)(w.opwf + (size_t)o * kOUT);
  float a2 = w.opbf[o];
  for (int kb = 0; kb < 64; ++kb){
    float4 qv = opr[kb];
    a2 += row[kb*4]*qv.x + row[kb*4+1]*qv.y + row[kb*4+2]*qv.z + row[kb*4+3]*qv.w;
  }
  float mu = blk_red(a2, red, false) * (1.0f/kOUT);
  float dv = a2 - mu;
  float var = blk_red(dv*dv, red, false) * (1.0f/kOUT);
  float y = dv * rsqrtf(var + 1e-5f) * w.lngf[o] + w.lnbf[o];
  y = (y > 0.f) ? y : expm1f(y);
  if (*w.flag) ((float*)w.out)[(size_t)i*kOUT + o] = y;
  else         ((u16*)w.out)[(size_t)i*kOUT + o]   = f2us(y);
}

extern "C" void kernel_launch(void* const* d_in, const int* in_sizes, int n_in,
                              void* d_out, int out_size, void* d_ws, size_t ws_size,
                              hipStream_t stream)
{
  const void* V     = d_in[0];
  const int*  adj   = (const int*)d_in[1];
  const void* prev  = d_in[2];
  const void* W1    = d_in[3];
  // d_in[4] = sa0 : dead (row-shift invariant softmax)
  const void* sa1   = d_in[5];
  const void* ce_w1 = d_in[6];
  const void* ce_b1 = d_in[7];
  const void* ce_w2 = d_in[8];
  const void* ce_b2 = d_in[9];
  const void* ca0   = d_in[10];
  const void* ca1   = d_in[11];
  const void* te_w1 = d_in[12];
  const void* te_b1 = d_in[13];
  const void* te_w2 = d_in[14];
  const void* te_b2 = d_in[15];
  // d_in[16,17] = ta0,ta1 : dead
  const void* pe_w1 = d_in[18];
  const void* pe_b1 = d_in[19];
  const void* pe_w2 = d_in[20];
  const void* pe_b2 = d_in[21];
  // d_in[22,23] = pa0,pa1 : dead
  const void* W2    = d_in[24];
  const void* op_w  = d_in[25];
  const void* op_b  = d_in[26];
  const void* ln_g  = d_in[27];
  const void* ln_b  = d_in[28];

  // ---- workspace layout (floats) ----
  float* ws  = (float*)d_ws;
  int*  flag = (int*)ws;               // 16 floats reserved
  float* p   = ws + 16;
  float* Vf   = p; p += 131072;
  float* prevf= p; p += 131072;
  float* W1f  = p; p += 65536;
  float* sa1f = p; p += 256;
  float* cw1f = p; p += 131072;
  float* cb1f = p; p += 256;
  float* cw2f = p; p += 16384;
  float* cb2f = p; p += 64;
  float* ca0f = p; p += 64;
  float* ca1f = p; p += 64;
  float* tw1f = p; p += 131072;
  float* tb1f = p; p += 256;
  float* tw2f = p; p += 16384;
  float* tb2f = p; p += 64;
  float* pw1f = p; p += 196608;
  float* pb1f = p; p += 256;
  float* pw2f = p; p += 16384;
  float* pb2f = p; p += 64;
  float* W2f  = p; p += 98560;
  float* opwf = p; p += 65536;
  float* opbf = p; p += 256;
  float* lngf = p; p += 256;
  float* lnbf = p; p += 256;
  float* Wh1      = p; p += 131072;
  float* e1v      = p; p += 512;
  float* minv     = p; p += 512;
  float* invzv    = p; p += 512;
  float* H1p      = p; p += 1048576;
  float* H1       = p; p += 131072;
  float* Am       = p; p += 131072;
  float* Bm       = p; p += 131072;
  float* uvec     = p; p += 256;
  float* beta     = p; p += 16;
  float* s2       = p; p += 262144;
  float* maxp     = p; p += 4096;
  float* zpart    = p; p += 4096;
  float* MZ       = p; p += 16;
  float* gsum     = p; p += 256;
  float* c2v      = p; p += 256;
  float* htp0     = p; p += 131072;
  float* htp1     = p; p += 131072;
  float* hpp0     = p; p += 131072;
  float* hpp1     = p; p += 131072;
  float* hpp2     = p; p += 131072;
  float* hidden_t = p; p += 131072;
  float* hidden_p = p; p += 131072;
  float* tfp0     = p; p += 32768;
  float* tfp1     = p; p += 32768;
  float* tfp2     = p; p += 32768;
  float* tfp3     = p; p += 32768;
  float* cfp0     = p; p += 32768;
  float* cfp1     = p; p += 32768;
  float* cfp2     = p; p += 32768;
  float* cfp3     = p; p += 32768;
  float* tfm      = p; p += 32768;
  float* cfm      = p; p += 32768;
  float* H3       = p; p += 32768;
  float* H4v      = p; p += 64;
  float* Xp       = p; p += 393216;

  // ---- dtype probe + input widening ----
  k_probe<<<1, 256, 0, stream>>>((const unsigned int*)V, flag);
  ConvArgs ca;
  const void* srcs[23] = {V, prev, W1, sa1, ce_w1, ce_b1, ce_w2, ce_b2, ca0, ca1,
                          te_w1, te_b1, te_w2, te_b2, pe_w1, pe_b1, pe_w2, pe_b2,
                          W2, op_w, op_b, ln_g, ln_b};
  float* dsts[23] = {Vf, prevf, W1f, sa1f, cw1f, cb1f, cw2f, cb2f, ca0f, ca1f,
                     tw1f, tb1f, tw2f, tb2f, pw1f, pb1f, pw2f, pb2f,
                     W2f, opwf, opbf, lngf, lnbf};
  int ns[23] = {131072, 131072, 65536, 256, 131072, 256, 16384, 64, 64, 64,
                131072, 256, 16384, 64, 196608, 256, 16384, 64,
                98560, 65536, 256, 256, 256};
  for (int s = 0; s < 23; ++s){ ca.src[s] = srcs[s]; ca.dst[s] = dsts[s]; ca.n[s] = ns[s]; }
  k_convert_all<<<256, 256, 0, stream>>>(ca, flag);

  // ---- pointer bundle ----
  WSP w;
  w.adj = adj; w.flag = flag; w.out = d_out;
  w.Vf=Vf; w.prevf=prevf; w.W1f=W1f; w.sa1f=sa1f; w.cw1f=cw1f; w.cb1f=cb1f;
  w.cw2f=cw2f; w.cb2f=cb2f; w.ca0f=ca0f; w.ca1f=ca1f;
  w.tw1f=tw1f; w.tb1f=tb1f; w.tw2f=tw2f; w.tb2f=tb2f;
  w.pw1f=pw1f; w.pb1f=pb1f; w.pw2f=pw2f; w.pb2f=pb2f;
  w.W2f=W2f; w.opwf=opwf; w.opbf=opbf; w.lngf=lngf; w.lnbf=lnbf;
  w.Wh1=Wh1; w.e1v=e1v; w.minv=minv; w.invzv=invzv; w.H1p=H1p; w.H1=H1;
  w.Am=Am; w.Bm=Bm; w.uvec=uvec; w.beta=beta;
  w.s2=s2; w.maxp=maxp; w.zp=zpart; w.MZ=MZ; w.gsum=gsum; w.c2v=c2v;
  w.htp0=htp0; w.htp1=htp1; w.hpp0=hpp0; w.hpp1=hpp1; w.hpp2=hpp2;
  w.hidden_t=hidden_t; w.hidden_p=hidden_p;
  w.tfp0=tfp0; w.tfp1=tfp1; w.tfp2=tfp2; w.tfp3=tfp3;
  w.cfp0=cfp0; w.cfp1=cfp1; w.cfp2=cfp2; w.cfp3=cfp3;
  w.tfm=tfm; w.cfm=cfm; w.H3=H3; w.H4v=H4v; w.Xp=Xp;

  // ---- pair-branch input prep (ballot pairsel + gather) ----
  k_packsel<<<kN, 256, 0, stream>>>(adj, Vf, Xp);

  // ---- GEMM batch A: 8 segs x 16 tiles = 128 blocks ----
  {
    GArgs2 g{};
    g.s[0] = {Vf,       W1f,        Wh1,  256, 256, 256, 256};
    g.s[1] = {Vf,       cw1f,       Am,   256, 512, 256, 256};
    g.s[2] = {Vf,       cw1f + 256, Bm,   256, 512, 256, 256};
    g.s[3] = {Vf,       tw1f,       htp0, 256, 512, 256, 256};
    g.s[4] = {prevf,    tw1f + 256, htp1, 256, 512, 256, 256};
    g.s[5] = {Xp,       pw1f,       hpp0, 768, 768, 256, 256};
    g.s[6] = {Xp + 256, pw1f + 256, hpp1, 768, 768, 256, 256};
    g.s[7] = {Xp + 512, pw1f + 512, hpp2, 768, 768, 256, 256};
    k_gemmA<<<dim3(16, 8), 256, 0, stream>>>(g);
  }

  // ---- stage2: redH | e1 | ub (+zero H4v) ----
  k_stage2<<<257, 256, 0, stream>>>(w);

  // ---- stage3: gemmB (split-K4) | h1stats | s2 ----
  {
    GArgs2 gb{};
    for (int k = 0; k < 4; ++k){
      gb.s[k]   = {hidden_t + 64*k, tw2f + 64*k,
                   (k==0?tfp0:k==1?tfp1:k==2?tfp2:tfp3), 256, 256, 64, 64};
      gb.s[4+k] = {hidden_p + 64*k, pw2f + 64*k,
                   (k==0?cfp0:k==1?cfp1:k==2?cfp2:cfp3), 256, 256, 64, 64};
    }
    k_stage3<<<1568, 256, 0, stream>>>(w, gb);
  }

  // ---- stage4: redB+h4 | h1p | mz (+zero gsum) ----
  k_stage4<<<1057, 256, 0, stream>>>(w);

  // ---- stage5: gpart | h1r | h3 ----
  k_stage5<<<1600, 256, 0, stream>>>(w);

  // ---- h2 -> c2 ----
  k_h2c<<<1, 256, 0, stream>>>(w);

  // ---- fused out2 + final ----
  k_outfin<<<kN, 256, 0, stream>>>(w);
}

// Round 5
// 271.697 us; speedup vs baseline: 1.6293x; 1.0218x over previous
//
#include <hip/hip_runtime.h>

typedef unsigned short u16;

constexpr int kN   = 512;
constexpr int kIN  = 256;
constexpr int kHID = 256;
constexpr int kHD  = 64;
constexpr int kOUT = 256;

// ---------- bf16 helpers ----------
__device__ __forceinline__ float us2f(u16 u){
  union { unsigned int i; float f; } c; c.i = ((unsigned int)u) << 16; return c.f;
}
__device__ __forceinline__ u16 f2us(float f){
  union { float f; unsigned int i; } c; c.f = f;
  unsigned int r = c.i + 0x7fff + ((c.i >> 16) & 1);
  return (u16)(r >> 16);
}

// ---------- per-block dtype probe (reads first 16KB of V) ----------
__device__ bool probe_is_f32(const unsigned int* __restrict__ V){
  __shared__ int cnt;
  if (threadIdx.x == 0) cnt = 0;
  __syncthreads();
  int c = 0;
  for (int k = threadIdx.x; k < 4096; k += 256){
    float x = us2f((u16)(V[k] & 0xffffu));
    if (!(fabsf(x) <= 32.0f)) c++;
  }
  atomicAdd(&cnt, c);
  __syncthreads();
  return cnt > 64;
}

// ---------- fused convert + probe + pairsel/packxp ----------
struct ConvArgs { const void* src[23]; float* dst[23]; int n[23]; };

__global__ __launch_bounds__(256) void k_conv(ConvArgs a, const unsigned int* __restrict__ Vraw,
                                              const int* __restrict__ adj, int* __restrict__ flag,
                                              float* __restrict__ Xp)
{
  int b = blockIdx.x, tid = threadIdx.x;
  bool f32 = probe_is_f32(Vraw);
  if (b < 256){
    if (b == 0 && tid == 0) *flag = f32 ? 1 : 0;
    int t = b*256 + tid;
    const int stride = 65536;
    for (int s = 0; s < 23; ++s){
      int n4 = a.n[s] >> 2;
      float4* d = (float4*)a.dst[s];
      if (f32){
        const float4* sf = (const float4*)a.src[s];
        for (int i = t; i < n4; i += stride) d[i] = sf[i];
      } else {
        const ushort4* sb = (const ushort4*)a.src[s];
        for (int i = t; i < n4; i += stride){
          ushort4 u = sb[i];
          d[i] = make_float4(us2f(u.x), us2f(u.y), us2f(u.z), us2f(u.w));
        }
      }
    }
  } else {
    // pairsel + packxp for row i (inline bf16 decode)
    __shared__ unsigned long long msk[8];
    __shared__ int sj[2];
    int i = b - 256;
    int w = tid >> 6, lane = tid & 63;
    unsigned long long m0 = __ballot(adj[(size_t)i*kN + tid] != 0);
    unsigned long long m1 = __ballot(adj[(size_t)i*kN + 256 + tid] != 0);
    if (lane == 0){ msk[w] = m0; msk[4 + w] = m1; }
    __syncthreads();
    if (tid == 0){
      int j0 = -1, j1 = -1;
      for (int c = 0; c < 8 && j1 < 0; ++c){
        unsigned long long m = msk[c];
        while (m && j1 < 0){
          int bb = __builtin_ctzll(m);
          int j = c*64 + bb;
          if (j0 < 0) j0 = j; else j1 = j;
          m &= m - 1;
        }
      }
      if (j1 < 0) j0 = -1;
      sj[0] = j0; sj[1] = j1;
    }
    __syncthreads();
    int j0 = sj[0], j1 = sj[1];
    const float* Vf = (const float*)Vraw;
    const u16*  Vb = (const u16*)Vraw;
    auto rdV = [&](int r, int k)->float{
      return f32 ? Vf[(size_t)r*kIN + k] : us2f(Vb[(size_t)r*kIN + k]);
    };
    Xp[(size_t)i*768 + tid]       = rdV(i, tid);
    Xp[(size_t)i*768 + 256 + tid] = (j0 >= 0) ? rdV(j0, tid) : 0.f;
    Xp[(size_t)i*768 + 512 + tid] = (j1 >= 0) ? rdV(j1, tid) : 0.f;
  }
}

// ---------- block reduction (256 threads) ----------
__device__ __forceinline__ float blk_red(float v, float* tmp, bool isMax){
  int lane = threadIdx.x & 63, wv = threadIdx.x >> 6;
  #pragma unroll
  for (int o = 32; o > 0; o >>= 1){
    float t = __shfl_down(v, o, 64);
    v = isMax ? fmaxf(v, t) : (v + t);
  }
  __syncthreads();
  if (lane == 0) tmp[wv] = v;
  __syncthreads();
  float r = tmp[0];
  for (int i = 1; i < 4; ++i) r = isMax ? fmaxf(r, tmp[i]) : (r + tmp[i]);
  return r;
}

// ---------- workspace pointer bundle ----------
struct WSP {
  const int* adj; const int* flag; void* out;
  float *Vf,*prevf,*W1f,*sa1f,*cw1f,*cb1f,*cw2f,*cb2f,*ca0f,*ca1f;
  float *tw1f,*tb1f,*tw2f,*tb2f,*pw1f,*pb1f,*pw2f,*pb2f;
  float *W2f,*opwf,*opbf,*lngf,*lnbf;
  float *tw2t,*pw2t,*W2t;
  float *Wh1,*e1v,*minv,*invzv,*H1p,*H1,*Am,*Bm,*uvec,*beta;
  float *s2,*maxp,*zp,*MZ,*gsum;
  float *htp0,*htp1,*hpp0,*hpp1,*hpp2,*hidden_t,*hidden_p;
  float *tfm,*cfm,*H3,*H4v,*Xp;
};

// ================== GEMM A: 32x64 tile, BK=32, 2x4 micro, dbuf ==================
struct GSeg2 { const float* X; const float* W; float* C; int ldx, ldw, ldc, K; };
struct GArgs2 { GSeg2 s[8]; };

__global__ __launch_bounds__(256) void k_gemmA(GArgs2 ga)
{
  __shared__ __align__(16) float Xs[2][32][36];
  __shared__ __align__(16) float Ws[2][32][68];
  const GSeg2 sg = ga.s[blockIdx.y];
  const int tm = blockIdx.x & 15;      // 16 m-tiles of 32 rows
  const int tn = blockIdx.x >> 4;      // 4 n-tiles of 64 cols
  const int i0 = tm << 5;
  const int n0 = tn << 6;
  const int tid = threadIdx.x;

  const int xrow = tid >> 3;           // 0..31
  const int xk   = (tid & 7) << 2;     // 0..28
  const int rg = (tid >> 4) << 1;      // 0..30 (2 rows)
  const int cg = (tid & 15) << 2;      // 0..60 (4 cols)

  const float* Xb = sg.X + (size_t)i0 * sg.ldx;
  const float* Wb = sg.W + (size_t)n0 * sg.ldw;

  float4 xr, wr0, wr1;
  auto loadT = [&](int kt){
    xr  = *(const float4*)(Xb + (size_t)xrow * sg.ldx + kt + xk);
    wr0 = *(const float4*)(Wb + (size_t)xrow * sg.ldw + kt + xk);
    wr1 = *(const float4*)(Wb + (size_t)(xrow+32) * sg.ldw + kt + xk);
  };
  auto writeT = [&](int bu){
    Xs[bu][xk+0][xrow] = xr.x;  Xs[bu][xk+1][xrow] = xr.y;
    Xs[bu][xk+2][xrow] = xr.z;  Xs[bu][xk+3][xrow] = xr.w;
    Ws[bu][xk+0][xrow]    = wr0.x; Ws[bu][xk+1][xrow]    = wr0.y;
    Ws[bu][xk+2][xrow]    = wr0.z; Ws[bu][xk+3][xrow]    = wr0.w;
    Ws[bu][xk+0][xrow+32] = wr1.x; Ws[bu][xk+1][xrow+32] = wr1.y;
    Ws[bu][xk+2][xrow+32] = wr1.z; Ws[bu][xk+3][xrow+32] = wr1.w;
  };

  loadT(0); writeT(0); __syncthreads();

  float acc[2][4] = {};
  const int nkt = sg.K >> 5;
  for (int t = 0; t < nkt; ++t){
    if (t + 1 < nkt) loadT((t + 1) << 5);
    const int bu = t & 1;
    #pragma unroll
    for (int kk = 0; kk < 32; ++kk){
      const float2 av = *(const float2*)&Xs[bu][kk][rg];
      const float4 bv = *(const float4*)&Ws[bu][kk][cg];
      acc[0][0]+=av.x*bv.x; acc[0][1]+=av.x*bv.y; acc[0][2]+=av.x*bv.z; acc[0][3]+=av.x*bv.w;
      acc[1][0]+=av.y*bv.x; acc[1][1]+=av.y*bv.y; acc[1][2]+=av.y*bv.z; acc[1][3]+=av.y*bv.w;
    }
    if (t + 1 < nkt) writeT((t + 1) & 1);
    __syncthreads();
  }

  #pragma unroll
  for (int ri = 0; ri < 2; ++ri)
    *(float4*)(sg.C + (size_t)(i0 + rg + ri) * sg.ldc + (n0 + cg)) =
      make_float4(acc[ri][0], acc[ri][1], acc[ri][2], acc[ri][3]);
}

// ---------- stage2: [0,128) redH | [128,256) e1 | 256 ub+zeroH4v | 257,258 w2-small transposes | [259,356) W2t ----------
__global__ __launch_bounds__(256) void k_stage2(WSP w)
{
  __shared__ float st[64*65];
  int b = blockIdx.x, tid = threadIdx.x;
  if (b < 128){
    int f = b*256 + tid;           // 32768 float4 per matrix
    int c4 = f & 63;
    {
      float4 a = ((const float4*)w.htp0)[f], bb = ((const float4*)w.htp1)[f];
      float4 bi = ((const float4*)w.tb1f)[c4];
      ((float4*)w.hidden_t)[f] = make_float4(
        fmaxf(a.x+bb.x+bi.x,0.f), fmaxf(a.y+bb.y+bi.y,0.f),
        fmaxf(a.z+bb.z+bi.z,0.f), fmaxf(a.w+bb.w+bi.w,0.f));
    }
    {
      float4 a = ((const float4*)w.hpp0)[f], bb = ((const float4*)w.hpp1)[f];
      float4 c = ((const float4*)w.hpp2)[f];
      float4 bi = ((const float4*)w.pb1f)[c4];
      ((float4*)w.hidden_p)[f] = make_float4(
        fmaxf(a.x+bb.x+c.x+bi.x,0.f), fmaxf(a.y+bb.y+c.y+bi.y,0.f),
        fmaxf(a.z+bb.z+c.z+bi.z,0.f), fmaxf(a.w+bb.w+c.w+bi.w,0.f));
    }
  } else if (b < 256){
    int r = (b-128)*4 + (tid >> 6), lane = tid & 63;
    float a = 0.f;
    for (int k = lane; k < kHID; k += 64) a += w.Wh1[(size_t)r*kHID + k] * w.sa1f[k];
    #pragma unroll
    for (int o = 32; o > 0; o >>= 1) a += __shfl_down(a, o, 64);
    if (lane == 0) w.e1v[r] = a;
  } else if (b == 256){
    if (tid < 64){ st[tid] = w.ca0f[tid] + w.ca1f[tid]; w.H4v[tid] = 0.f; }
    __syncthreads();
    float a = 0.f;
    for (int d = 0; d < kHD; ++d) a += w.cw2f[(size_t)d*kHID + tid] * st[d];
    w.uvec[tid] = a;
    if (tid == 0){
      float bsum = 0.f;
      for (int d = 0; d < kHD; ++d) bsum += w.cb2f[d] * st[d];
      *w.beta = bsum;
    }
  } else if (b < 259){
    // transpose 64x256 -> 256x64 (tw2 or pw2)
    const float* src = (b == 257) ? w.tw2f : w.pw2f;
    float* dst = (b == 257) ? w.tw2t : w.pw2t;
    for (int ch = 0; ch < 4; ++ch){
      __syncthreads();
      #pragma unroll
      for (int e = 0; e < 16; ++e){
        int lin = e*256 + tid;
        int r = lin >> 6, c = lin & 63;
        st[r*65 + c] = src[(size_t)r*256 + ch*64 + c];
      }
      __syncthreads();
      #pragma unroll
      for (int e = 0; e < 16; ++e){
        int lin = e*256 + tid;
        int kc = lin >> 6, dd = lin & 63;
        dst[(size_t)(ch*64 + kc)*64 + dd] = st[dd*65 + kc];
      }
    }
  } else {
    // W2 transpose: W2t[c*256+o] = W2f[o*385+c]; 97 blocks x 4 cols
    int c0 = (b - 259) * 4;
    for (int cc = 0; cc < 4; ++cc){
      int c = c0 + cc;
      if (c < 385) w.W2t[(size_t)c*256 + tid] = w.W2f[(size_t)tid*385 + c];
    }
  }
}

// ---------- stage3: [0,64) gemmB(reg) | [64,576) h1stats | [576,1600) s2 ----------
__global__ __launch_bounds__(256) void k_stage3(WSP w)
{
  __shared__ __align__(16) float smem3[4*256 + 256];
  int b = blockIdx.x, tid = threadIdx.x;
  if (b < 64){
    int m = b >> 5, grp = b & 31;
    const float* X  = m ? w.hidden_p : w.hidden_t;
    const float* Wt = m ? w.pw2t : w.tw2t;
    const float* bi = m ? w.pb2f : w.tb2f;
    float* C = m ? w.cfm : w.tfm;
    int i0 = grp*16 + (tid >> 6)*4;
    int d = tid & 63;
    const float* x0 = X + (size_t)i0*256;
    const float* x1 = x0 + 256;
    const float* x2 = x0 + 512;
    const float* x3 = x0 + 768;
    float a0=0.f, a1=0.f, a2=0.f, a3=0.f;
    for (int k = 0; k < 256; k += 4){
      float w0 = Wt[(size_t)(k+0)*64 + d];
      float w1 = Wt[(size_t)(k+1)*64 + d];
      float w2 = Wt[(size_t)(k+2)*64 + d];
      float w3 = Wt[(size_t)(k+3)*64 + d];
      float4 f0 = *(const float4*)(x0 + k);
      float4 f1 = *(const float4*)(x1 + k);
      float4 f2 = *(const float4*)(x2 + k);
      float4 f3 = *(const float4*)(x3 + k);
      a0 += f0.x*w0 + f0.y*w1 + f0.z*w2 + f0.w*w3;
      a1 += f1.x*w0 + f1.y*w1 + f1.z*w2 + f1.w*w3;
      a2 += f2.x*w0 + f2.y*w1 + f2.z*w2 + f2.w*w3;
      a3 += f3.x*w0 + f3.y*w1 + f3.z*w2 + f3.w*w3;
    }
    float bd = bi[d];
    C[(size_t)(i0+0)*64 + d] = a0 + bd;
    C[(size_t)(i0+1)*64 + d] = a1 + bd;
    C[(size_t)(i0+2)*64 + d] = a2 + bd;
    C[(size_t)(i0+3)*64 + d] = a3 + bd;
  } else if (b < 576){
    float* red = smem3;
    int i = b - 64;
    int m0 = w.adj[(size_t)i*kN + tid];
    int m1 = w.adj[(size_t)i*kN + tid + 256];
    float ea = w.e1v[tid], eb = w.e1v[tid+256];
    float v0 = m0 ? ea : -1e30f;
    float v1 = m1 ? eb : -1e30f;
    float m = blk_red(fmaxf(v0, v1), red, true);
    float z = blk_red((m0 ? expf(ea-m) : 0.f) + (m1 ? expf(eb-m) : 0.f), red, false);
    if (tid == 0){ w.minv[i] = m; w.invzv[i] = 1.0f / z; }
  } else {
    float* aib = smem3;                 // [4][256]
    float* uu  = smem3 + 1024;          // [256]
    int q = b - 576;
    int i0 = (q & 127) * 4, j0 = (q >> 7) * 64;
    int wv = tid >> 6, lane = tid & 63;
    uu[tid] = w.uvec[tid];
    float b1v = w.cb1f[tid];
    #pragma unroll
    for (int r = 0; r < 4; ++r) aib[r*256 + tid] = w.Am[(size_t)(i0+r)*kHID + tid] + b1v;
    __syncthreads();
    int i = i0 + wv, j = j0 + lane;
    const float4* bp = (const float4*)(w.Bm + (size_t)j*kHID);
    float acc = *w.beta;
    #pragma unroll 8
    for (int k4 = 0; k4 < kHID/4; ++k4){
      float4 bv = bp[k4];
      float4 a4 = *(const float4*)&aib[wv*256 + k4*4];
      float4 u4 = *(const float4*)&uu[k4*4];
      acc += fmaxf(a4.x+bv.x,0.f)*u4.x + fmaxf(a4.y+bv.y,0.f)*u4.y
           + fmaxf(a4.z+bv.z,0.f)*u4.z + fmaxf(a4.w+bv.w,0.f)*u4.w;
    }
    if (j == i) acc = -1e30f;
    w.s2[(size_t)i*kN + j] = acc;
    float m = acc;
    #pragma unroll
    for (int o = 32; o > 0; o >>= 1) m = fmaxf(m, __shfl_down(m, o, 64));
    m = __shfl(m, 0, 64);
    float e = expf(acc - m);
    #pragma unroll
    for (int o = 32; o > 0; o >>= 1) e += __shfl_down(e, o, 64);
    if (lane == 0){
      int pb = q*4 + wv;
      w.maxp[pb] = m; w.zp[pb] = e;
    }
  }
}

// ---------- stage4: [0,8) h4 | [8,1032) h1p | 1032 mz + zero gsum ----------
__global__ __launch_bounds__(256) void k_stage4(WSP w)
{
  __shared__ __align__(16) float smem[272];
  int b = blockIdx.x, tid = threadIdx.x;
  if (b < 8){
    int d = tid & 63, sub = tid >> 6;
    int r0 = b*64 + sub*16;
    float s = 0.f;
    #pragma unroll
    for (int e = 0; e < 16; ++e) s += w.cfm[(size_t)(r0+e)*kHD + d];
    smem[sub*64 + d] = s;
    __syncthreads();
    if (tid < 64)
      atomicAdd(&w.H4v[tid], smem[tid] + smem[64+tid] + smem[128+tid] + smem[192+tid]);
  } else if (b < 1032){
    float* wt = smem;        // [4][64]
    int q = b - 8;
    int i0 = (q & 127) * 4, jt = q >> 7, j0 = jt * 64;
    {
      int r = tid >> 6, jj = tid & 63;
      int j = j0 + jj;
      wt[r*64 + jj] = w.adj[(size_t)(i0+r)*kN + j]
                    ? expf(w.e1v[j] - w.minv[i0+r]) * w.invzv[i0+r] : 0.f;
    }
    __syncthreads();
    float a0=0,a1=0,a2=0,a3=0;
    #pragma unroll 4
    for (int jj = 0; jj < 64; ++jj){
      float wh = w.Wh1[(size_t)(j0+jj)*kHID + tid];
      a0 += wt[jj]*wh; a1 += wt[64+jj]*wh; a2 += wt[128+jj]*wh; a3 += wt[192+jj]*wh;
    }
    size_t base = ((size_t)jt*kN + i0)*kHID + tid;
    w.H1p[base]          = a0;
    w.H1p[base + kHID]   = a1;
    w.H1p[base + 2*kHID] = a2;
    w.H1p[base + 3*kHID] = a3;
  } else {
    float* red = smem;
    float m = -1e30f;
    #pragma unroll
    for (int r = 0; r < 16; ++r) m = fmaxf(m, w.maxp[tid + 256*r]);
    m = blk_red(m, red, true);
    float z = 0.f;
    #pragma unroll
    for (int r = 0; r < 16; ++r) z += w.zp[tid + 256*r] * expf(w.maxp[tid + 256*r] - m);
    z = blk_red(z, red, false);
    if (tid == 0){ w.MZ[0] = m; w.MZ[1] = z; }
    w.gsum[tid] = 0.f;
  }
}

// ---------- stage5: [0,1024) gpart | [1024,1536) h1r | [1536,1600) h3 ----------
__global__ __launch_bounds__(256) void k_stage5(WSP w)
{
  __shared__ __align__(16) char smem[1536];
  int b = blockIdx.x, tid = threadIdx.x;
  if (b < 1024){
    float* wt = (float*)smem;        // [16][16]
    int i0 = (b & 31) * 16, j0 = (b >> 5) * 16;
    float M = w.MZ[0], invZ = 1.0f / w.MZ[1];
    {
      int r = tid >> 4, c = tid & 15;
      wt[r*16 + c] = expf(w.s2[(size_t)(i0+r)*kN + (j0+c)] - M) * invZ;
    }
    float b1v = w.cb1f[tid];
    float aib[16];
    #pragma unroll
    for (int r = 0; r < 16; ++r) aib[r] = w.Am[(size_t)(i0+r)*kHID + tid] + b1v;
    __syncthreads();
    float acc = 0.f;
    for (int j = 0; j < 16; ++j){
      float bj = w.Bm[(size_t)(j0+j)*kHID + tid];
      #pragma unroll
      for (int r = 0; r < 16; ++r)
        acc += wt[r*16 + j] * fmaxf(aib[r] + bj, 0.f);
    }
    atomicAdd(&w.gsum[tid], acc);
  } else if (b < 1536){
    int i = b - 1024;
    float s = 0.f;
    #pragma unroll
    for (int jt = 0; jt < 8; ++jt)
      s += w.H1p[((size_t)jt*kN + i)*kHID + tid];
    w.H1[(size_t)i*kHID + tid] = s;
  } else {
    int d = b - 1536;
    int lane = tid & 63, wv = tid >> 6;
    float v0 = w.tfm[(size_t)(2*tid)*kHD + d];
    float v1 = w.tfm[(size_t)(2*tid+1)*kHD + d];
    float s = v0 + v1;
    float x = s;
    #pragma unroll
    for (int off = 1; off < 64; off <<= 1){
      float y = __shfl_up(x, off, 64);
      if (lane >= off) x += y;
    }
    float* wsum = (float*)smem;
    if (lane == 63) wsum[wv] = x;
    __syncthreads();
    float base = 0.f;
    for (int k = 0; k < wv; ++k) base += wsum[k];
    float excl = base + x - s;
    w.H3[(size_t)(2*tid)*kHD + d]   = (excl + v0) / (float)(2*tid + 1);
    w.H3[(size_t)(2*tid+1)*kHD + d] = (excl + s)  / (float)(2*tid + 2);
  }
}

// ---------- fused h2 + out2 + final: grid 512 ----------
__global__ __launch_bounds__(256) void k_outfin(WSP w)
{
  __shared__ float h1s[kHID];
  __shared__ float gssh[kHID];
  __shared__ float part[kHD][4];
  __shared__ float h2s[kHD];
  __shared__ float h3s[kHD];
  __shared__ float row[kOUT];
  __shared__ float red[4];
  __shared__ float h4sh;
  int i = blockIdx.x, o = threadIdx.x;
  h1s[o] = w.H1[(size_t)i*kHID + o];
  gssh[o] = w.gsum[o];
  if (o < kHD) h3s[o] = w.H3[(size_t)i*kHD + o];
  if (o == 0)  h4sh = (i < kHD) ? w.H4v[i] : 0.f;
  __syncthreads();
  // recompute H2vec = gsum @ cw2^T + cb2 (block-local)
  {
    int dd = o >> 2, q = o & 3;
    float a = 0.f;
    for (int kk = 0; kk < 64; ++kk){
      int k = q*64 + kk;
      a += gssh[k] * w.cw2f[(size_t)dd*kHID + k];
    }
    part[dd][q] = a;
  }
  __syncthreads();
  if (o < kHD)
    h2s[o] = w.cb2f[o] + part[o][0] + part[o][1] + part[o][2] + part[o][3];
  __syncthreads();
  // out2 row: coalesced via W2t
  float acc = 0.f;
  for (int k = 0; k < kHID; ++k) acc += h1s[k] * w.W2t[(size_t)k*256 + o];
  for (int dd = 0; dd < kHD; ++dd){
    acc += h2s[dd] * w.W2t[(size_t)(256+dd)*256 + o];
    acc += h3s[dd] * w.W2t[(size_t)(320+dd)*256 + o];
  }
  acc += h4sh * w.W2t[(size_t)384*256 + o];
  row[o] = acc;
  __syncthreads();
  const float4* opr = (const float4*)(w.opwf + (size_t)o * kOUT);
  float a2 = w.opbf[o];
  for (int kb = 0; kb < 64; ++kb){
    float4 qv = opr[kb];
    a2 += row[kb*4]*qv.x + row[kb*4+1]*qv.y + row[kb*4+2]*qv.z + row[kb*4+3]*qv.w;
  }
  float mu = blk_red(a2, red, false) * (1.0f/kOUT);
  float dv = a2 - mu;
  float var = blk_red(dv*dv, red, false) * (1.0f/kOUT);
  float y = dv * rsqrtf(var + 1e-5f) * w.lngf[o] + w.lnbf[o];
  y = (y > 0.f) ? y : expm1f(y);
  if (*w.flag) ((float*)w.out)[(size_t)i*kOUT + o] = y;
  else         ((u16*)w.out)[(size_t)i*kOUT + o]   = f2us(y);
}

extern "C" void kernel_launch(void* const* d_in, const int* in_sizes, int n_in,
                              void* d_out, int out_size, void* d_ws, size_t ws_size,
                              hipStream_t stream)
{
  const void* V     = d_in[0];
  const int*  adj   = (const int*)d_in[1];
  const void* prev  = d_in[2];
  const void* W1    = d_in[3];
  // d_in[4] = sa0 : dead (row-shift invariant softmax)
  const void* sa1   = d_in[5];
  const void* ce_w1 = d_in[6];
  const void* ce_b1 = d_in[7];
  const void* ce_w2 = d_in[8];
  const void* ce_b2 = d_in[9];
  const void* ca0   = d_in[10];
  const void* ca1   = d_in[11];
  const void* te_w1 = d_in[12];
  const void* te_b1 = d_in[13];
  const void* te_w2 = d_in[14];
  const void* te_b2 = d_in[15];
  // d_in[16,17] = ta0,ta1 : dead
  const void* pe_w1 = d_in[18];
  const void* pe_b1 = d_in[19];
  const void* pe_w2 = d_in[20];
  const void* pe_b2 = d_in[21];
  // d_in[22,23] = pa0,pa1 : dead
  const void* W2    = d_in[24];
  const void* op_w  = d_in[25];
  const void* op_b  = d_in[26];
  const void* ln_g  = d_in[27];
  const void* ln_b  = d_in[28];

  // ---- workspace layout (floats) ----
  float* ws  = (float*)d_ws;
  int*  flag = (int*)ws;               // 16 floats reserved
  float* p   = ws + 16;
  float* Vf   = p; p += 131072;
  float* prevf= p; p += 131072;
  float* W1f  = p; p += 65536;
  float* sa1f = p; p += 256;
  float* cw1f = p; p += 131072;
  float* cb1f = p; p += 256;
  float* cw2f = p; p += 16384;
  float* cb2f = p; p += 64;
  float* ca0f = p; p += 64;
  float* ca1f = p; p += 64;
  float* tw1f = p; p += 131072;
  float* tb1f = p; p += 256;
  float* tw2f = p; p += 16384;
  float* tb2f = p; p += 64;
  float* pw1f = p; p += 196608;
  float* pb1f = p; p += 256;
  float* pw2f = p; p += 16384;
  float* pb2f = p; p += 64;
  float* W2f  = p; p += 98560;
  float* opwf = p; p += 65536;
  float* opbf = p; p += 256;
  float* lngf = p; p += 256;
  float* lnbf = p; p += 256;
  float* tw2t = p; p += 16384;
  float* pw2t = p; p += 16384;
  float* W2t  = p; p += 98560;
  float* Wh1      = p; p += 131072;
  float* e1v      = p; p += 512;
  float* minv     = p; p += 512;
  float* invzv    = p; p += 512;
  float* H1p      = p; p += 1048576;
  float* H1       = p; p += 131072;
  float* Am       = p; p += 131072;
  float* Bm       = p; p += 131072;
  float* uvec     = p; p += 256;
  float* beta     = p; p += 16;
  float* s2       = p; p += 262144;
  float* maxp     = p; p += 4096;
  float* zpart    = p; p += 4096;
  float* MZ       = p; p += 16;
  float* gsum     = p; p += 256;
  float* htp0     = p; p += 131072;
  float* htp1     = p; p += 131072;
  float* hpp0     = p; p += 131072;
  float* hpp1     = p; p += 131072;
  float* hpp2     = p; p += 131072;
  float* hidden_t = p; p += 131072;
  float* hidden_p = p; p += 131072;
  float* tfm      = p; p += 32768;
  float* cfm      = p; p += 32768;
  float* H3       = p; p += 32768;
  float* H4v      = p; p += 64;
  float* Xp       = p; p += 393216;

  // ---- pointer bundle ----
  WSP w;
  w.adj = adj; w.flag = flag; w.out = d_out;
  w.Vf=Vf; w.prevf=prevf; w.W1f=W1f; w.sa1f=sa1f; w.cw1f=cw1f; w.cb1f=cb1f;
  w.cw2f=cw2f; w.cb2f=cb2f; w.ca0f=ca0f; w.ca1f=ca1f;
  w.tw1f=tw1f; w.tb1f=tb1f; w.tw2f=tw2f; w.tb2f=tb2f;
  w.pw1f=pw1f; w.pb1f=pb1f; w.pw2f=pw2f; w.pb2f=pb2f;
  w.W2f=W2f; w.opwf=opwf; w.opbf=opbf; w.lngf=lngf; w.lnbf=lnbf;
  w.tw2t=tw2t; w.pw2t=pw2t; w.W2t=W2t;
  w.Wh1=Wh1; w.e1v=e1v; w.minv=minv; w.invzv=invzv; w.H1p=H1p; w.H1=H1;
  w.Am=Am; w.Bm=Bm; w.uvec=uvec; w.beta=beta;
  w.s2=s2; w.maxp=maxp; w.zp=zpart; w.MZ=MZ; w.gsum=gsum;
  w.htp0=htp0; w.htp1=htp1; w.hpp0=hpp0; w.hpp1=hpp1; w.hpp2=hpp2;
  w.hidden_t=hidden_t; w.hidden_p=hidden_p;
  w.tfm=tfm; w.cfm=cfm; w.H3=H3; w.H4v=H4v; w.Xp=Xp;

  // ---- fused convert + probe + packsel: 768 blocks ----
  {
    ConvArgs ca;
    const void* srcs[23] = {V, prev, W1, sa1, ce_w1, ce_b1, ce_w2, ce_b2, ca0, ca1,
                            te_w1, te_b1, te_w2, te_b2, pe_w1, pe_b1, pe_w2, pe_b2,
                            W2, op_w, op_b, ln_g, ln_b};
    float* dsts[23] = {Vf, prevf, W1f, sa1f, cw1f, cb1f, cw2f, cb2f, ca0f, ca1f,
                       tw1f, tb1f, tw2f, tb2f, pw1f, pb1f, pw2f, pb2f,
                       W2f, opwf, opbf, lngf, lnbf};
    int ns[23] = {131072, 131072, 65536, 256, 131072, 256, 16384, 64, 64, 64,
                  131072, 256, 16384, 64, 196608, 256, 16384, 64,
                  98560, 65536, 256, 256, 256};
    for (int s = 0; s < 23; ++s){ ca.src[s] = srcs[s]; ca.dst[s] = dsts[s]; ca.n[s] = ns[s]; }
    k_conv<<<768, 256, 0, stream>>>(ca, (const unsigned int*)V, adj, flag, Xp);
  }

  // ---- GEMM batch A: 8 segs x 64 tiles = 512 blocks ----
  {
    GArgs2 g{};
    g.s[0] = {Vf,       W1f,        Wh1,  256, 256, 256, 256};
    g.s[1] = {Vf,       cw1f,       Am,   256, 512, 256, 256};
    g.s[2] = {Vf,       cw1f + 256, Bm,   256, 512, 256, 256};
    g.s[3] = {Vf,       tw1f,       htp0, 256, 512, 256, 256};
    g.s[4] = {prevf,    tw1f + 256, htp1, 256, 512, 256, 256};
    g.s[5] = {Xp,       pw1f,       hpp0, 768, 768, 256, 256};
    g.s[6] = {Xp + 256, pw1f + 256, hpp1, 768, 768, 256, 256};
    g.s[7] = {Xp + 512, pw1f + 512, hpp2, 768, 768, 256, 256};
    k_gemmA<<<dim3(64, 8), 256, 0, stream>>>(g);
  }

  // ---- stage2: redH | e1 | ub | transposes ----
  k_stage2<<<356, 256, 0, stream>>>(w);

  // ---- stage3: gemmB(reg) | h1stats | s2 ----
  k_stage3<<<1600, 256, 0, stream>>>(w);

  // ---- stage4: h4 | h1p | mz ----
  k_stage4<<<1033, 256, 0, stream>>>(w);

  // ---- stage5: gpart | h1r | h3 ----
  k_stage5<<<1600, 256, 0, stream>>>(w);

  // ---- fused h2 + out2 + final ----
  k_outfin<<<kN, 256, 0, stream>>>(w);
}

// Round 6
// 244.736 us; speedup vs baseline: 1.8088x; 1.1102x over previous
//
#include <hip/hip_runtime.h>

typedef unsigned short u16;

constexpr int kN   = 512;
constexpr int kIN  = 256;
constexpr int kHID = 256;
constexpr int kHD  = 64;
constexpr int kOUT = 256;

// ---------- bf16 helpers ----------
__device__ __forceinline__ float us2f(u16 u){
  union { unsigned int i; float f; } c; c.i = ((unsigned int)u) << 16; return c.f;
}
__device__ __forceinline__ u16 f2us(float f){
  union { float f; unsigned int i; } c; c.f = f;
  unsigned int r = c.i + 0x7fff + ((c.i >> 16) & 1);
  return (u16)(r >> 16);
}

// ---------- per-block dtype probe (reads first 16KB of V) ----------
__device__ bool probe_is_f32(const unsigned int* __restrict__ V){
  __shared__ int cnt;
  if (threadIdx.x == 0) cnt = 0;
  __syncthreads();
  int c = 0;
  for (int k = threadIdx.x; k < 4096; k += 256){
    float x = us2f((u16)(V[k] & 0xffffu));
    if (!(fabsf(x) <= 32.0f)) c++;
  }
  atomicAdd(&cnt, c);
  __syncthreads();
  return cnt > 64;
}

// ---------- fused convert + probe + pairsel/packxp ----------
struct ConvArgs { const void* src[23]; float* dst[23]; int n[23]; };

__global__ __launch_bounds__(256) void k_conv(ConvArgs a, const unsigned int* __restrict__ Vraw,
                                              const int* __restrict__ adj, int* __restrict__ flag,
                                              float* __restrict__ Xp)
{
  int b = blockIdx.x, tid = threadIdx.x;
  bool f32 = probe_is_f32(Vraw);
  if (b < 256){
    if (b == 0 && tid == 0) *flag = f32 ? 1 : 0;
    int t = b*256 + tid;
    const int stride = 65536;
    for (int s = 0; s < 23; ++s){
      int n4 = a.n[s] >> 2;
      float4* d = (float4*)a.dst[s];
      if (f32){
        const float4* sf = (const float4*)a.src[s];
        for (int i = t; i < n4; i += stride) d[i] = sf[i];
      } else {
        const ushort4* sb = (const ushort4*)a.src[s];
        for (int i = t; i < n4; i += stride){
          ushort4 u = sb[i];
          d[i] = make_float4(us2f(u.x), us2f(u.y), us2f(u.z), us2f(u.w));
        }
      }
    }
  } else {
    __shared__ unsigned long long msk[8];
    __shared__ int sj[2];
    int i = b - 256;
    int w = tid >> 6, lane = tid & 63;
    unsigned long long m0 = __ballot(adj[(size_t)i*kN + tid] != 0);
    unsigned long long m1 = __ballot(adj[(size_t)i*kN + 256 + tid] != 0);
    if (lane == 0){ msk[w] = m0; msk[4 + w] = m1; }
    __syncthreads();
    if (tid == 0){
      int j0 = -1, j1 = -1;
      for (int c = 0; c < 8 && j1 < 0; ++c){
        unsigned long long m = msk[c];
        while (m && j1 < 0){
          int bb = __builtin_ctzll(m);
          int j = c*64 + bb;
          if (j0 < 0) j0 = j; else j1 = j;
          m &= m - 1;
        }
      }
      if (j1 < 0) j0 = -1;
      sj[0] = j0; sj[1] = j1;
    }
    __syncthreads();
    int j0 = sj[0], j1 = sj[1];
    const float* Vf = (const float*)Vraw;
    const u16*  Vb = (const u16*)Vraw;
    auto rdV = [&](int r, int k)->float{
      return f32 ? Vf[(size_t)r*kIN + k] : us2f(Vb[(size_t)r*kIN + k]);
    };
    Xp[(size_t)i*768 + tid]       = rdV(i, tid);
    Xp[(size_t)i*768 + 256 + tid] = (j0 >= 0) ? rdV(j0, tid) : 0.f;
    Xp[(size_t)i*768 + 512 + tid] = (j1 >= 0) ? rdV(j1, tid) : 0.f;
  }
}

// ---------- block reduction (256 threads) ----------
__device__ __forceinline__ float blk_red(float v, float* tmp, bool isMax){
  int lane = threadIdx.x & 63, wv = threadIdx.x >> 6;
  #pragma unroll
  for (int o = 32; o > 0; o >>= 1){
    float t = __shfl_down(v, o, 64);
    v = isMax ? fmaxf(v, t) : (v + t);
  }
  __syncthreads();
  if (lane == 0) tmp[wv] = v;
  __syncthreads();
  float r = tmp[0];
  for (int i = 1; i < 4; ++i) r = isMax ? fmaxf(r, tmp[i]) : (r + tmp[i]);
  return r;
}

// ---------- workspace pointer bundle ----------
struct WSP {
  const int* adj; const int* flag; void* out;
  float *Vf,*prevf,*W1f,*sa1f,*cw1f,*cb1f,*cw2f,*cb2f,*ca0f,*ca1f;
  float *tw1f,*tb1f,*tw2f,*tb2f,*pw1f,*pb1f,*pw2f,*pb2f;
  float *W2f,*opwf,*opbf,*lngf,*lnbf;
  float *tw2t,*pw2t,*W2c,*W2midt,*w384v,*c2v;
  float *Wh1,*e1v,*minv,*invzv,*H1p,*Hc,*Am,*Bm,*uvec,*beta;
  float *s2,*maxp,*zp,*MZ,*gsum;
  float *htp0,*htp1,*hpp0,*hpp1,*hpp2,*hidden_t,*hidden_p;
  float *tfm,*cfm,*H4v,*Xp,*out2,*out3;
};

// ================== GEMM A: 64x64 tile, BK=32, 4x4 micro, dbuf ==================
struct GSeg2 { const float* X; const float* W; float* C; int ldx, ldw, ldc, K; };
struct GArgs2 { GSeg2 s[8]; };

__global__ __launch_bounds__(256) void k_gemmA(GArgs2 ga)
{
  __shared__ __align__(16) float Xs[2][32][68];
  __shared__ __align__(16) float Ws[2][32][68];
  const GSeg2 sg = ga.s[blockIdx.y];
  const int tm = blockIdx.x & 7;       // 8 m-tiles of 64 rows
  const int tn = blockIdx.x >> 3;      // 4 n-tiles of 64 cols
  const int i0 = tm << 6;
  const int n0 = tn << 6;
  const int tid = threadIdx.x;

  const int xrow = tid >> 3;           // 0..31
  const int xk   = (tid & 7) << 2;     // 0..28
  const int rg = (tid >> 4) << 2;      // 0..60
  const int cg = (tid & 15) << 2;      // 0..60

  const float* Xb = sg.X + (size_t)i0 * sg.ldx;
  const float* Wb = sg.W + (size_t)n0 * sg.ldw;

  float4 xr0, xr1, wr0, wr1;
  auto loadT = [&](int kt){
    xr0 = *(const float4*)(Xb + (size_t)xrow * sg.ldx + kt + xk);
    xr1 = *(const float4*)(Xb + (size_t)(xrow+32) * sg.ldx + kt + xk);
    wr0 = *(const float4*)(Wb + (size_t)xrow * sg.ldw + kt + xk);
    wr1 = *(const float4*)(Wb + (size_t)(xrow+32) * sg.ldw + kt + xk);
  };
  auto writeT = [&](int bu){
    Xs[bu][xk+0][xrow] = xr0.x;  Xs[bu][xk+1][xrow] = xr0.y;
    Xs[bu][xk+2][xrow] = xr0.z;  Xs[bu][xk+3][xrow] = xr0.w;
    Xs[bu][xk+0][xrow+32] = xr1.x;  Xs[bu][xk+1][xrow+32] = xr1.y;
    Xs[bu][xk+2][xrow+32] = xr1.z;  Xs[bu][xk+3][xrow+32] = xr1.w;
    Ws[bu][xk+0][xrow]    = wr0.x; Ws[bu][xk+1][xrow]    = wr0.y;
    Ws[bu][xk+2][xrow]    = wr0.z; Ws[bu][xk+3][xrow]    = wr0.w;
    Ws[bu][xk+0][xrow+32] = wr1.x; Ws[bu][xk+1][xrow+32] = wr1.y;
    Ws[bu][xk+2][xrow+32] = wr1.z; Ws[bu][xk+3][xrow+32] = wr1.w;
  };

  loadT(0); writeT(0); __syncthreads();

  float acc[4][4] = {};
  const int nkt = sg.K >> 5;
  for (int t = 0; t < nkt; ++t){
    if (t + 1 < nkt) loadT((t + 1) << 5);
    const int bu = t & 1;
    #pragma unroll
    for (int kk = 0; kk < 32; ++kk){
      const float4 av = *(const float4*)&Xs[bu][kk][rg];
      const float4 bv = *(const float4*)&Ws[bu][kk][cg];
      acc[0][0]+=av.x*bv.x; acc[0][1]+=av.x*bv.y; acc[0][2]+=av.x*bv.z; acc[0][3]+=av.x*bv.w;
      acc[1][0]+=av.y*bv.x; acc[1][1]+=av.y*bv.y; acc[1][2]+=av.y*bv.z; acc[1][3]+=av.y*bv.w;
      acc[2][0]+=av.z*bv.x; acc[2][1]+=av.z*bv.y; acc[2][2]+=av.z*bv.z; acc[2][3]+=av.z*bv.w;
      acc[3][0]+=av.w*bv.x; acc[3][1]+=av.w*bv.y; acc[3][2]+=av.w*bv.z; acc[3][3]+=av.w*bv.w;
    }
    if (t + 1 < nkt) writeT((t + 1) & 1);
    __syncthreads();
  }

  #pragma unroll
  for (int ri = 0; ri < 4; ++ri)
    *(float4*)(sg.C + (size_t)(i0 + rg + ri) * sg.ldc + (n0 + cg)) =
      make_float4(acc[ri][0], acc[ri][1], acc[ri][2], acc[ri][3]);
}

// ================== GEMM-32 body: 32x32 tile, BK=32, 2x2 micro, dbuf ==================
// optional fold: X'[i][k] = X[i][k] + c2[k] + h4(i)*w384[k]
struct GS32 { const float* X; const float* W; float* C; int ldx, ldw, ldc, K;
              const float* c2; const float* w384; const float* h4; };

__device__ __forceinline__ void gemm32_body(const GS32 sg, int tm, int tn, int tid,
                                            float* Xs, float* Ws)
{
  const int i0 = tm << 5, n0 = tn << 5;
  const int xrow = tid >> 3;           // 0..31
  const int xk = (tid & 7) << 2;       // 0..28
  const int rg = (tid >> 4) << 1;      // 0..30
  const int cg = (tid & 15) << 1;      // 0..30
  const float* Xb = sg.X + (size_t)i0 * sg.ldx;
  const float* Wb = sg.W + (size_t)n0 * sg.ldw;
  float h4r = 0.f;
  if (sg.h4){ int i = i0 + xrow; h4r = (i < 64) ? sg.h4[i] : 0.f; }
  float4 xr, wr;
  auto loadT = [&](int kt){
    xr = *(const float4*)(Xb + (size_t)xrow * sg.ldx + kt + xk);
    wr = *(const float4*)(Wb + (size_t)xrow * sg.ldw + kt + xk);
    if (sg.c2){
      float4 c = *(const float4*)(sg.c2 + kt + xk);
      float4 w3 = *(const float4*)(sg.w384 + kt + xk);
      xr.x += c.x + h4r*w3.x; xr.y += c.y + h4r*w3.y;
      xr.z += c.z + h4r*w3.z; xr.w += c.w + h4r*w3.w;
    }
  };
  auto writeT = [&](int bu){
    float* xs = Xs + bu*1152;
    xs[(xk+0)*36 + xrow] = xr.x; xs[(xk+1)*36 + xrow] = xr.y;
    xs[(xk+2)*36 + xrow] = xr.z; xs[(xk+3)*36 + xrow] = xr.w;
    float* wsp = Ws + bu*1152;
    wsp[(xk+0)*36 + xrow] = wr.x; wsp[(xk+1)*36 + xrow] = wr.y;
    wsp[(xk+2)*36 + xrow] = wr.z; wsp[(xk+3)*36 + xrow] = wr.w;
  };
  loadT(0); writeT(0); __syncthreads();
  float a00=0,a01=0,a10=0,a11=0;
  const int nkt = sg.K >> 5;
  for (int t = 0; t < nkt; ++t){
    if (t+1 < nkt) loadT((t+1) << 5);
    const float* xs = Xs + (t&1)*1152;
    const float* wsp = Ws + (t&1)*1152;
    #pragma unroll
    for (int kk = 0; kk < 32; ++kk){
      float2 av = *(const float2*)&xs[kk*36 + rg];
      float2 bv = *(const float2*)&wsp[kk*36 + cg];
      a00 += av.x*bv.x; a01 += av.x*bv.y;
      a10 += av.y*bv.x; a11 += av.y*bv.y;
    }
    if (t+1 < nkt) writeT((t+1)&1);
    __syncthreads();
  }
  float* cp = sg.C + (size_t)(i0+rg)*sg.ldc + n0 + cg;
  *(float2*)cp = make_float2(a00, a01);
  *(float2*)(cp + sg.ldc) = make_float2(a10, a11);
}

// ---------- stage2: redH | e1 | ub | small transposes | W2c/W2midt/w384 ----------
__global__ __launch_bounds__(256) void k_stage2(WSP w)
{
  __shared__ float st[64*65];
  int b = blockIdx.x, tid = threadIdx.x;
  if (b < 128){
    int f = b*256 + tid;           // 32768 float4 per matrix
    int c4 = f & 63;
    {
      float4 a = ((const float4*)w.htp0)[f], bb = ((const float4*)w.htp1)[f];
      float4 bi = ((const float4*)w.tb1f)[c4];
      ((float4*)w.hidden_t)[f] = make_float4(
        fmaxf(a.x+bb.x+bi.x,0.f), fmaxf(a.y+bb.y+bi.y,0.f),
        fmaxf(a.z+bb.z+bi.z,0.f), fmaxf(a.w+bb.w+bi.w,0.f));
    }
    {
      float4 a = ((const float4*)w.hpp0)[f], bb = ((const float4*)w.hpp1)[f];
      float4 c = ((const float4*)w.hpp2)[f];
      float4 bi = ((const float4*)w.pb1f)[c4];
      ((float4*)w.hidden_p)[f] = make_float4(
        fmaxf(a.x+bb.x+c.x+bi.x,0.f), fmaxf(a.y+bb.y+c.y+bi.y,0.f),
        fmaxf(a.z+bb.z+c.z+bi.z,0.f), fmaxf(a.w+bb.w+c.w+bi.w,0.f));
    }
  } else if (b < 256){
    int r = (b-128)*4 + (tid >> 6), lane = tid & 63;
    float a = 0.f;
    for (int k = lane; k < kHID; k += 64) a += w.Wh1[(size_t)r*kHID + k] * w.sa1f[k];
    #pragma unroll
    for (int o = 32; o > 0; o >>= 1) a += __shfl_down(a, o, 64);
    if (lane == 0) w.e1v[r] = a;
  } else if (b == 256){
    if (tid < 64){ st[tid] = w.ca0f[tid] + w.ca1f[tid]; w.H4v[tid] = 0.f; }
    __syncthreads();
    float a = 0.f;
    for (int d = 0; d < kHD; ++d) a += w.cw2f[(size_t)d*kHID + tid] * st[d];
    w.uvec[tid] = a;
    if (tid == 0){
      float bsum = 0.f;
      for (int d = 0; d < kHD; ++d) bsum += w.cb2f[d] * st[d];
      *w.beta = bsum;
    }
  } else if (b < 259){
    // transpose 64x256 -> 256x64 (tw2 or pw2)
    const float* src = (b == 257) ? w.tw2f : w.pw2f;
    float* dst = (b == 257) ? w.tw2t : w.pw2t;
    for (int ch = 0; ch < 4; ++ch){
      __syncthreads();
      #pragma unroll
      for (int e = 0; e < 16; ++e){
        int lin = e*256 + tid;
        int r = lin >> 6, c = lin & 63;
        st[r*65 + c] = src[(size_t)r*256 + ch*64 + c];
      }
      __syncthreads();
      #pragma unroll
      for (int e = 0; e < 16; ++e){
        int lin = e*256 + tid;
        int kc = lin >> 6, dd = lin & 63;
        dst[(size_t)(ch*64 + kc)*64 + dd] = st[dd*65 + kc];
      }
    }
  } else if (b < 323){
    // W2c[o][k]: k<256 -> W2[o][k]; k in [256,320) -> W2[o][320+(k-256)]
    int o0 = (b - 259) * 4;
    for (int r = 0; r < 4; ++r){
      int o = o0 + r;
      const float* src = w.W2f + (size_t)o * 385;
      float* dst = w.W2c + (size_t)o * 320;
      for (int c = tid; c < 320; c += 256)
        dst[c] = src[(c < 256) ? c : c + 64];
    }
  } else if (b < 339){
    // W2midt[d][o] = W2[o][256+d]
    int d0 = (b - 323) * 4;
    #pragma unroll
    for (int dd = 0; dd < 4; ++dd)
      w.W2midt[(size_t)(d0+dd)*256 + tid] = w.W2f[(size_t)tid*385 + 256 + d0 + dd];
  } else {
    // w384[o] = W2[o][384]
    w.w384v[tid] = w.W2f[(size_t)tid*385 + 384];
  }
}

// ---------- stage3: [0,64) gemmB(reg) | [64,576) h1stats | [576,1600) s2 ----------
__global__ __launch_bounds__(256) void k_stage3(WSP w)
{
  __shared__ __align__(16) float smem3[4*256 + 256];
  int b = blockIdx.x, tid = threadIdx.x;
  if (b < 64){
    int m = b >> 5, grp = b & 31;
    const float* X  = m ? w.hidden_p : w.hidden_t;
    const float* Wt = m ? w.pw2t : w.tw2t;
    const float* bi = m ? w.pb2f : w.tb2f;
    float* C = m ? w.cfm : w.tfm;
    int i0 = grp*16 + (tid >> 6)*4;
    int d = tid & 63;
    const float* x0 = X + (size_t)i0*256;
    const float* x1 = x0 + 256;
    const float* x2 = x0 + 512;
    const float* x3 = x0 + 768;
    float a0=0.f, a1=0.f, a2=0.f, a3=0.f;
    for (int k = 0; k < 256; k += 4){
      float w0 = Wt[(size_t)(k+0)*64 + d];
      float w1 = Wt[(size_t)(k+1)*64 + d];
      float w2 = Wt[(size_t)(k+2)*64 + d];
      float w3 = Wt[(size_t)(k+3)*64 + d];
      float4 f0 = *(const float4*)(x0 + k);
      float4 f1 = *(const float4*)(x1 + k);
      float4 f2 = *(const float4*)(x2 + k);
      float4 f3 = *(const float4*)(x3 + k);
      a0 += f0.x*w0 + f0.y*w1 + f0.z*w2 + f0.w*w3;
      a1 += f1.x*w0 + f1.y*w1 + f1.z*w2 + f1.w*w3;
      a2 += f2.x*w0 + f2.y*w1 + f2.z*w2 + f2.w*w3;
      a3 += f3.x*w0 + f3.y*w1 + f3.z*w2 + f3.w*w3;
    }
    float bd = bi[d];
    C[(size_t)(i0+0)*64 + d] = a0 + bd;
    C[(size_t)(i0+1)*64 + d] = a1 + bd;
    C[(size_t)(i0+2)*64 + d] = a2 + bd;
    C[(size_t)(i0+3)*64 + d] = a3 + bd;
  } else if (b < 576){
    float* red = smem3;
    int i = b - 64;
    int m0 = w.adj[(size_t)i*kN + tid];
    int m1 = w.adj[(size_t)i*kN + tid + 256];
    float ea = w.e1v[tid], eb = w.e1v[tid+256];
    float v0 = m0 ? ea : -1e30f;
    float v1 = m1 ? eb : -1e30f;
    float m = blk_red(fmaxf(v0, v1), red, true);
    float z = blk_red((m0 ? expf(ea-m) : 0.f) + (m1 ? expf(eb-m) : 0.f), red, false);
    if (tid == 0){ w.minv[i] = m; w.invzv[i] = 1.0f / z; }
  } else {
    float* aib = smem3;                 // [4][256]
    float* uu  = smem3 + 1024;          // [256]
    int q = b - 576;
    int i0 = (q & 127) * 4, j0 = (q >> 7) * 64;
    int wv = tid >> 6, lane = tid & 63;
    uu[tid] = w.uvec[tid];
    float b1v = w.cb1f[tid];
    #pragma unroll
    for (int r = 0; r < 4; ++r) aib[r*256 + tid] = w.Am[(size_t)(i0+r)*kHID + tid] + b1v;
    __syncthreads();
    int i = i0 + wv, j = j0 + lane;
    const float4* bp = (const float4*)(w.Bm + (size_t)j*kHID);
    float acc = *w.beta;
    #pragma unroll 8
    for (int k4 = 0; k4 < kHID/4; ++k4){
      float4 bv = bp[k4];
      float4 a4 = *(const float4*)&aib[wv*256 + k4*4];
      float4 u4 = *(const float4*)&uu[k4*4];
      acc += fmaxf(a4.x+bv.x,0.f)*u4.x + fmaxf(a4.y+bv.y,0.f)*u4.y
           + fmaxf(a4.z+bv.z,0.f)*u4.z + fmaxf(a4.w+bv.w,0.f)*u4.w;
    }
    if (j == i) acc = -1e30f;
    w.s2[(size_t)i*kN + j] = acc;
    float m = acc;
    #pragma unroll
    for (int o = 32; o > 0; o >>= 1) m = fmaxf(m, __shfl_down(m, o, 64));
    m = __shfl(m, 0, 64);
    float e = expf(acc - m);
    #pragma unroll
    for (int o = 32; o > 0; o >>= 1) e += __shfl_down(e, o, 64);
    if (lane == 0){
      int pb = q*4 + wv;
      w.maxp[pb] = m; w.zp[pb] = e;
    }
  }
}

// ---------- stage4: [0,8) h4 | [8,1032) h1p | 1032 mz + zero gsum ----------
__global__ __launch_bounds__(256) void k_stage4(WSP w)
{
  __shared__ __align__(16) float smem[272];
  int b = blockIdx.x, tid = threadIdx.x;
  if (b < 8){
    int d = tid & 63, sub = tid >> 6;
    int r0 = b*64 + sub*16;
    float s = 0.f;
    #pragma unroll
    for (int e = 0; e < 16; ++e) s += w.cfm[(size_t)(r0+e)*kHD + d];
    smem[sub*64 + d] = s;
    __syncthreads();
    if (tid < 64)
      atomicAdd(&w.H4v[tid], smem[tid] + smem[64+tid] + smem[128+tid] + smem[192+tid]);
  } else if (b < 1032){
    float* wt = smem;        // [4][64]
    int q = b - 8;
    int i0 = (q & 127) * 4, jt = q >> 7, j0 = jt * 64;
    {
      int r = tid >> 6, jj = tid & 63;
      int j = j0 + jj;
      wt[r*64 + jj] = w.adj[(size_t)(i0+r)*kN + j]
                    ? expf(w.e1v[j] - w.minv[i0+r]) * w.invzv[i0+r] : 0.f;
    }
    __syncthreads();
    float a0=0,a1=0,a2=0,a3=0;
    #pragma unroll 4
    for (int jj = 0; jj < 64; ++jj){
      float wh = w.Wh1[(size_t)(j0+jj)*kHID + tid];
      a0 += wt[jj]*wh; a1 += wt[64+jj]*wh; a2 += wt[128+jj]*wh; a3 += wt[192+jj]*wh;
    }
    size_t base = ((size_t)jt*kN + i0)*kHID + tid;
    w.H1p[base]          = a0;
    w.H1p[base + kHID]   = a1;
    w.H1p[base + 2*kHID] = a2;
    w.H1p[base + 3*kHID] = a3;
  } else {
    float* red = smem;
    float m = -1e30f;
    #pragma unroll
    for (int r = 0; r < 16; ++r) m = fmaxf(m, w.maxp[tid + 256*r]);
    m = blk_red(m, red, true);
    float z = 0.f;
    #pragma unroll
    for (int r = 0; r < 16; ++r) z += w.zp[tid + 256*r] * expf(w.maxp[tid + 256*r] - m);
    z = blk_red(z, red, false);
    if (tid == 0){ w.MZ[0] = m; w.MZ[1] = z; }
    w.gsum[tid] = 0.f;
  }
}

// ---------- stage5: [0,1024) gpart | [1024,1536) h1r->Hc | [1536,1600) h3->Hc ----------
__global__ __launch_bounds__(256) void k_stage5(WSP w)
{
  __shared__ __align__(16) char smem[1536];
  int b = blockIdx.x, tid = threadIdx.x;
  if (b < 1024){
    float* wt = (float*)smem;        // [16][16]
    int i0 = (b & 31) * 16, j0 = (b >> 5) * 16;
    float M = w.MZ[0], invZ = 1.0f / w.MZ[1];
    {
      int r = tid >> 4, c = tid & 15;
      wt[r*16 + c] = expf(w.s2[(size_t)(i0+r)*kN + (j0+c)] - M) * invZ;
    }
    float b1v = w.cb1f[tid];
    float aib[16];
    #pragma unroll
    for (int r = 0; r < 16; ++r) aib[r] = w.Am[(size_t)(i0+r)*kHID + tid] + b1v;
    __syncthreads();
    float acc = 0.f;
    for (int j = 0; j < 16; ++j){
      float bj = w.Bm[(size_t)(j0+j)*kHID + tid];
      #pragma unroll
      for (int r = 0; r < 16; ++r)
        acc += wt[r*16 + j] * fmaxf(aib[r] + bj, 0.f);
    }
    atomicAdd(&w.gsum[tid], acc);
  } else if (b < 1536){
    int i = b - 1024;
    float s = 0.f;
    #pragma unroll
    for (int jt = 0; jt < 8; ++jt)
      s += w.H1p[((size_t)jt*kN + i)*kHID + tid];
    w.Hc[(size_t)i*320 + tid] = s;
  } else {
    int d = b - 1536;
    int lane = tid & 63, wv = tid >> 6;
    float v0 = w.tfm[(size_t)(2*tid)*kHD + d];
    float v1 = w.tfm[(size_t)(2*tid+1)*kHD + d];
    float s = v0 + v1;
    float x = s;
    #pragma unroll
    for (int off = 1; off < 64; off <<= 1){
      float y = __shfl_up(x, off, 64);
      if (lane >= off) x += y;
    }
    float* wsum = (float*)smem;
    if (lane == 63) wsum[wv] = x;
    __syncthreads();
    float base = 0.f;
    for (int k = 0; k < wv; ++k) base += wsum[k];
    float excl = base + x - s;
    w.Hc[(size_t)(2*tid)*320 + 256 + d]   = (excl + v0) / (float)(2*tid + 1);
    w.Hc[(size_t)(2*tid+1)*320 + 256 + d] = (excl + s)  / (float)(2*tid + 2);
  }
}

// ---------- out2 GEMM (Hc[512x320] @ W2c^T) + h2c block -> c2v ----------
__global__ __launch_bounds__(256) void k_out2g(WSP w)
{
  __shared__ __align__(16) char smem[18432];
  int b = blockIdx.x, tid = threadIdx.x;
  if (b < 128){
    GS32 sg{w.Hc, w.W2c, w.out2, 320, 320, 256, 320, nullptr, nullptr, nullptr};
    gemm32_body(sg, b & 15, b >> 4, tid, (float*)smem, (float*)(smem + 9216));
  } else {
    float* gs  = (float*)smem;            // [256]
    float* part= (float*)(smem + 1024);   // [64][4]
    float* h2s = (float*)(smem + 2048);   // [64]
    gs[tid] = w.gsum[tid];
    __syncthreads();
    int dd = tid >> 2, q = tid & 3;
    float a = 0.f;
    for (int kk = 0; kk < 64; ++kk){
      int k = q*64 + kk;
      a += gs[k] * w.cw2f[(size_t)dd*kHID + k];
    }
    part[dd*4 + q] = a;
    __syncthreads();
    if (tid < kHD)
      h2s[tid] = w.cb2f[tid] + part[tid*4] + part[tid*4+1] + part[tid*4+2] + part[tid*4+3];
    __syncthreads();
    float c = 0.f;
    for (int d = 0; d < kHD; ++d) c += h2s[d] * w.W2midt[(size_t)d*256 + tid];
    w.c2v[tid] = c;
  }
}

// ---------- out3 GEMM: (out2 + c2 + h4col*w384) @ opw^T ----------
__global__ __launch_bounds__(256) void k_out3g(WSP w)
{
  __shared__ __align__(16) char smem[18432];
  GS32 sg{w.out2, w.opwf, w.out3, 256, 256, 256, 256, w.c2v, w.w384v, w.H4v};
  gemm32_body(sg, blockIdx.x & 15, blockIdx.x >> 4, threadIdx.x, (float*)smem, (float*)(smem + 9216));
}

// ---------- final: wave-per-row LN + ELU, grid 128 ----------
__global__ __launch_bounds__(256) void k_final(WSP w)
{
  int b = blockIdx.x, tid = threadIdx.x;
  int row = b*4 + (tid >> 6), lane = tid & 63;
  float4 v = *(const float4*)(w.out3 + (size_t)row*kOUT + lane*4);
  float4 pb = *(const float4*)(w.opbf + lane*4);
  v.x += pb.x; v.y += pb.y; v.z += pb.z; v.w += pb.w;
  float s = v.x + v.y + v.z + v.w;
  #pragma unroll
  for (int o = 32; o > 0; o >>= 1) s += __shfl_xor(s, o, 64);
  float mu = s * (1.0f/kOUT);
  float dx = v.x-mu, dy = v.y-mu, dz = v.z-mu, dw = v.w-mu;
  float ss = dx*dx + dy*dy + dz*dz + dw*dw;
  #pragma unroll
  for (int o = 32; o > 0; o >>= 1) ss += __shfl_xor(ss, o, 64);
  float rs = rsqrtf(ss * (1.0f/kOUT) + 1e-5f);
  float4 g = *(const float4*)(w.lngf + lane*4);
  float4 be = *(const float4*)(w.lnbf + lane*4);
  float y0 = dx*rs*g.x + be.x, y1 = dy*rs*g.y + be.y;
  float y2 = dz*rs*g.z + be.z, y3 = dw*rs*g.w + be.w;
  y0 = (y0 > 0.f) ? y0 : expm1f(y0);
  y1 = (y1 > 0.f) ? y1 : expm1f(y1);
  y2 = (y2 > 0.f) ? y2 : expm1f(y2);
  y3 = (y3 > 0.f) ? y3 : expm1f(y3);
  if (*w.flag){
    *(float4*)((float*)w.out + (size_t)row*kOUT + lane*4) = make_float4(y0,y1,y2,y3);
  } else {
    ushort4 u; u.x = f2us(y0); u.y = f2us(y1); u.z = f2us(y2); u.w = f2us(y3);
    ((ushort4*)w.out)[(size_t)row*64 + lane] = u;
  }
}

extern "C" void kernel_launch(void* const* d_in, const int* in_sizes, int n_in,
                              void* d_out, int out_size, void* d_ws, size_t ws_size,
                              hipStream_t stream)
{
  const void* V     = d_in[0];
  const int*  adj   = (const int*)d_in[1];
  const void* prev  = d_in[2];
  const void* W1    = d_in[3];
  // d_in[4] = sa0 : dead (row-shift invariant softmax)
  const void* sa1   = d_in[5];
  const void* ce_w1 = d_in[6];
  const void* ce_b1 = d_in[7];
  const void* ce_w2 = d_in[8];
  const void* ce_b2 = d_in[9];
  const void* ca0   = d_in[10];
  const void* ca1   = d_in[11];
  const void* te_w1 = d_in[12];
  const void* te_b1 = d_in[13];
  const void* te_w2 = d_in[14];
  const void* te_b2 = d_in[15];
  // d_in[16,17] = ta0,ta1 : dead
  const void* pe_w1 = d_in[18];
  const void* pe_b1 = d_in[19];
  const void* pe_w2 = d_in[20];
  const void* pe_b2 = d_in[21];
  // d_in[22,23] = pa0,pa1 : dead
  const void* W2    = d_in[24];
  const void* op_w  = d_in[25];
  const void* op_b  = d_in[26];
  const void* ln_g  = d_in[27];
  const void* ln_b  = d_in[28];

  // ---- workspace layout (floats) ----
  float* ws  = (float*)d_ws;
  int*  flag = (int*)ws;               // 16 floats reserved
  float* p   = ws + 16;
  float* Vf   = p; p += 131072;
  float* prevf= p; p += 131072;
  float* W1f  = p; p += 65536;
  float* sa1f = p; p += 256;
  float* cw1f = p; p += 131072;
  float* cb1f = p; p += 256;
  float* cw2f = p; p += 16384;
  float* cb2f = p; p += 64;
  float* ca0f = p; p += 64;
  float* ca1f = p; p += 64;
  float* tw1f = p; p += 131072;
  float* tb1f = p; p += 256;
  float* tw2f = p; p += 16384;
  float* tb2f = p; p += 64;
  float* pw1f = p; p += 196608;
  float* pb1f = p; p += 256;
  float* pw2f = p; p += 16384;
  float* pb2f = p; p += 64;
  float* W2f  = p; p += 98560;
  float* opwf = p; p += 65536;
  float* opbf = p; p += 256;
  float* lngf = p; p += 256;
  float* lnbf = p; p += 256;
  float* tw2t = p; p += 16384;
  float* pw2t = p; p += 16384;
  float* W2c  = p; p += 81920;
  float* W2midt = p; p += 16384;
  float* w384v  = p; p += 256;
  float* c2v    = p; p += 256;
  float* Wh1      = p; p += 131072;
  float* e1v      = p; p += 512;
  float* minv     = p; p += 512;
  float* invzv    = p; p += 512;
  float* H1p      = p; p += 1048576;
  float* Hc       = p; p += 163840;
  float* Am       = p; p += 131072;
  float* Bm       = p; p += 131072;
  float* uvec     = p; p += 256;
  float* beta     = p; p += 16;
  float* s2       = p; p += 262144;
  float* maxp     = p; p += 4096;
  float* zpart    = p; p += 4096;
  float* MZ       = p; p += 16;
  float* gsum     = p; p += 256;
  float* htp0     = p; p += 131072;
  float* htp1     = p; p += 131072;
  float* hpp0     = p; p += 131072;
  float* hpp1     = p; p += 131072;
  float* hpp2     = p; p += 131072;
  float* hidden_t = p; p += 131072;
  float* hidden_p = p; p += 131072;
  float* tfm      = p; p += 32768;
  float* cfm      = p; p += 32768;
  float* H4v      = p; p += 64;
  float* Xp       = p; p += 393216;
  float* out2     = p; p += 131072;
  float* out3     = p; p += 131072;

  // ---- pointer bundle ----
  WSP w;
  w.adj = adj; w.flag = flag; w.out = d_out;
  w.Vf=Vf; w.prevf=prevf; w.W1f=W1f; w.sa1f=sa1f; w.cw1f=cw1f; w.cb1f=cb1f;
  w.cw2f=cw2f; w.cb2f=cb2f; w.ca0f=ca0f; w.ca1f=ca1f;
  w.tw1f=tw1f; w.tb1f=tb1f; w.tw2f=tw2f; w.tb2f=tb2f;
  w.pw1f=pw1f; w.pb1f=pb1f; w.pw2f=pw2f; w.pb2f=pb2f;
  w.W2f=W2f; w.opwf=opwf; w.opbf=opbf; w.lngf=lngf; w.lnbf=lnbf;
  w.tw2t=tw2t; w.pw2t=pw2t; w.W2c=W2c; w.W2midt=W2midt; w.w384v=w384v; w.c2v=c2v;
  w.Wh1=Wh1; w.e1v=e1v; w.minv=minv; w.invzv=invzv; w.H1p=H1p; w.Hc=Hc;
  w.Am=Am; w.Bm=Bm; w.uvec=uvec; w.beta=beta;
  w.s2=s2; w.maxp=maxp; w.zp=zpart; w.MZ=MZ; w.gsum=gsum;
  w.htp0=htp0; w.htp1=htp1; w.hpp0=hpp0; w.hpp1=hpp1; w.hpp2=hpp2;
  w.hidden_t=hidden_t; w.hidden_p=hidden_p;
  w.tfm=tfm; w.cfm=cfm; w.H4v=H4v; w.Xp=Xp; w.out2=out2; w.out3=out3;

  // ---- fused convert + probe + packsel: 768 blocks ----
  {
    ConvArgs ca;
    const void* srcs[23] = {V, prev, W1, sa1, ce_w1, ce_b1, ce_w2, ce_b2, ca0, ca1,
                            te_w1, te_b1, te_w2, te_b2, pe_w1, pe_b1, pe_w2, pe_b2,
                            W2, op_w, op_b, ln_g, ln_b};
    float* dsts[23] = {Vf, prevf, W1f, sa1f, cw1f, cb1f, cw2f, cb2f, ca0f, ca1f,
                       tw1f, tb1f, tw2f, tb2f, pw1f, pb1f, pw2f, pb2f,
                       W2f, opwf, opbf, lngf, lnbf};
    int ns[23] = {131072, 131072, 65536, 256, 131072, 256, 16384, 64, 64, 64,
                  131072, 256, 16384, 64, 196608, 256, 16384, 64,
                  98560, 65536, 256, 256, 256};
    for (int s = 0; s < 23; ++s){ ca.src[s] = srcs[s]; ca.dst[s] = dsts[s]; ca.n[s] = ns[s]; }
    k_conv<<<768, 256, 0, stream>>>(ca, (const unsigned int*)V, adj, flag, Xp);
  }

  // ---- GEMM batch A: 8 segs x 32 tiles = 256 blocks ----
  {
    GArgs2 g{};
    g.s[0] = {Vf,       W1f,        Wh1,  256, 256, 256, 256};
    g.s[1] = {Vf,       cw1f,       Am,   256, 512, 256, 256};
    g.s[2] = {Vf,       cw1f + 256, Bm,   256, 512, 256, 256};
    g.s[3] = {Vf,       tw1f,       htp0, 256, 512, 256, 256};
    g.s[4] = {prevf,    tw1f + 256, htp1, 256, 512, 256, 256};
    g.s[5] = {Xp,       pw1f,       hpp0, 768, 768, 256, 256};
    g.s[6] = {Xp + 256, pw1f + 256, hpp1, 768, 768, 256, 256};
    g.s[7] = {Xp + 512, pw1f + 512, hpp2, 768, 768, 256, 256};
    k_gemmA<<<dim3(32, 8), 256, 0, stream>>>(g);
  }

  // ---- stage2: redH | e1 | ub | transposes | W2c/W2midt/w384 ----
  k_stage2<<<340, 256, 0, stream>>>(w);

  // ---- stage3: gemmB(reg) | h1stats | s2 ----
  k_stage3<<<1600, 256, 0, stream>>>(w);

  // ---- stage4: h4 | h1p | mz ----
  k_stage4<<<1033, 256, 0, stream>>>(w);

  // ---- stage5: gpart | h1r->Hc | h3->Hc ----
  k_stage5<<<1600, 256, 0, stream>>>(w);

  // ---- out2 GEMM + h2c ----
  k_out2g<<<129, 256, 0, stream>>>(w);

  // ---- out3 GEMM (fold c2 + h4 rank-1 terms) ----
  k_out3g<<<128, 256, 0, stream>>>(w);

  // ---- LN + ELU ----
  k_final<<<128, 256, 0, stream>>>(w);
}

// Round 7
// 243.481 us; speedup vs baseline: 1.8182x; 1.0052x over previous
//
#include <hip/hip_runtime.h>

typedef unsigned short u16;

constexpr int kN   = 512;
constexpr int kIN  = 256;
constexpr int kHID = 256;
constexpr int kHD  = 64;
constexpr int kOUT = 256;

// ---------- bf16 helpers ----------
__device__ __forceinline__ float us2f(u16 u){
  union { unsigned int i; float f; } c; c.i = ((unsigned int)u) << 16; return c.f;
}
__device__ __forceinline__ u16 f2us(float f){
  union { float f; unsigned int i; } c; c.f = f;
  unsigned int r = c.i + 0x7fff + ((c.i >> 16) & 1);
  return (u16)(r >> 16);
}

// ---------- per-block dtype probe (reads first 16KB of V) ----------
__device__ bool probe_is_f32(const unsigned int* __restrict__ V){
  __shared__ int cnt;
  if (threadIdx.x == 0) cnt = 0;
  __syncthreads();
  int c = 0;
  for (int k = threadIdx.x; k < 4096; k += 256){
    float x = us2f((u16)(V[k] & 0xffffu));
    if (!(fabsf(x) <= 32.0f)) c++;
  }
  atomicAdd(&cnt, c);
  __syncthreads();
  return cnt > 64;
}

// ---------- fused convert + probe + pairsel/packxp + zero e1 ----------
struct ConvArgs { const void* src[23]; float* dst[23]; int n[23]; };

__global__ __launch_bounds__(256) void k_conv(ConvArgs a, const unsigned int* __restrict__ Vraw,
                                              const int* __restrict__ adj, int* __restrict__ flag,
                                              float* __restrict__ Xp, float* __restrict__ e1v)
{
  int b = blockIdx.x, tid = threadIdx.x;
  bool f32 = probe_is_f32(Vraw);
  if (b < 256){
    if (b == 0){
      if (tid == 0) *flag = f32 ? 1 : 0;
      e1v[tid] = 0.f; e1v[tid + 256] = 0.f;
    }
    int t = b*256 + tid;
    const int stride = 65536;
    for (int s = 0; s < 23; ++s){
      int n4 = a.n[s] >> 2;
      float4* d = (float4*)a.dst[s];
      if (f32){
        const float4* sf = (const float4*)a.src[s];
        for (int i = t; i < n4; i += stride) d[i] = sf[i];
      } else {
        const ushort4* sb = (const ushort4*)a.src[s];
        for (int i = t; i < n4; i += stride){
          ushort4 u = sb[i];
          d[i] = make_float4(us2f(u.x), us2f(u.y), us2f(u.z), us2f(u.w));
        }
      }
    }
  } else {
    __shared__ unsigned long long msk[8];
    __shared__ int sj[2];
    int i = b - 256;
    int w = tid >> 6, lane = tid & 63;
    unsigned long long m0 = __ballot(adj[(size_t)i*kN + tid] != 0);
    unsigned long long m1 = __ballot(adj[(size_t)i*kN + 256 + tid] != 0);
    if (lane == 0){ msk[w] = m0; msk[4 + w] = m1; }
    __syncthreads();
    if (tid == 0){
      int j0 = -1, j1 = -1;
      for (int c = 0; c < 8 && j1 < 0; ++c){
        unsigned long long m = msk[c];
        while (m && j1 < 0){
          int bb = __builtin_ctzll(m);
          int j = c*64 + bb;
          if (j0 < 0) j0 = j; else j1 = j;
          m &= m - 1;
        }
      }
      if (j1 < 0) j0 = -1;
      sj[0] = j0; sj[1] = j1;
    }
    __syncthreads();
    int j0 = sj[0], j1 = sj[1];
    const float* Vf = (const float*)Vraw;
    const u16*  Vb = (const u16*)Vraw;
    auto rdV = [&](int r, int k)->float{
      return f32 ? Vf[(size_t)r*kIN + k] : us2f(Vb[(size_t)r*kIN + k]);
    };
    Xp[(size_t)i*768 + tid]       = rdV(i, tid);
    Xp[(size_t)i*768 + 256 + tid] = (j0 >= 0) ? rdV(j0, tid) : 0.f;
    Xp[(size_t)i*768 + 512 + tid] = (j1 >= 0) ? rdV(j1, tid) : 0.f;
  }
}

// ---------- block reduction (256 threads) ----------
__device__ __forceinline__ float blk_red(float v, float* tmp, bool isMax){
  int lane = threadIdx.x & 63, wv = threadIdx.x >> 6;
  #pragma unroll
  for (int o = 32; o > 0; o >>= 1){
    float t = __shfl_down(v, o, 64);
    v = isMax ? fmaxf(v, t) : (v + t);
  }
  __syncthreads();
  if (lane == 0) tmp[wv] = v;
  __syncthreads();
  float r = tmp[0];
  for (int i = 1; i < 4; ++i) r = isMax ? fmaxf(r, tmp[i]) : (r + tmp[i]);
  return r;
}

// ---------- workspace pointer bundle ----------
struct WSP {
  const int* adj; const int* flag; void* out;
  float *Vf,*prevf,*W1f,*sa1f,*cw1f,*cb1f,*cw2f,*cb2f,*ca0f,*ca1f;
  float *tw1f,*tb1f,*tw2f,*tb2f,*pw1f,*pb1f,*pw2f,*pb2f;
  float *W2f,*opwf,*opbf,*lngf,*lnbf;
  float *tw2t,*pw2t,*W2c,*W2midt,*w384v,*c2v;
  float *Wh1,*e1v,*minv,*invzv,*wadj,*Hc,*Am,*Bm,*uvec,*beta;
  float *s2,*maxp,*zp,*MZ,*gsum;
  float *htp0,*htp1,*hpp0,*hpp1,*hpp2,*hidden_t,*hidden_p;
  float *tfm,*cfm,*H4v,*Xp,*out2,*out3;
};

// ================== GEMM A: 64x64 tile, BK=32, 4x4 micro, dbuf ==================
struct GSeg2 { const float* X; const float* W; float* C; int ldx, ldw, ldc, K; };
struct GArgs2 { GSeg2 s[8]; const float* sa1; float* e1; };

__global__ __launch_bounds__(256) void k_gemmA(GArgs2 ga)
{
  __shared__ __align__(16) float Xs[2][32][68];
  __shared__ __align__(16) float Ws[2][32][68];
  const GSeg2 sg = ga.s[blockIdx.y];
  const int tm = blockIdx.x & 7;
  const int tn = blockIdx.x >> 3;
  const int i0 = tm << 6;
  const int n0 = tn << 6;
  const int tid = threadIdx.x;

  const int xrow = tid >> 3;
  const int xk   = (tid & 7) << 2;
  const int rg = (tid >> 4) << 2;
  const int cg = (tid & 15) << 2;

  const float* Xb = sg.X + (size_t)i0 * sg.ldx;
  const float* Wb = sg.W + (size_t)n0 * sg.ldw;

  float4 xr0, xr1, wr0, wr1;
  auto loadT = [&](int kt){
    xr0 = *(const float4*)(Xb + (size_t)xrow * sg.ldx + kt + xk);
    xr1 = *(const float4*)(Xb + (size_t)(xrow+32) * sg.ldx + kt + xk);
    wr0 = *(const float4*)(Wb + (size_t)xrow * sg.ldw + kt + xk);
    wr1 = *(const float4*)(Wb + (size_t)(xrow+32) * sg.ldw + kt + xk);
  };
  auto writeT = [&](int bu){
    Xs[bu][xk+0][xrow] = xr0.x;  Xs[bu][xk+1][xrow] = xr0.y;
    Xs[bu][xk+2][xrow] = xr0.z;  Xs[bu][xk+3][xrow] = xr0.w;
    Xs[bu][xk+0][xrow+32] = xr1.x;  Xs[bu][xk+1][xrow+32] = xr1.y;
    Xs[bu][xk+2][xrow+32] = xr1.z;  Xs[bu][xk+3][xrow+32] = xr1.w;
    Ws[bu][xk+0][xrow]    = wr0.x; Ws[bu][xk+1][xrow]    = wr0.y;
    Ws[bu][xk+2][xrow]    = wr0.z; Ws[bu][xk+3][xrow]    = wr0.w;
    Ws[bu][xk+0][xrow+32] = wr1.x; Ws[bu][xk+1][xrow+32] = wr1.y;
    Ws[bu][xk+2][xrow+32] = wr1.z; Ws[bu][xk+3][xrow+32] = wr1.w;
  };

  loadT(0); writeT(0); __syncthreads();

  float acc[4][4] = {};
  const int nkt = sg.K >> 5;
  for (int t = 0; t < nkt; ++t){
    if (t + 1 < nkt) loadT((t + 1) << 5);
    const int bu = t & 1;
    #pragma unroll
    for (int kk = 0; kk < 32; ++kk){
      const float4 av = *(const float4*)&Xs[bu][kk][rg];
      const float4 bv = *(const float4*)&Ws[bu][kk][cg];
      acc[0][0]+=av.x*bv.x; acc[0][1]+=av.x*bv.y; acc[0][2]+=av.x*bv.z; acc[0][3]+=av.x*bv.w;
      acc[1][0]+=av.y*bv.x; acc[1][1]+=av.y*bv.y; acc[1][2]+=av.y*bv.z; acc[1][3]+=av.y*bv.w;
      acc[2][0]+=av.z*bv.x; acc[2][1]+=av.z*bv.y; acc[2][2]+=av.z*bv.z; acc[2][3]+=av.z*bv.w;
      acc[3][0]+=av.w*bv.x; acc[3][1]+=av.w*bv.y; acc[3][2]+=av.w*bv.z; acc[3][3]+=av.w*bv.w;
    }
    if (t + 1 < nkt) writeT((t + 1) & 1);
    __syncthreads();
  }

  #pragma unroll
  for (int ri = 0; ri < 4; ++ri)
    *(float4*)(sg.C + (size_t)(i0 + rg + ri) * sg.ldc + (n0 + cg)) =
      make_float4(acc[ri][0], acc[ri][1], acc[ri][2], acc[ri][3]);

  // seg 0 = Wh1: fused e1 partial (e1[j] = Wh1[j,:].sa1)
  if (blockIdx.y == 0){
    int cb = n0 + cg;
    float s0 = ga.sa1[cb], s1 = ga.sa1[cb+1], s2v = ga.sa1[cb+2], s3 = ga.sa1[cb+3];
    #pragma unroll
    for (int ri = 0; ri < 4; ++ri){
      float v = acc[ri][0]*s0 + acc[ri][1]*s1 + acc[ri][2]*s2v + acc[ri][3]*s3;
      v += __shfl_xor(v, 1, 16);
      v += __shfl_xor(v, 2, 16);
      v += __shfl_xor(v, 4, 16);
      v += __shfl_xor(v, 8, 16);
      if ((tid & 15) == 0) atomicAdd(&ga.e1[i0 + rg + ri], v);
    }
  }
}

// ================== GEMM-32 body: 32x32 tile, BK=32, 2x2 micro, dbuf ==================
// bkn=0: W row-major [n][k]; bkn=1: W row-major [k][n] (no transpose needed)
// optional fold: X'[i][k] = X[i][k] + c2[k] + h4(i)*w384[k]
struct GS32 { const float* X; const float* W; float* C; int ldx, ldw, ldc, K;
              const float* c2; const float* w384; const float* h4; int bkn; };

__device__ __forceinline__ void gemm32_body(const GS32 sg, int tm, int tn, int tid,
                                            float* Xs, float* Ws)
{
  const int i0 = tm << 5, n0 = tn << 5;
  const int xrow = tid >> 3;           // 0..31
  const int xk = (tid & 7) << 2;       // 0..28
  const int rg = (tid >> 4) << 1;      // 0..30
  const int cg = (tid & 15) << 1;      // 0..30
  const float* Xb = sg.X + (size_t)i0 * sg.ldx;
  const float* Wb = sg.bkn ? (sg.W + n0) : (sg.W + (size_t)n0 * sg.ldw);
  float h4r = 0.f;
  if (sg.h4){ int i = i0 + xrow; h4r = (i < 64) ? sg.h4[i] : 0.f; }
  float4 xr, wr;
  auto loadT = [&](int kt){
    xr = *(const float4*)(Xb + (size_t)xrow * sg.ldx + kt + xk);
    if (sg.bkn) wr = *(const float4*)(Wb + (size_t)(kt + xrow) * sg.ldw + xk);
    else        wr = *(const float4*)(Wb + (size_t)xrow * sg.ldw + kt + xk);
    if (sg.c2){
      float4 c = *(const float4*)(sg.c2 + kt + xk);
      float4 w3 = *(const float4*)(sg.w384 + kt + xk);
      xr.x += c.x + h4r*w3.x; xr.y += c.y + h4r*w3.y;
      xr.z += c.z + h4r*w3.z; xr.w += c.w + h4r*w3.w;
    }
  };
  auto writeT = [&](int bu){
    float* xs = Xs + bu*1152;
    xs[(xk+0)*36 + xrow] = xr.x; xs[(xk+1)*36 + xrow] = xr.y;
    xs[(xk+2)*36 + xrow] = xr.z; xs[(xk+3)*36 + xrow] = xr.w;
    float* wsp = Ws + bu*1152;
    if (sg.bkn){
      wsp[xrow*36 + xk+0] = wr.x; wsp[xrow*36 + xk+1] = wr.y;
      wsp[xrow*36 + xk+2] = wr.z; wsp[xrow*36 + xk+3] = wr.w;
    } else {
      wsp[(xk+0)*36 + xrow] = wr.x; wsp[(xk+1)*36 + xrow] = wr.y;
      wsp[(xk+2)*36 + xrow] = wr.z; wsp[(xk+3)*36 + xrow] = wr.w;
    }
  };
  loadT(0); writeT(0); __syncthreads();
  float a00=0,a01=0,a10=0,a11=0;
  const int nkt = sg.K >> 5;
  for (int t = 0; t < nkt; ++t){
    if (t+1 < nkt) loadT((t+1) << 5);
    const float* xs = Xs + (t&1)*1152;
    const float* wsp = Ws + (t&1)*1152;
    #pragma unroll
    for (int kk = 0; kk < 32; ++kk){
      float2 av = *(const float2*)&xs[kk*36 + rg];
      float2 bv = *(const float2*)&wsp[kk*36 + cg];
      a00 += av.x*bv.x; a01 += av.x*bv.y;
      a10 += av.y*bv.x; a11 += av.y*bv.y;
    }
    if (t+1 < nkt) writeT((t+1)&1);
    __syncthreads();
  }
  float* cp = sg.C + (size_t)(i0+rg)*sg.ldc + n0 + cg;
  *(float2*)cp = make_float2(a00, a01);
  *(float2*)(cp + sg.ldc) = make_float2(a10, a11);
}

// ---------- stage2: [0,128) redH | [128,640) h1stats | 640 ub+zeroH4v |
//            641,642 tw2t/pw2t | [643,707) W2c | [707,723) W2midt | 723 w384 ----------
__global__ __launch_bounds__(256) void k_stage2(WSP w)
{
  __shared__ float st[64*65];
  int b = blockIdx.x, tid = threadIdx.x;
  if (b < 128){
    int f = b*256 + tid;
    int c4 = f & 63;
    {
      float4 a = ((const float4*)w.htp0)[f], bb = ((const float4*)w.htp1)[f];
      float4 bi = ((const float4*)w.tb1f)[c4];
      ((float4*)w.hidden_t)[f] = make_float4(
        fmaxf(a.x+bb.x+bi.x,0.f), fmaxf(a.y+bb.y+bi.y,0.f),
        fmaxf(a.z+bb.z+bi.z,0.f), fmaxf(a.w+bb.w+bi.w,0.f));
    }
    {
      float4 a = ((const float4*)w.hpp0)[f], bb = ((const float4*)w.hpp1)[f];
      float4 c = ((const float4*)w.hpp2)[f];
      float4 bi = ((const float4*)w.pb1f)[c4];
      ((float4*)w.hidden_p)[f] = make_float4(
        fmaxf(a.x+bb.x+c.x+bi.x,0.f), fmaxf(a.y+bb.y+c.y+bi.y,0.f),
        fmaxf(a.z+bb.z+c.z+bi.z,0.f), fmaxf(a.w+bb.w+c.w+bi.w,0.f));
    }
  } else if (b < 640){
    float* red = st;
    int i = b - 128;
    int m0 = w.adj[(size_t)i*kN + tid];
    int m1 = w.adj[(size_t)i*kN + tid + 256];
    float ea = w.e1v[tid], eb = w.e1v[tid+256];
    float v0 = m0 ? ea : -1e30f;
    float v1 = m1 ? eb : -1e30f;
    float m = blk_red(fmaxf(v0, v1), red, true);
    float z = blk_red((m0 ? expf(ea-m) : 0.f) + (m1 ? expf(eb-m) : 0.f), red, false);
    if (tid == 0){ w.minv[i] = m; w.invzv[i] = 1.0f / z; }
  } else if (b == 640){
    if (tid < 64){ st[tid] = w.ca0f[tid] + w.ca1f[tid]; w.H4v[tid] = 0.f; }
    __syncthreads();
    float a = 0.f;
    for (int d = 0; d < kHD; ++d) a += w.cw2f[(size_t)d*kHID + tid] * st[d];
    w.uvec[tid] = a;
    if (tid == 0){
      float bsum = 0.f;
      for (int d = 0; d < kHD; ++d) bsum += w.cb2f[d] * st[d];
      *w.beta = bsum;
    }
  } else if (b < 643){
    const float* src = (b == 641) ? w.tw2f : w.pw2f;
    float* dst = (b == 641) ? w.tw2t : w.pw2t;
    for (int ch = 0; ch < 4; ++ch){
      __syncthreads();
      #pragma unroll
      for (int e = 0; e < 16; ++e){
        int lin = e*256 + tid;
        int r = lin >> 6, c = lin & 63;
        st[r*65 + c] = src[(size_t)r*256 + ch*64 + c];
      }
      __syncthreads();
      #pragma unroll
      for (int e = 0; e < 16; ++e){
        int lin = e*256 + tid;
        int kc = lin >> 6, dd = lin & 63;
        dst[(size_t)(ch*64 + kc)*64 + dd] = st[dd*65 + kc];
      }
    }
  } else if (b < 707){
    int o0 = (b - 643) * 4;
    for (int r = 0; r < 4; ++r){
      int o = o0 + r;
      const float* src = w.W2f + (size_t)o * 385;
      float* dst = w.W2c + (size_t)o * 320;
      for (int c = tid; c < 320; c += 256)
        dst[c] = src[(c < 256) ? c : c + 64];
    }
  } else if (b < 723){
    int d0 = (b - 707) * 4;
    #pragma unroll
    for (int dd = 0; dd < 4; ++dd)
      w.W2midt[(size_t)(d0+dd)*256 + tid] = w.W2f[(size_t)tid*385 + 256 + d0 + dd];
  } else {
    w.w384v[tid] = w.W2f[(size_t)tid*385 + 384];
  }
}

// ---------- stage3: [0,64) gemmB(reg) | [64,576) wadj | [576,1600) s2 ----------
__global__ __launch_bounds__(256) void k_stage3(WSP w)
{
  __shared__ __align__(16) float smem3[4*256 + 256];
  int b = blockIdx.x, tid = threadIdx.x;
  if (b < 64){
    int m = b >> 5, grp = b & 31;
    const float* X  = m ? w.hidden_p : w.hidden_t;
    const float* Wt = m ? w.pw2t : w.tw2t;
    const float* bi = m ? w.pb2f : w.tb2f;
    float* C = m ? w.cfm : w.tfm;
    int i0 = grp*16 + (tid >> 6)*4;
    int d = tid & 63;
    const float* x0 = X + (size_t)i0*256;
    const float* x1 = x0 + 256;
    const float* x2 = x0 + 512;
    const float* x3 = x0 + 768;
    float a0=0.f, a1=0.f, a2=0.f, a3=0.f;
    for (int k = 0; k < 256; k += 4){
      float w0 = Wt[(size_t)(k+0)*64 + d];
      float w1 = Wt[(size_t)(k+1)*64 + d];
      float w2 = Wt[(size_t)(k+2)*64 + d];
      float w3 = Wt[(size_t)(k+3)*64 + d];
      float4 f0 = *(const float4*)(x0 + k);
      float4 f1 = *(const float4*)(x1 + k);
      float4 f2 = *(const float4*)(x2 + k);
      float4 f3 = *(const float4*)(x3 + k);
      a0 += f0.x*w0 + f0.y*w1 + f0.z*w2 + f0.w*w3;
      a1 += f1.x*w0 + f1.y*w1 + f1.z*w2 + f1.w*w3;
      a2 += f2.x*w0 + f2.y*w1 + f2.z*w2 + f2.w*w3;
      a3 += f3.x*w0 + f3.y*w1 + f3.z*w2 + f3.w*w3;
    }
    float bd = bi[d];
    C[(size_t)(i0+0)*64 + d] = a0 + bd;
    C[(size_t)(i0+1)*64 + d] = a1 + bd;
    C[(size_t)(i0+2)*64 + d] = a2 + bd;
    C[(size_t)(i0+3)*64 + d] = a3 + bd;
  } else if (b < 576){
    int i = b - 64;
    float mi = w.minv[i], zi = w.invzv[i];
    w.wadj[(size_t)i*kN + tid] =
      w.adj[(size_t)i*kN + tid] ? expf(w.e1v[tid] - mi) * zi : 0.f;
    w.wadj[(size_t)i*kN + tid + 256] =
      w.adj[(size_t)i*kN + tid + 256] ? expf(w.e1v[tid+256] - mi) * zi : 0.f;
  } else {
    float* aib = smem3;                 // [4][256]
    float* uu  = smem3 + 1024;          // [256]
    int q = b - 576;
    int i0 = (q & 127) * 4, j0 = (q >> 7) * 64;
    int wv = tid >> 6, lane = tid & 63;
    uu[tid] = w.uvec[tid];
    float b1v = w.cb1f[tid];
    #pragma unroll
    for (int r = 0; r < 4; ++r) aib[r*256 + tid] = w.Am[(size_t)(i0+r)*kHID + tid] + b1v;
    __syncthreads();
    int i = i0 + wv, j = j0 + lane;
    const float4* bp = (const float4*)(w.Bm + (size_t)j*kHID);
    float acc = *w.beta;
    #pragma unroll 8
    for (int k4 = 0; k4 < kHID/4; ++k4){
      float4 bv = bp[k4];
      float4 a4 = *(const float4*)&aib[wv*256 + k4*4];
      float4 u4 = *(const float4*)&uu[k4*4];
      acc += fmaxf(a4.x+bv.x,0.f)*u4.x + fmaxf(a4.y+bv.y,0.f)*u4.y
           + fmaxf(a4.z+bv.z,0.f)*u4.z + fmaxf(a4.w+bv.w,0.f)*u4.w;
    }
    if (j == i) acc = -1e30f;
    w.s2[(size_t)i*kN + j] = acc;
    float m = acc;
    #pragma unroll
    for (int o = 32; o > 0; o >>= 1) m = fmaxf(m, __shfl_down(m, o, 64));
    m = __shfl(m, 0, 64);
    float e = expf(acc - m);
    #pragma unroll
    for (int o = 32; o > 0; o >>= 1) e += __shfl_down(e, o, 64);
    if (lane == 0){
      int pb = q*4 + wv;
      w.maxp[pb] = m; w.zp[pb] = e;
    }
  }
}

// ---------- stage4: [0,128) H1gemm->Hc | [128,192) h3->Hc | [192,200) h4 | 200 mz+zero gsum ----------
__global__ __launch_bounds__(256) void k_stage4(WSP w)
{
  __shared__ __align__(16) char smem[18432];
  int b = blockIdx.x, tid = threadIdx.x;
  if (b < 128){
    // H1 = wadj[512x512] @ Wh1[512x256]  (Wh1 already [k][n]) -> Hc cols 0..255
    GS32 sg{w.wadj, w.Wh1, w.Hc, 512, 256, 320, 512, nullptr, nullptr, nullptr, 1};
    gemm32_body(sg, b & 15, b >> 4, tid, (float*)smem, (float*)(smem + 9216));
  } else if (b < 192){
    int d = b - 128;
    int lane = tid & 63, wv = tid >> 6;
    float v0 = w.tfm[(size_t)(2*tid)*kHD + d];
    float v1 = w.tfm[(size_t)(2*tid+1)*kHD + d];
    float s = v0 + v1;
    float x = s;
    #pragma unroll
    for (int off = 1; off < 64; off <<= 1){
      float y = __shfl_up(x, off, 64);
      if (lane >= off) x += y;
    }
    float* wsum = (float*)smem;
    if (lane == 63) wsum[wv] = x;
    __syncthreads();
    float base = 0.f;
    for (int k = 0; k < wv; ++k) base += wsum[k];
    float excl = base + x - s;
    w.Hc[(size_t)(2*tid)*320 + 256 + d]   = (excl + v0) / (float)(2*tid + 1);
    w.Hc[(size_t)(2*tid+1)*320 + 256 + d] = (excl + s)  / (float)(2*tid + 2);
  } else if (b < 200){
    float* sm = (float*)smem;
    int d = tid & 63, sub = tid >> 6;
    int r0 = (b-192)*64 + sub*16;
    float s = 0.f;
    #pragma unroll
    for (int e = 0; e < 16; ++e) s += w.cfm[(size_t)(r0+e)*kHD + d];
    sm[sub*64 + d] = s;
    __syncthreads();
    if (tid < 64)
      atomicAdd(&w.H4v[tid], sm[tid] + sm[64+tid] + sm[128+tid] + sm[192+tid]);
  } else {
    float* red = (float*)smem;
    float m = -1e30f;
    #pragma unroll
    for (int r = 0; r < 16; ++r) m = fmaxf(m, w.maxp[tid + 256*r]);
    m = blk_red(m, red, true);
    float z = 0.f;
    #pragma unroll
    for (int r = 0; r < 16; ++r) z += w.zp[tid + 256*r] * expf(w.maxp[tid + 256*r] - m);
    z = blk_red(z, red, false);
    if (tid == 0){ w.MZ[0] = m; w.MZ[1] = z; }
    w.gsum[tid] = 0.f;
  }
}

// ---------- stage5: [0,1024) gpart | [1024,1152) out2 tiles ----------
__global__ __launch_bounds__(256) void k_stage5(WSP w)
{
  __shared__ __align__(16) char smem[18432];
  int b = blockIdx.x, tid = threadIdx.x;
  if (b < 1024){
    float* wt = (float*)smem;        // [16][16]
    int i0 = (b & 31) * 16, j0 = (b >> 5) * 16;
    float M = w.MZ[0], invZ = 1.0f / w.MZ[1];
    {
      int r = tid >> 4, c = tid & 15;
      wt[r*16 + c] = expf(w.s2[(size_t)(i0+r)*kN + (j0+c)] - M) * invZ;
    }
    float b1v = w.cb1f[tid];
    float aib[16];
    #pragma unroll
    for (int r = 0; r < 16; ++r) aib[r] = w.Am[(size_t)(i0+r)*kHID + tid] + b1v;
    __syncthreads();
    float acc = 0.f;
    for (int j = 0; j < 16; ++j){
      float bj = w.Bm[(size_t)(j0+j)*kHID + tid];
      #pragma unroll
      for (int r = 0; r < 16; ++r)
        acc += wt[r*16 + j] * fmaxf(aib[r] + bj, 0.f);
    }
    atomicAdd(&w.gsum[tid], acc);
  } else {
    int q = b - 1024;
    GS32 sg{w.Hc, w.W2c, w.out2, 320, 320, 256, 320, nullptr, nullptr, nullptr, 0};
    gemm32_body(sg, q & 15, q >> 4, tid, (float*)smem, (float*)(smem + 9216));
  }
}

// ---------- h2c: gsum -> H2vec -> c2v (1 block) ----------
__global__ void k_h2c(WSP w)
{
  __shared__ float gs[kHID];
  __shared__ float part[kHD][4];
  __shared__ float h2s[kHD];
  int tid = threadIdx.x;
  gs[tid] = w.gsum[tid];
  __syncthreads();
  int dd = tid >> 2, q = tid & 3;
  float a = 0.f;
  for (int kk = 0; kk < 64; ++kk){
    int k = q*64 + kk;
    a += gs[k] * w.cw2f[(size_t)dd*kHID + k];
  }
  part[dd][q] = a;
  __syncthreads();
  if (tid < kHD)
    h2s[tid] = w.cb2f[tid] + part[tid][0] + part[tid][1] + part[tid][2] + part[tid][3];
  __syncthreads();
  float c = 0.f;
  for (int d = 0; d < kHD; ++d) c += h2s[d] * w.W2midt[(size_t)d*256 + tid];
  w.c2v[tid] = c;
}

// ---------- out3 GEMM: (out2 + c2 + h4col*w384) @ opw^T ----------
__global__ __launch_bounds__(256) void k_out3g(WSP w)
{
  __shared__ __align__(16) char smem[18432];
  GS32 sg{w.out2, w.opwf, w.out3, 256, 256, 256, 256, w.c2v, w.w384v, w.H4v, 0};
  gemm32_body(sg, blockIdx.x & 15, blockIdx.x >> 4, threadIdx.x, (float*)smem, (float*)(smem + 9216));
}

// ---------- final: wave-per-row LN + ELU, grid 128 ----------
__global__ __launch_bounds__(256) void k_final(WSP w)
{
  int b = blockIdx.x, tid = threadIdx.x;
  int row = b*4 + (tid >> 6), lane = tid & 63;
  float4 v = *(const float4*)(w.out3 + (size_t)row*kOUT + lane*4);
  float4 pb = *(const float4*)(w.opbf + lane*4);
  v.x += pb.x; v.y += pb.y; v.z += pb.z; v.w += pb.w;
  float s = v.x + v.y + v.z + v.w;
  #pragma unroll
  for (int o = 32; o > 0; o >>= 1) s += __shfl_xor(s, o, 64);
  float mu = s * (1.0f/kOUT);
  float dx = v.x-mu, dy = v.y-mu, dz = v.z-mu, dw = v.w-mu;
  float ss = dx*dx + dy*dy + dz*dz + dw*dw;
  #pragma unroll
  for (int o = 32; o > 0; o >>= 1) ss += __shfl_xor(ss, o, 64);
  float rs = rsqrtf(ss * (1.0f/kOUT) + 1e-5f);
  float4 g = *(const float4*)(w.lngf + lane*4);
  float4 be = *(const float4*)(w.lnbf + lane*4);
  float y0 = dx*rs*g.x + be.x, y1 = dy*rs*g.y + be.y;
  float y2 = dz*rs*g.z + be.z, y3 = dw*rs*g.w + be.w;
  y0 = (y0 > 0.f) ? y0 : expm1f(y0);
  y1 = (y1 > 0.f) ? y1 : expm1f(y1);
  y2 = (y2 > 0.f) ? y2 : expm1f(y2);
  y3 = (y3 > 0.f) ? y3 : expm1f(y3);
  if (*w.flag){
    *(float4*)((float*)w.out + (size_t)row*kOUT + lane*4) = make_float4(y0,y1,y2,y3);
  } else {
    ushort4 u; u.x = f2us(y0); u.y = f2us(y1); u.z = f2us(y2); u.w = f2us(y3);
    ((ushort4*)w.out)[(size_t)row*64 + lane] = u;
  }
}

extern "C" void kernel_launch(void* const* d_in, const int* in_sizes, int n_in,
                              void* d_out, int out_size, void* d_ws, size_t ws_size,
                              hipStream_t stream)
{
  const void* V     = d_in[0];
  const int*  adj   = (const int*)d_in[1];
  const void* prev  = d_in[2];
  const void* W1    = d_in[3];
  // d_in[4] = sa0 : dead (row-shift invariant softmax)
  const void* sa1   = d_in[5];
  const void* ce_w1 = d_in[6];
  const void* ce_b1 = d_in[7];
  const void* ce_w2 = d_in[8];
  const void* ce_b2 = d_in[9];
  const void* ca0   = d_in[10];
  const void* ca1   = d_in[11];
  const void* te_w1 = d_in[12];
  const void* te_b1 = d_in[13];
  const void* te_w2 = d_in[14];
  const void* te_b2 = d_in[15];
  // d_in[16,17] = ta0,ta1 : dead
  const void* pe_w1 = d_in[18];
  const void* pe_b1 = d_in[19];
  const void* pe_w2 = d_in[20];
  const void* pe_b2 = d_in[21];
  // d_in[22,23] = pa0,pa1 : dead
  const void* W2    = d_in[24];
  const void* op_w  = d_in[25];
  const void* op_b  = d_in[26];
  const void* ln_g  = d_in[27];
  const void* ln_b  = d_in[28];

  // ---- workspace layout (floats) ----
  float* ws  = (float*)d_ws;
  int*  flag = (int*)ws;               // 16 floats reserved
  float* p   = ws + 16;
  float* Vf   = p; p += 131072;
  float* prevf= p; p += 131072;
  float* W1f  = p; p += 65536;
  float* sa1f = p; p += 256;
  float* cw1f = p; p += 131072;
  float* cb1f = p; p += 256;
  float* cw2f = p; p += 16384;
  float* cb2f = p; p += 64;
  float* ca0f = p; p += 64;
  float* ca1f = p; p += 64;
  float* tw1f = p; p += 131072;
  float* tb1f = p; p += 256;
  float* tw2f = p; p += 16384;
  float* tb2f = p; p += 64;
  float* pw1f = p; p += 196608;
  float* pb1f = p; p += 256;
  float* pw2f = p; p += 16384;
  float* pb2f = p; p += 64;
  float* W2f  = p; p += 98560;
  float* opwf = p; p += 65536;
  float* opbf = p; p += 256;
  float* lngf = p; p += 256;
  float* lnbf = p; p += 256;
  float* tw2t = p; p += 16384;
  float* pw2t = p; p += 16384;
  float* W2c  = p; p += 81920;
  float* W2midt = p; p += 16384;
  float* w384v  = p; p += 256;
  float* c2v    = p; p += 256;
  float* Wh1      = p; p += 131072;
  float* e1v      = p; p += 512;
  float* minv     = p; p += 512;
  float* invzv    = p; p += 512;
  float* wadj     = p; p += 262144;
  float* Hc       = p; p += 163840;
  float* Am       = p; p += 131072;
  float* Bm       = p; p += 131072;
  float* uvec     = p; p += 256;
  float* beta     = p; p += 16;
  float* s2       = p; p += 262144;
  float* maxp     = p; p += 4096;
  float* zpart    = p; p += 4096;
  float* MZ       = p; p += 16;
  float* gsum     = p; p += 256;
  float* htp0     = p; p += 131072;
  float* htp1     = p; p += 131072;
  float* hpp0     = p; p += 131072;
  float* hpp1     = p; p += 131072;
  float* hpp2     = p; p += 131072;
  float* hidden_t = p; p += 131072;
  float* hidden_p = p; p += 131072;
  float* tfm      = p; p += 32768;
  float* cfm      = p; p += 32768;
  float* H4v      = p; p += 64;
  float* Xp       = p; p += 393216;
  float* out2     = p; p += 131072;
  float* out3     = p; p += 131072;

  // ---- pointer bundle ----
  WSP w;
  w.adj = adj; w.flag = flag; w.out = d_out;
  w.Vf=Vf; w.prevf=prevf; w.W1f=W1f; w.sa1f=sa1f; w.cw1f=cw1f; w.cb1f=cb1f;
  w.cw2f=cw2f; w.cb2f=cb2f; w.ca0f=ca0f; w.ca1f=ca1f;
  w.tw1f=tw1f; w.tb1f=tb1f; w.tw2f=tw2f; w.tb2f=tb2f;
  w.pw1f=pw1f; w.pb1f=pb1f; w.pw2f=pw2f; w.pb2f=pb2f;
  w.W2f=W2f; w.opwf=opwf; w.opbf=opbf; w.lngf=lngf; w.lnbf=lnbf;
  w.tw2t=tw2t; w.pw2t=pw2t; w.W2c=W2c; w.W2midt=W2midt; w.w384v=w384v; w.c2v=c2v;
  w.Wh1=Wh1; w.e1v=e1v; w.minv=minv; w.invzv=invzv; w.wadj=wadj; w.Hc=Hc;
  w.Am=Am; w.Bm=Bm; w.uvec=uvec; w.beta=beta;
  w.s2=s2; w.maxp=maxp; w.zp=zpart; w.MZ=MZ; w.gsum=gsum;
  w.htp0=htp0; w.htp1=htp1; w.hpp0=hpp0; w.hpp1=hpp1; w.hpp2=hpp2;
  w.hidden_t=hidden_t; w.hidden_p=hidden_p;
  w.tfm=tfm; w.cfm=cfm; w.H4v=H4v; w.Xp=Xp; w.out2=out2; w.out3=out3;

  // ---- fused convert + probe + packsel + zero e1: 768 blocks ----
  {
    ConvArgs ca;
    const void* srcs[23] = {V, prev, W1, sa1, ce_w1, ce_b1, ce_w2, ce_b2, ca0, ca1,
                            te_w1, te_b1, te_w2, te_b2, pe_w1, pe_b1, pe_w2, pe_b2,
                            W2, op_w, op_b, ln_g, ln_b};
    float* dsts[23] = {Vf, prevf, W1f, sa1f, cw1f, cb1f, cw2f, cb2f, ca0f, ca1f,
                       tw1f, tb1f, tw2f, tb2f, pw1f, pb1f, pw2f, pb2f,
                       W2f, opwf, opbf, lngf, lnbf};
    int ns[23] = {131072, 131072, 65536, 256, 131072, 256, 16384, 64, 64, 64,
                  131072, 256, 16384, 64, 196608, 256, 16384, 64,
                  98560, 65536, 256, 256, 256};
    for (int s = 0; s < 23; ++s){ ca.src[s] = srcs[s]; ca.dst[s] = dsts[s]; ca.n[s] = ns[s]; }
    k_conv<<<768, 256, 0, stream>>>(ca, (const unsigned int*)V, adj, flag, Xp, e1v);
  }

  // ---- GEMM batch A: 8 segs x 32 tiles = 256 blocks (+ fused e1 partials) ----
  {
    GArgs2 g{};
    g.s[0] = {Vf,       W1f,        Wh1,  256, 256, 256, 256};
    g.s[1] = {Vf,       cw1f,       Am,   256, 512, 256, 256};
    g.s[2] = {Vf,       cw1f + 256, Bm,   256, 512, 256, 256};
    g.s[3] = {Vf,       tw1f,       htp0, 256, 512, 256, 256};
    g.s[4] = {prevf,    tw1f + 256, htp1, 256, 512, 256, 256};
    g.s[5] = {Xp,       pw1f,       hpp0, 768, 768, 256, 256};
    g.s[6] = {Xp + 256, pw1f + 256, hpp1, 768, 768, 256, 256};
    g.s[7] = {Xp + 512, pw1f + 512, hpp2, 768, 768, 256, 256};
    g.sa1 = sa1f; g.e1 = e1v;
    k_gemmA<<<dim3(32, 8), 256, 0, stream>>>(g);
  }

  // ---- stage2: redH | h1stats | ub | transposes | W2 packs ----
  k_stage2<<<724, 256, 0, stream>>>(w);

  // ---- stage3: gemmB | wadj | s2 ----
  k_stage3<<<1600, 256, 0, stream>>>(w);

  // ---- stage4: H1gemm->Hc | h3->Hc | h4 | mz ----
  k_stage4<<<201, 256, 0, stream>>>(w);

  // ---- stage5: gpart | out2 tiles ----
  k_stage5<<<1152, 256, 0, stream>>>(w);

  // ---- h2c -> c2v ----
  k_h2c<<<1, 256, 0, stream>>>(w);

  // ---- out3 GEMM (fold c2 + h4 rank-1 terms) ----
  k_out3g<<<128, 256, 0, stream>>>(w);

  // ---- LN + ELU ----
  k_final<<<128, 256, 0, stream>>>(w);
}

// Round 8
// 243.020 us; speedup vs baseline: 1.8216x; 1.0019x over previous
//
#include <hip/hip_runtime.h>

typedef unsigned short u16;

constexpr int kN   = 512;
constexpr int kIN  = 256;
constexpr int kHID = 256;
constexpr int kHD  = 64;
constexpr int kOUT = 256;

// ---------- bf16 helpers ----------
__device__ __forceinline__ float us2f(u16 u){
  union { unsigned int i; float f; } c; c.i = ((unsigned int)u) << 16; return c.f;
}
__device__ __forceinline__ u16 f2us(float f){
  union { float f; unsigned int i; } c; c.f = f;
  unsigned int r = c.i + 0x7fff + ((c.i >> 16) & 1);
  return (u16)(r >> 16);
}

// ---------- per-block dtype probe (reads first 16KB of V) ----------
__device__ bool probe_is_f32(const unsigned int* __restrict__ V){
  __shared__ int cnt;
  if (threadIdx.x == 0) cnt = 0;
  __syncthreads();
  int c = 0;
  for (int k = threadIdx.x; k < 4096; k += 256){
    float x = us2f((u16)(V[k] & 0xffffu));
    if (!(fabsf(x) <= 32.0f)) c++;
  }
  atomicAdd(&cnt, c);
  __syncthreads();
  return cnt > 64;
}

// ---------- fused convert + probe + pairsel/packxp + zero e1 ----------
struct ConvArgs { const void* src[23]; float* dst[23]; int n[23]; };

__global__ __launch_bounds__(256) void k_conv(ConvArgs a, const unsigned int* __restrict__ Vraw,
                                              const int* __restrict__ adj, int* __restrict__ flag,
                                              float* __restrict__ Xp, float* __restrict__ e1v)
{
  int b = blockIdx.x, tid = threadIdx.x;
  bool f32 = probe_is_f32(Vraw);
  if (b < 256){
    if (b == 0){
      if (tid == 0) *flag = f32 ? 1 : 0;
      e1v[tid] = 0.f; e1v[tid + 256] = 0.f;
    }
    int t = b*256 + tid;
    const int stride = 65536;
    for (int s = 0; s < 23; ++s){
      int n4 = a.n[s] >> 2;
      float4* d = (float4*)a.dst[s];
      if (f32){
        const float4* sf = (const float4*)a.src[s];
        for (int i = t; i < n4; i += stride) d[i] = sf[i];
      } else {
        const ushort4* sb = (const ushort4*)a.src[s];
        for (int i = t; i < n4; i += stride){
          ushort4 u = sb[i];
          d[i] = make_float4(us2f(u.x), us2f(u.y), us2f(u.z), us2f(u.w));
        }
      }
    }
  } else {
    __shared__ unsigned long long msk[8];
    __shared__ int sj[2];
    int i = b - 256;
    int w = tid >> 6, lane = tid & 63;
    unsigned long long m0 = __ballot(adj[(size_t)i*kN + tid] != 0);
    unsigned long long m1 = __ballot(adj[(size_t)i*kN + 256 + tid] != 0);
    if (lane == 0){ msk[w] = m0; msk[4 + w] = m1; }
    __syncthreads();
    if (tid == 0){
      int j0 = -1, j1 = -1;
      for (int c = 0; c < 8 && j1 < 0; ++c){
        unsigned long long m = msk[c];
        while (m && j1 < 0){
          int bb = __builtin_ctzll(m);
          int j = c*64 + bb;
          if (j0 < 0) j0 = j; else j1 = j;
          m &= m - 1;
        }
      }
      if (j1 < 0) j0 = -1;
      sj[0] = j0; sj[1] = j1;
    }
    __syncthreads();
    int j0 = sj[0], j1 = sj[1];
    const float* Vf = (const float*)Vraw;
    const u16*  Vb = (const u16*)Vraw;
    auto rdV = [&](int r, int k)->float{
      return f32 ? Vf[(size_t)r*kIN + k] : us2f(Vb[(size_t)r*kIN + k]);
    };
    Xp[(size_t)i*768 + tid]       = rdV(i, tid);
    Xp[(size_t)i*768 + 256 + tid] = (j0 >= 0) ? rdV(j0, tid) : 0.f;
    Xp[(size_t)i*768 + 512 + tid] = (j1 >= 0) ? rdV(j1, tid) : 0.f;
  }
}

// ---------- block reduction (256 threads) ----------
__device__ __forceinline__ float blk_red(float v, float* tmp, bool isMax){
  int lane = threadIdx.x & 63, wv = threadIdx.x >> 6;
  #pragma unroll
  for (int o = 32; o > 0; o >>= 1){
    float t = __shfl_down(v, o, 64);
    v = isMax ? fmaxf(v, t) : (v + t);
  }
  __syncthreads();
  if (lane == 0) tmp[wv] = v;
  __syncthreads();
  float r = tmp[0];
  for (int i = 1; i < 4; ++i) r = isMax ? fmaxf(r, tmp[i]) : (r + tmp[i]);
  return r;
}

// ---------- workspace pointer bundle ----------
struct WSP {
  const int* adj; const int* flag; void* out;
  float *Vf,*prevf,*W1f,*sa1f,*cw1f,*cb1f,*cw2f,*cb2f,*ca0f,*ca1f;
  float *tw1f,*tb1f,*tw2f,*tb2f,*pw1f,*pb1f,*pw2f,*pb2f;
  float *W2f,*opwf,*opbf,*lngf,*lnbf;
  float *tw2t,*pw2t,*Wcomb,*OM,*ow4;
  float *Wh1,*e1v,*wadj,*Hc,*Am,*Bm,*uvec,*beta;
  float *s2,*maxp,*zp,*MZ,*gsum;
  float *htp0,*htp1,*hpp0,*hpp1,*hpp2,*hidden_t,*hidden_p;
  float *tfm,*cfm,*H4v,*Xp,*out3;
};

// ================== GEMM A: 64x64 tile, BK=32, 4x4 micro, dbuf ==================
struct GSeg2 { const float* X; const float* W; float* C; int ldx, ldw, ldc, K; };
struct GArgs2 { GSeg2 s[8]; const float* sa1; float* e1; };

__global__ __launch_bounds__(256) void k_gemmA(GArgs2 ga)
{
  __shared__ __align__(16) float Xs[2][32][68];
  __shared__ __align__(16) float Ws[2][32][68];
  const GSeg2 sg = ga.s[blockIdx.y];
  const int tm = blockIdx.x & 7;
  const int tn = blockIdx.x >> 3;
  const int i0 = tm << 6;
  const int n0 = tn << 6;
  const int tid = threadIdx.x;

  const int xrow = tid >> 3;
  const int xk   = (tid & 7) << 2;
  const int rg = (tid >> 4) << 2;
  const int cg = (tid & 15) << 2;

  const float* Xb = sg.X + (size_t)i0 * sg.ldx;
  const float* Wb = sg.W + (size_t)n0 * sg.ldw;

  float4 xr0, xr1, wr0, wr1;
  auto loadT = [&](int kt){
    xr0 = *(const float4*)(Xb + (size_t)xrow * sg.ldx + kt + xk);
    xr1 = *(const float4*)(Xb + (size_t)(xrow+32) * sg.ldx + kt + xk);
    wr0 = *(const float4*)(Wb + (size_t)xrow * sg.ldw + kt + xk);
    wr1 = *(const float4*)(Wb + (size_t)(xrow+32) * sg.ldw + kt + xk);
  };
  auto writeT = [&](int bu){
    Xs[bu][xk+0][xrow] = xr0.x;  Xs[bu][xk+1][xrow] = xr0.y;
    Xs[bu][xk+2][xrow] = xr0.z;  Xs[bu][xk+3][xrow] = xr0.w;
    Xs[bu][xk+0][xrow+32] = xr1.x;  Xs[bu][xk+1][xrow+32] = xr1.y;
    Xs[bu][xk+2][xrow+32] = xr1.z;  Xs[bu][xk+3][xrow+32] = xr1.w;
    Ws[bu][xk+0][xrow]    = wr0.x; Ws[bu][xk+1][xrow]    = wr0.y;
    Ws[bu][xk+2][xrow]    = wr0.z; Ws[bu][xk+3][xrow]    = wr0.w;
    Ws[bu][xk+0][xrow+32] = wr1.x; Ws[bu][xk+1][xrow+32] = wr1.y;
    Ws[bu][xk+2][xrow+32] = wr1.z; Ws[bu][xk+3][xrow+32] = wr1.w;
  };

  loadT(0); writeT(0); __syncthreads();

  float acc[4][4] = {};
  const int nkt = sg.K >> 5;
  for (int t = 0; t < nkt; ++t){
    if (t + 1 < nkt) loadT((t + 1) << 5);
    const int bu = t & 1;
    #pragma unroll
    for (int kk = 0; kk < 32; ++kk){
      const float4 av = *(const float4*)&Xs[bu][kk][rg];
      const float4 bv = *(const float4*)&Ws[bu][kk][cg];
      acc[0][0]+=av.x*bv.x; acc[0][1]+=av.x*bv.y; acc[0][2]+=av.x*bv.z; acc[0][3]+=av.x*bv.w;
      acc[1][0]+=av.y*bv.x; acc[1][1]+=av.y*bv.y; acc[1][2]+=av.y*bv.z; acc[1][3]+=av.y*bv.w;
      acc[2][0]+=av.z*bv.x; acc[2][1]+=av.z*bv.y; acc[2][2]+=av.z*bv.z; acc[2][3]+=av.z*bv.w;
      acc[3][0]+=av.w*bv.x; acc[3][1]+=av.w*bv.y; acc[3][2]+=av.w*bv.z; acc[3][3]+=av.w*bv.w;
    }
    if (t + 1 < nkt) writeT((t + 1) & 1);
    __syncthreads();
  }

  #pragma unroll
  for (int ri = 0; ri < 4; ++ri)
    *(float4*)(sg.C + (size_t)(i0 + rg + ri) * sg.ldc + (n0 + cg)) =
      make_float4(acc[ri][0], acc[ri][1], acc[ri][2], acc[ri][3]);

  // seg 0 = Wh1: fused e1 partial (e1[j] = Wh1[j,:].sa1)
  if (blockIdx.y == 0){
    int cb = n0 + cg;
    float s0 = ga.sa1[cb], s1 = ga.sa1[cb+1], s2v = ga.sa1[cb+2], s3 = ga.sa1[cb+3];
    #pragma unroll
    for (int ri = 0; ri < 4; ++ri){
      float v = acc[ri][0]*s0 + acc[ri][1]*s1 + acc[ri][2]*s2v + acc[ri][3]*s3;
      v += __shfl_xor(v, 1, 16);
      v += __shfl_xor(v, 2, 16);
      v += __shfl_xor(v, 4, 16);
      v += __shfl_xor(v, 8, 16);
      if ((tid & 15) == 0) atomicAdd(&ga.e1[i0 + rg + ri], v);
    }
  }
}

// ================== GEMM-32 body: 32x32 tile, BK=32, 2x2 micro, dbuf ==================
// bkn=0: W row-major [n][k]; bkn=1: W row-major [k][n]
struct GS32 { const float* X; const float* W; float* C; int ldx, ldw, ldc, K; int bkn; };

__device__ __forceinline__ void gemm32_body(const GS32 sg, int tm, int tn, int tid,
                                            float* Xs, float* Ws)
{
  const int i0 = tm << 5, n0 = tn << 5;
  const int xrow = tid >> 3;           // 0..31
  const int xk = (tid & 7) << 2;       // 0..28
  const int rg = (tid >> 4) << 1;      // 0..30
  const int cg = (tid & 15) << 1;      // 0..30
  const float* Xb = sg.X + (size_t)i0 * sg.ldx;
  const float* Wb = sg.bkn ? (sg.W + n0) : (sg.W + (size_t)n0 * sg.ldw);
  float4 xr, wr;
  auto loadT = [&](int kt){
    xr = *(const float4*)(Xb + (size_t)xrow * sg.ldx + kt + xk);
    if (sg.bkn) wr = *(const float4*)(Wb + (size_t)(kt + xrow) * sg.ldw + xk);
    else        wr = *(const float4*)(Wb + (size_t)xrow * sg.ldw + kt + xk);
  };
  auto writeT = [&](int bu){
    float* xs = Xs + bu*1152;
    xs[(xk+0)*36 + xrow] = xr.x; xs[(xk+1)*36 + xrow] = xr.y;
    xs[(xk+2)*36 + xrow] = xr.z; xs[(xk+3)*36 + xrow] = xr.w;
    float* wsp = Ws + bu*1152;
    if (sg.bkn){
      wsp[xrow*36 + xk+0] = wr.x; wsp[xrow*36 + xk+1] = wr.y;
      wsp[xrow*36 + xk+2] = wr.z; wsp[xrow*36 + xk+3] = wr.w;
    } else {
      wsp[(xk+0)*36 + xrow] = wr.x; wsp[(xk+1)*36 + xrow] = wr.y;
      wsp[(xk+2)*36 + xrow] = wr.z; wsp[(xk+3)*36 + xrow] = wr.w;
    }
  };
  loadT(0); writeT(0); __syncthreads();
  float a00=0,a01=0,a10=0,a11=0;
  const int nkt = sg.K >> 5;
  for (int t = 0; t < nkt; ++t){
    if (t+1 < nkt) loadT((t+1) << 5);
    const float* xs = Xs + (t&1)*1152;
    const float* wsp = Ws + (t&1)*1152;
    #pragma unroll
    for (int kk = 0; kk < 32; ++kk){
      float2 av = *(const float2*)&xs[kk*36 + rg];
      float2 bv = *(const float2*)&wsp[kk*36 + cg];
      a00 += av.x*bv.x; a01 += av.x*bv.y;
      a10 += av.y*bv.x; a11 += av.y*bv.y;
    }
    if (t+1 < nkt) writeT((t+1)&1);
    __syncthreads();
  }
  float* cp = sg.C + (size_t)(i0+rg)*sg.ldc + n0 + cg;
  *(float2*)cp = make_float2(a00, a01);
  *(float2*)(cp + sg.ldc) = make_float2(a10, a11);
}

// ---------- stage2: [0,128) redH | [128,640) h1stats+wadj | 640 ub+zeroH4v |
//            641,642 tw2t/pw2t | [643,723) Wcomb | [723,739) OM | 739 ow4 ----------
__global__ __launch_bounds__(256) void k_stage2(WSP w)
{
  __shared__ __align__(16) char smem[18432];
  float* st = (float*)smem;
  int b = blockIdx.x, tid = threadIdx.x;
  if (b < 128){
    int f = b*256 + tid;
    int c4 = f & 63;
    {
      float4 a = ((const float4*)w.htp0)[f], bb = ((const float4*)w.htp1)[f];
      float4 bi = ((const float4*)w.tb1f)[c4];
      ((float4*)w.hidden_t)[f] = make_float4(
        fmaxf(a.x+bb.x+bi.x,0.f), fmaxf(a.y+bb.y+bi.y,0.f),
        fmaxf(a.z+bb.z+bi.z,0.f), fmaxf(a.w+bb.w+bi.w,0.f));
    }
    {
      float4 a = ((const float4*)w.hpp0)[f], bb = ((const float4*)w.hpp1)[f];
      float4 c = ((const float4*)w.hpp2)[f];
      float4 bi = ((const float4*)w.pb1f)[c4];
      ((float4*)w.hidden_p)[f] = make_float4(
        fmaxf(a.x+bb.x+c.x+bi.x,0.f), fmaxf(a.y+bb.y+c.y+bi.y,0.f),
        fmaxf(a.z+bb.z+c.z+bi.z,0.f), fmaxf(a.w+bb.w+c.w+bi.w,0.f));
    }
  } else if (b < 640){
    int i = b - 128;
    int m0 = w.adj[(size_t)i*kN + tid];
    int m1 = w.adj[(size_t)i*kN + tid + 256];
    float ea = w.e1v[tid], eb = w.e1v[tid+256];
    float v0 = m0 ? ea : -1e30f;
    float v1 = m1 ? eb : -1e30f;
    float m = blk_red(fmaxf(v0, v1), st, true);
    float z = blk_red((m0 ? expf(ea-m) : 0.f) + (m1 ? expf(eb-m) : 0.f), st, false);
    float iz = 1.0f / z;
    w.wadj[(size_t)i*kN + tid]       = m0 ? expf(ea - m) * iz : 0.f;
    w.wadj[(size_t)i*kN + tid + 256] = m1 ? expf(eb - m) * iz : 0.f;
  } else if (b == 640){
    if (tid < 64){ st[tid] = w.ca0f[tid] + w.ca1f[tid]; w.H4v[tid] = 0.f; }
    __syncthreads();
    float a = 0.f;
    for (int d = 0; d < kHD; ++d) a += w.cw2f[(size_t)d*kHID + tid] * st[d];
    w.uvec[tid] = a;
    if (tid == 0){
      float bsum = 0.f;
      for (int d = 0; d < kHD; ++d) bsum += w.cb2f[d] * st[d];
      *w.beta = bsum;
    }
  } else if (b < 643){
    const float* src = (b == 641) ? w.tw2f : w.pw2f;
    float* dst = (b == 641) ? w.tw2t : w.pw2t;
    for (int ch = 0; ch < 4; ++ch){
      __syncthreads();
      #pragma unroll
      for (int e = 0; e < 16; ++e){
        int lin = e*256 + tid;
        int r = lin >> 6, c = lin & 63;
        st[r*65 + c] = src[(size_t)r*256 + ch*64 + c];
      }
      __syncthreads();
      #pragma unroll
      for (int e = 0; e < 16; ++e){
        int lin = e*256 + tid;
        int kc = lin >> 6, dd = lin & 63;
        dst[(size_t)(ch*64 + kc)*64 + dd] = st[dd*65 + kc];
      }
    }
  } else if (b < 723){
    // Wcomb[n][k] = sum_m opw[n][m] * W2[m][sel(k)], sel: k<256 -> k, else k+64
    int q = b - 643;
    int tm = q & 7, tn = q >> 3;       // tn 0..9
    const float* Wsrc = w.W2f + ((tn < 8) ? 0 : 64);
    GS32 sg{w.opwf, Wsrc, w.Wcomb, 256, 385, 320, 256, 1};
    gemm32_body(sg, tm, tn, tid, (float*)smem, (float*)(smem + 9216));
  } else if (b < 739){
    // OM[n][d] = sum_m opw[n][m] * W2[m][256+d]
    int q = b - 723;
    GS32 sg{w.opwf, w.W2f + 256, w.OM, 256, 385, 64, 256, 1};
    gemm32_body(sg, q & 7, q >> 3, tid, (float*)smem, (float*)(smem + 9216));
  } else {
    // ow4[n] = sum_m opw[n][m] * W2[m][384]
    st[tid] = w.W2f[(size_t)tid*385 + 384];
    __syncthreads();
    float a = 0.f;
    const float* orow = w.opwf + (size_t)tid*256;
    for (int m = 0; m < 256; m += 4){
      float4 o4 = *(const float4*)(orow + m);
      a += o4.x*st[m] + o4.y*st[m+1] + o4.z*st[m+2] + o4.w*st[m+3];
    }
    w.ow4[tid] = a;
  }
}

// ---------- stage3: [0,64) gemmB(reg) | [64,1088) s2 ----------
__global__ __launch_bounds__(256) void k_stage3(WSP w)
{
  __shared__ __align__(16) float smem3[4*256 + 256];
  int b = blockIdx.x, tid = threadIdx.x;
  if (b < 64){
    int m = b >> 5, grp = b & 31;
    const float* X  = m ? w.hidden_p : w.hidden_t;
    const float* Wt = m ? w.pw2t : w.tw2t;
    const float* bi = m ? w.pb2f : w.tb2f;
    float* C = m ? w.cfm : w.tfm;
    int i0 = grp*16 + (tid >> 6)*4;
    int d = tid & 63;
    const float* x0 = X + (size_t)i0*256;
    const float* x1 = x0 + 256;
    const float* x2 = x0 + 512;
    const float* x3 = x0 + 768;
    float a0=0.f, a1=0.f, a2=0.f, a3=0.f;
    for (int k = 0; k < 256; k += 4){
      float w0 = Wt[(size_t)(k+0)*64 + d];
      float w1 = Wt[(size_t)(k+1)*64 + d];
      float w2 = Wt[(size_t)(k+2)*64 + d];
      float w3 = Wt[(size_t)(k+3)*64 + d];
      float4 f0 = *(const float4*)(x0 + k);
      float4 f1 = *(const float4*)(x1 + k);
      float4 f2 = *(const float4*)(x2 + k);
      float4 f3 = *(const float4*)(x3 + k);
      a0 += f0.x*w0 + f0.y*w1 + f0.z*w2 + f0.w*w3;
      a1 += f1.x*w0 + f1.y*w1 + f1.z*w2 + f1.w*w3;
      a2 += f2.x*w0 + f2.y*w1 + f2.z*w2 + f2.w*w3;
      a3 += f3.x*w0 + f3.y*w1 + f3.z*w2 + f3.w*w3;
    }
    float bd = bi[d];
    C[(size_t)(i0+0)*64 + d] = a0 + bd;
    C[(size_t)(i0+1)*64 + d] = a1 + bd;
    C[(size_t)(i0+2)*64 + d] = a2 + bd;
    C[(size_t)(i0+3)*64 + d] = a3 + bd;
  } else {
    float* aib = smem3;                 // [4][256]
    float* uu  = smem3 + 1024;          // [256]
    int q = b - 64;
    int i0 = (q & 127) * 4, j0 = (q >> 7) * 64;
    int wv = tid >> 6, lane = tid & 63;
    uu[tid] = w.uvec[tid];
    float b1v = w.cb1f[tid];
    #pragma unroll
    for (int r = 0; r < 4; ++r) aib[r*256 + tid] = w.Am[(size_t)(i0+r)*kHID + tid] + b1v;
    __syncthreads();
    int i = i0 + wv, j = j0 + lane;
    const float4* bp = (const float4*)(w.Bm + (size_t)j*kHID);
    float acc = *w.beta;
    #pragma unroll 8
    for (int k4 = 0; k4 < kHID/4; ++k4){
      float4 bv = bp[k4];
      float4 a4 = *(const float4*)&aib[wv*256 + k4*4];
      float4 u4 = *(const float4*)&uu[k4*4];
      acc += fmaxf(a4.x+bv.x,0.f)*u4.x + fmaxf(a4.y+bv.y,0.f)*u4.y
           + fmaxf(a4.z+bv.z,0.f)*u4.z + fmaxf(a4.w+bv.w,0.f)*u4.w;
    }
    if (j == i) acc = -1e30f;
    w.s2[(size_t)i*kN + j] = acc;
    float m = acc;
    #pragma unroll
    for (int o = 32; o > 0; o >>= 1) m = fmaxf(m, __shfl_down(m, o, 64));
    m = __shfl(m, 0, 64);
    float e = expf(acc - m);
    #pragma unroll
    for (int o = 32; o > 0; o >>= 1) e += __shfl_down(e, o, 64);
    if (lane == 0){
      int pb = q*4 + wv;
      w.maxp[pb] = m; w.zp[pb] = e;
    }
  }
}

// ---------- stage4: [0,128) H1gemm->Hc | [128,192) h3->Hc | [192,200) h4 | 200 mz+zero gsum ----------
__global__ __launch_bounds__(256) void k_stage4(WSP w)
{
  __shared__ __align__(16) char smem[18432];
  int b = blockIdx.x, tid = threadIdx.x;
  if (b < 128){
    // H1 = wadj[512x512] @ Wh1[512x256]  (Wh1 already [k][n]) -> Hc cols 0..255
    GS32 sg{w.wadj, w.Wh1, w.Hc, 512, 256, 320, 512, 1};
    gemm32_body(sg, b & 15, b >> 4, tid, (float*)smem, (float*)(smem + 9216));
  } else if (b < 192){
    int d = b - 128;
    int lane = tid & 63, wv = tid >> 6;
    float v0 = w.tfm[(size_t)(2*tid)*kHD + d];
    float v1 = w.tfm[(size_t)(2*tid+1)*kHD + d];
    float s = v0 + v1;
    float x = s;
    #pragma unroll
    for (int off = 1; off < 64; off <<= 1){
      float y = __shfl_up(x, off, 64);
      if (lane >= off) x += y;
    }
    float* wsum = (float*)smem;
    if (lane == 63) wsum[wv] = x;
    __syncthreads();
    float base = 0.f;
    for (int k = 0; k < wv; ++k) base += wsum[k];
    float excl = base + x - s;
    w.Hc[(size_t)(2*tid)*320 + 256 + d]   = (excl + v0) / (float)(2*tid + 1);
    w.Hc[(size_t)(2*tid+1)*320 + 256 + d] = (excl + s)  / (float)(2*tid + 2);
  } else if (b < 200){
    float* sm = (float*)smem;
    int d = tid & 63, sub = tid >> 6;
    int r0 = (b-192)*64 + sub*16;
    float s = 0.f;
    #pragma unroll
    for (int e = 0; e < 16; ++e) s += w.cfm[(size_t)(r0+e)*kHD + d];
    sm[sub*64 + d] = s;
    __syncthreads();
    if (tid < 64)
      atomicAdd(&w.H4v[tid], sm[tid] + sm[64+tid] + sm[128+tid] + sm[192+tid]);
  } else {
    float* red = (float*)smem;
    float m = -1e30f;
    #pragma unroll
    for (int r = 0; r < 16; ++r) m = fmaxf(m, w.maxp[tid + 256*r]);
    m = blk_red(m, red, true);
    float z = 0.f;
    #pragma unroll
    for (int r = 0; r < 16; ++r) z += w.zp[tid + 256*r] * expf(w.maxp[tid + 256*r] - m);
    z = blk_red(z, red, false);
    if (tid == 0){ w.MZ[0] = m; w.MZ[1] = z; }
    w.gsum[tid] = 0.f;
  }
}

// ---------- stage5: [0,1024) gpart | [1024,1152) out3 tiles (Hc @ Wcomb^T) ----------
__global__ __launch_bounds__(256) void k_stage5(WSP w)
{
  __shared__ __align__(16) char smem[18432];
  int b = blockIdx.x, tid = threadIdx.x;
  if (b < 1024){
    float* wt = (float*)smem;        // [16][16]
    int i0 = (b & 31) * 16, j0 = (b >> 5) * 16;
    float M = w.MZ[0], invZ = 1.0f / w.MZ[1];
    {
      int r = tid >> 4, c = tid & 15;
      wt[r*16 + c] = expf(w.s2[(size_t)(i0+r)*kN + (j0+c)] - M) * invZ;
    }
    float b1v = w.cb1f[tid];
    float aib[16];
    #pragma unroll
    for (int r = 0; r < 16; ++r) aib[r] = w.Am[(size_t)(i0+r)*kHID + tid] + b1v;
    __syncthreads();
    float acc = 0.f;
    for (int j = 0; j < 16; ++j){
      float bj = w.Bm[(size_t)(j0+j)*kHID + tid];
      #pragma unroll
      for (int r = 0; r < 16; ++r)
        acc += wt[r*16 + j] * fmaxf(aib[r] + bj, 0.f);
    }
    atomicAdd(&w.gsum[tid], acc);
  } else {
    int q = b - 1024;
    GS32 sg{w.Hc, w.Wcomb, w.out3, 320, 320, 256, 320, 0};
    gemm32_body(sg, q & 15, q >> 4, tid, (float*)smem, (float*)(smem + 9216));
  }
}

// ---------- final: H2vec/cc2 recompute + rank-1 adds + LN + ELU, grid 128 ----------
__global__ __launch_bounds__(256) void k_final(WSP w)
{
  __shared__ float gs[kHID];
  __shared__ float part[kHD][4];
  __shared__ float h2s[kHD];
  __shared__ float cc2s[kOUT];
  int b = blockIdx.x, tid = threadIdx.x;
  // H2vec = cb2 + gsum @ cw2^T   (block-local recompute, ~16K fma)
  gs[tid] = w.gsum[tid];
  __syncthreads();
  {
    int dd = tid >> 2, q = tid & 3;
    float a = 0.f;
    for (int kk = 0; kk < 64; ++kk){
      int k = q*64 + kk;
      a += gs[k] * w.cw2f[(size_t)dd*kHID + k];
    }
    part[dd][q] = a;
  }
  __syncthreads();
  if (tid < kHD)
    h2s[tid] = w.cb2f[tid] + part[tid][0] + part[tid][1] + part[tid][2] + part[tid][3];
  __syncthreads();
  // cc2[n] = OM[n][:] . H2vec
  {
    float a = 0.f;
    const float* om = w.OM + (size_t)tid*64;
    for (int d = 0; d < kHD; d += 4){
      float4 o4 = *(const float4*)(om + d);
      a += o4.x*h2s[d] + o4.y*h2s[d+1] + o4.z*h2s[d+2] + o4.w*h2s[d+3];
    }
    cc2s[tid] = a;
  }
  __syncthreads();
  int row = b*4 + (tid >> 6), lane = tid & 63;
  float h4r = (row < kHD) ? w.H4v[row] : 0.f;
  float4 v  = *(const float4*)(w.out3 + (size_t)row*kOUT + lane*4);
  float4 c2 = *(const float4*)(&cc2s[lane*4]);
  float4 o4 = *(const float4*)(w.ow4 + lane*4);
  float4 pb = *(const float4*)(w.opbf + lane*4);
  v.x += c2.x + h4r*o4.x + pb.x;
  v.y += c2.y + h4r*o4.y + pb.y;
  v.z += c2.z + h4r*o4.z + pb.z;
  v.w += c2.w + h4r*o4.w + pb.w;
  float s = v.x + v.y + v.z + v.w;
  #pragma unroll
  for (int o = 32; o > 0; o >>= 1) s += __shfl_xor(s, o, 64);
  float mu = s * (1.0f/kOUT);
  float dx = v.x-mu, dy = v.y-mu, dz = v.z-mu, dw = v.w-mu;
  float ss = dx*dx + dy*dy + dz*dz + dw*dw;
  #pragma unroll
  for (int o = 32; o > 0; o >>= 1) ss += __shfl_xor(ss, o, 64);
  float rs = rsqrtf(ss * (1.0f/kOUT) + 1e-5f);
  float4 g  = *(const float4*)(w.lngf + lane*4);
  float4 be = *(const float4*)(w.lnbf + lane*4);
  float y0 = dx*rs*g.x + be.x, y1 = dy*rs*g.y + be.y;
  float y2 = dz*rs*g.z + be.z, y3 = dw*rs*g.w + be.w;
  y0 = (y0 > 0.f) ? y0 : expm1f(y0);
  y1 = (y1 > 0.f) ? y1 : expm1f(y1);
  y2 = (y2 > 0.f) ? y2 : expm1f(y2);
  y3 = (y3 > 0.f) ? y3 : expm1f(y3);
  if (*w.flag){
    *(float4*)((float*)w.out + (size_t)row*kOUT + lane*4) = make_float4(y0,y1,y2,y3);
  } else {
    ushort4 u; u.x = f2us(y0); u.y = f2us(y1); u.z = f2us(y2); u.w = f2us(y3);
    ((ushort4*)w.out)[(size_t)row*64 + lane] = u;
  }
}

extern "C" void kernel_launch(void* const* d_in, const int* in_sizes, int n_in,
                              void* d_out, int out_size, void* d_ws, size_t ws_size,
                              hipStream_t stream)
{
  const void* V     = d_in[0];
  const int*  adj   = (const int*)d_in[1];
  const void* prev  = d_in[2];
  const void* W1    = d_in[3];
  // d_in[4] = sa0 : dead (row-shift invariant softmax)
  const void* sa1   = d_in[5];
  const void* ce_w1 = d_in[6];
  const void* ce_b1 = d_in[7];
  const void* ce_w2 = d_in[8];
  const void* ce_b2 = d_in[9];
  const void* ca0   = d_in[10];
  const void* ca1   = d_in[11];
  const void* te_w1 = d_in[12];
  const void* te_b1 = d_in[13];
  const void* te_w2 = d_in[14];
  const void* te_b2 = d_in[15];
  // d_in[16,17] = ta0,ta1 : dead
  const void* pe_w1 = d_in[18];
  const void* pe_b1 = d_in[19];
  const void* pe_w2 = d_in[20];
  const void* pe_b2 = d_in[21];
  // d_in[22,23] = pa0,pa1 : dead
  const void* W2    = d_in[24];
  const void* op_w  = d_in[25];
  const void* op_b  = d_in[26];
  const void* ln_g  = d_in[27];
  const void* ln_b  = d_in[28];

  // ---- workspace layout (floats) ----
  float* ws  = (float*)d_ws;
  int*  flag = (int*)ws;               // 16 floats reserved
  float* p   = ws + 16;
  float* Vf   = p; p += 131072;
  float* prevf= p; p += 131072;
  float* W1f  = p; p += 65536;
  float* sa1f = p; p += 256;
  float* cw1f = p; p += 131072;
  float* cb1f = p; p += 256;
  float* cw2f = p; p += 16384;
  float* cb2f = p; p += 64;
  float* ca0f = p; p += 64;
  float* ca1f = p; p += 64;
  float* tw1f = p; p += 131072;
  float* tb1f = p; p += 256;
  float* tw2f = p; p += 16384;
  float* tb2f = p; p += 64;
  float* pw1f = p; p += 196608;
  float* pb1f = p; p += 256;
  float* pw2f = p; p += 16384;
  float* pb2f = p; p += 64;
  float* W2f  = p; p += 98560;
  float* opwf = p; p += 65536;
  float* opbf = p; p += 256;
  float* lngf = p; p += 256;
  float* lnbf = p; p += 256;
  float* tw2t = p; p += 16384;
  float* pw2t = p; p += 16384;
  float* Wcomb= p; p += 81920;
  float* OM   = p; p += 16384;
  float* ow4  = p; p += 256;
  float* Wh1      = p; p += 131072;
  float* e1v      = p; p += 512;
  float* wadj     = p; p += 262144;
  float* Hc       = p; p += 163840;
  float* Am       = p; p += 131072;
  float* Bm       = p; p += 131072;
  float* uvec     = p; p += 256;
  float* beta     = p; p += 16;
  float* s2       = p; p += 262144;
  float* maxp     = p; p += 4096;
  float* zpart    = p; p += 4096;
  float* MZ       = p; p += 16;
  float* gsum     = p; p += 256;
  float* htp0     = p; p += 131072;
  float* htp1     = p; p += 131072;
  float* hpp0     = p; p += 131072;
  float* hpp1     = p; p += 131072;
  float* hpp2     = p; p += 131072;
  float* hidden_t = p; p += 131072;
  float* hidden_p = p; p += 131072;
  float* tfm      = p; p += 32768;
  float* cfm      = p; p += 32768;
  float* H4v      = p; p += 64;
  float* Xp       = p; p += 393216;
  float* out3     = p; p += 131072;

  // ---- pointer bundle ----
  WSP w;
  w.adj = adj; w.flag = flag; w.out = d_out;
  w.Vf=Vf; w.prevf=prevf; w.W1f=W1f; w.sa1f=sa1f; w.cw1f=cw1f; w.cb1f=cb1f;
  w.cw2f=cw2f; w.cb2f=cb2f; w.ca0f=ca0f; w.ca1f=ca1f;
  w.tw1f=tw1f; w.tb1f=tb1f; w.tw2f=tw2f; w.tb2f=tb2f;
  w.pw1f=pw1f; w.pb1f=pb1f; w.pw2f=pw2f; w.pb2f=pb2f;
  w.W2f=W2f; w.opwf=opwf; w.opbf=opbf; w.lngf=lngf; w.lnbf=lnbf;
  w.tw2t=tw2t; w.pw2t=pw2t; w.Wcomb=Wcomb; w.OM=OM; w.ow4=ow4;
  w.Wh1=Wh1; w.e1v=e1v; w.wadj=wadj; w.Hc=Hc;
  w.Am=Am; w.Bm=Bm; w.uvec=uvec; w.beta=beta;
  w.s2=s2; w.maxp=maxp; w.zp=zpart; w.MZ=MZ; w.gsum=gsum;
  w.htp0=htp0; w.htp1=htp1; w.hpp0=hpp0; w.hpp1=hpp1; w.hpp2=hpp2;
  w.hidden_t=hidden_t; w.hidden_p=hidden_p;
  w.tfm=tfm; w.cfm=cfm; w.H4v=H4v; w.Xp=Xp; w.out3=out3;

  // ---- fused convert + probe + packsel + zero e1: 768 blocks ----
  {
    ConvArgs ca;
    const void* srcs[23] = {V, prev, W1, sa1, ce_w1, ce_b1, ce_w2, ce_b2, ca0, ca1,
                            te_w1, te_b1, te_w2, te_b2, pe_w1, pe_b1, pe_w2, pe_b2,
                            W2, op_w, op_b, ln_g, ln_b};
    float* dsts[23] = {Vf, prevf, W1f, sa1f, cw1f, cb1f, cw2f, cb2f, ca0f, ca1f,
                       tw1f, tb1f, tw2f, tb2f, pw1f, pb1f, pw2f, pb2f,
                       W2f, opwf, opbf, lngf, lnbf};
    int ns[23] = {131072, 131072, 65536, 256, 131072, 256, 16384, 64, 64, 64,
                  131072, 256, 16384, 64, 196608, 256, 16384, 64,
                  98560, 65536, 256, 256, 256};
    for (int s = 0; s < 23; ++s){ ca.src[s] = srcs[s]; ca.dst[s] = dsts[s]; ca.n[s] = ns[s]; }
    k_conv<<<768, 256, 0, stream>>>(ca, (const unsigned int*)V, adj, flag, Xp, e1v);
  }

  // ---- GEMM batch A: 8 segs x 32 tiles = 256 blocks (+ fused e1 partials) ----
  {
    GArgs2 g{};
    g.s[0] = {Vf,       W1f,        Wh1,  256, 256, 256, 256};
    g.s[1] = {Vf,       cw1f,       Am,   256, 512, 256, 256};
    g.s[2] = {Vf,       cw1f + 256, Bm,   256, 512, 256, 256};
    g.s[3] = {Vf,       tw1f,       htp0, 256, 512, 256, 256};
    g.s[4] = {prevf,    tw1f + 256, htp1, 256, 512, 256, 256};
    g.s[5] = {Xp,       pw1f,       hpp0, 768, 768, 256, 256};
    g.s[6] = {Xp + 256, pw1f + 256, hpp1, 768, 768, 256, 256};
    g.s[7] = {Xp + 512, pw1f + 512, hpp2, 768, 768, 256, 256};
    g.sa1 = sa1f; g.e1 = e1v;
    k_gemmA<<<dim3(32, 8), 256, 0, stream>>>(g);
  }

  // ---- stage2: redH | h1stats+wadj | ub | transposes | Wcomb/OM/ow4 ----
  k_stage2<<<740, 256, 0, stream>>>(w);

  // ---- stage3: gemmB | s2 ----
  k_stage3<<<1088, 256, 0, stream>>>(w);

  // ---- stage4: H1gemm->Hc | h3->Hc | h4 | mz ----
  k_stage4<<<201, 256, 0, stream>>>(w);

  // ---- stage5: gpart | out3 tiles ----
  k_stage5<<<1152, 256, 0, stream>>>(w);

  // ---- final: H2/H4 rank-1 + LN + ELU ----
  k_final<<<128, 256, 0, stream>>>(w);
}